// Round 1
// baseline (2350.815 us; speedup 1.0000x reference)
//
#include <hip/hip_runtime.h>
#include <hip/hip_bf16.h>

#define N_NODES 10000
#define N_EDGES 160000

// ws layout (floats):
//   msg   [20,480,000]   (N * 2048)
//   x     [ 1,280,000]   (N * 128)
//   WC    [   655,360]   (4 * 1280 * 128), c = u*10+a major
//   demb  [ 1,280,000]   (N * 128)
//   tinv  [    10,000]
//   rho   [    10,000]

__device__ __forceinline__ float silu_f(float v){ return v / (1.f + expf(-v)); }

// ---------------------------------------------------------------- K1: x = nf @ Wup/sqrt(128)
__global__ __launch_bounds__(128) void k_node_up(const float* __restrict__ nf,
                                                 const float* __restrict__ Wup,
                                                 float* __restrict__ x){
  const int n = blockIdx.x, u = threadIdx.x;
  __shared__ float row[128];
  row[u] = nf[n*128 + u];
  __syncthreads();
  float acc = 0.f;
  #pragma unroll 16
  for (int k = 0; k < 128; ++k) acc += row[k] * Wup[k*128 + u];
  x[n*128 + u] = acc * 0.08838834764831843f;   // 1/sqrt(128)
}

// ---------------------------------------------------------------- K1b: WC[l,u,a,w] = sum_v Wlin[l,u,v]*Wskip[l,v,a,w] * 1/sqrt(128*1280)
__global__ __launch_bounds__(256) void k_wc(const float* __restrict__ Wlin,
                                            const float* __restrict__ Wskip,
                                            float* __restrict__ WC){
  const int lu = blockIdx.x;           // l*128 + u
  const int l  = lu >> 7;
  __shared__ float wl[128];
  if (threadIdx.x < 128) wl[threadIdx.x] = Wlin[lu*128 + threadIdx.x];
  __syncthreads();
  const float* Wsk = Wskip + (size_t)l * 163840;   // [v][a][w] = v*1280 + a*128 + w
  for (int i = threadIdx.x; i < 1280; i += 256){   // i = a*128 + w
    float acc = 0.f;
    #pragma unroll 16
    for (int v = 0; v < 128; ++v) acc += wl[v] * Wsk[v*1280 + i];
    WC[(size_t)lu*1280 + i] = acc * 0.0024705294220065465f;  // 1/sqrt(128*1280)
  }
}

// ---------------------------------------------------------------- K2: per-edge radial MLP + density + scatter
// 256 threads = 4 waves, 4 edges per wave => 16 edges/block, grid = 10000
__global__ __launch_bounds__(256) void k_edge(const float* __restrict__ ef,
                                              const float* __restrict__ ea,
                                              const int*   __restrict__ eidx,
                                              const float* __restrict__ x,
                                              const float* __restrict__ Wr1,
                                              const float* __restrict__ Wr2,
                                              const float* __restrict__ Wr3,
                                              const float* __restrict__ Wr4,
                                              const float* __restrict__ Wd,
                                              float* __restrict__ msg,
                                              float* __restrict__ rho){
  const int wave = threadIdx.x >> 6, lane = threadIdx.x & 63;
  const int ebase = blockIdx.x * 16 + wave * 4;

  __shared__ float sh_h [4][64];
  __shared__ float sh_g [4][64];
  __shared__ float sh_h3[4][4][64];
  alignas(16) __shared__ float sh_tpw[4][4][512];
  __shared__ float sh_xs[4][4][128];
  __shared__ float sh_ea[4][4][16];

  // ---- per-edge MLP to h3
  for (int e4 = 0; e4 < 4; ++e4){
    const int e = ebase + e4;
    float efv[8];
    #pragma unroll
    for (int i = 0; i < 8; ++i) efv[i] = ef[e*8 + i];

    float a1 = 0.f;
    #pragma unroll
    for (int i = 0; i < 8; ++i) a1 += efv[i] * Wr1[i*64 + lane];
    a1 *= 0.3535533905932738f;                 // 1/sqrt(8)
    sh_h[wave][lane] = silu_f(a1);
    __syncthreads();

    float a2 = 0.f;
    #pragma unroll 8
    for (int i = 0; i < 64; ++i) a2 += sh_h[wave][i] * Wr2[i*64 + lane];
    a2 *= 0.125f;
    sh_g[wave][lane] = silu_f(a2);
    __syncthreads();

    float a3 = 0.f;
    #pragma unroll 8
    for (int i = 0; i < 64; ++i) a3 += sh_g[wave][i] * Wr3[i*64 + lane];
    a3 *= 0.125f;
    sh_h3[wave][e4][lane] = silu_f(a3);

    if (lane == 0){
      float dd = 0.f;
      #pragma unroll
      for (int i = 0; i < 8; ++i) dd += efv[i] * Wd[i];
      dd = tanhf(dd * dd);
      atomicAdd(&rho[eidx[N_EDGES + e]], dd);
    }
    const int snd = eidx[e];
    sh_xs[wave][e4][lane]      = x[snd*128 + lane];
    sh_xs[wave][e4][lane + 64] = x[snd*128 + 64 + lane];
    if (lane < 16) sh_ea[wave][e4][lane] = ea[e*16 + lane];
    __syncthreads();
  }

  // ---- tpw = h3 @ Wr4/8 for the wave's 4 edges (Wr4 read once per 4 edges)
  float acct[2][4][4];
  #pragma unroll
  for (int cf = 0; cf < 2; ++cf)
    #pragma unroll
    for (int j = 0; j < 4; ++j)
      #pragma unroll
      for (int e4 = 0; e4 < 4; ++e4) acct[cf][j][e4] = 0.f;

  for (int i = 0; i < 64; ++i){
    const float h0 = sh_h3[wave][0][i];
    const float h1 = sh_h3[wave][1][i];
    const float h2 = sh_h3[wave][2][i];
    const float h3 = sh_h3[wave][3][i];
    #pragma unroll
    for (int cf = 0; cf < 2; ++cf){
      const float4 wv = *(const float4*)&Wr4[i*512 + cf*256 + lane*4];
      const float wj[4] = {wv.x, wv.y, wv.z, wv.w};
      #pragma unroll
      for (int j = 0; j < 4; ++j){
        acct[cf][j][0] += h0 * wj[j];
        acct[cf][j][1] += h1 * wj[j];
        acct[cf][j][2] += h2 * wj[j];
        acct[cf][j][3] += h3 * wj[j];
      }
    }
  }
  #pragma unroll
  for (int cf = 0; cf < 2; ++cf)
    #pragma unroll
    for (int j = 0; j < 4; ++j)
      #pragma unroll
      for (int e4 = 0; e4 < 4; ++e4)
        sh_tpw[wave][e4][cf*256 + lane*4 + j] = acct[cf][j][e4] * 0.125f;
  __syncthreads();

  // ---- scatter: message[rcv, 128*OFF_l + u*d + k] += xs[u]*tpw[l*128+u]*sh[OFF_l+k]
  for (int e4 = 0; e4 < 4; ++e4){
    const int e = ebase + e4;
    const int rcv = eidx[N_EDGES + e];
    float* mrow = msg + (size_t)rcv * 2048;
    #pragma unroll
    for (int l = 0; l < 4; ++l){
      const int d   = 2*l + 1;
      const int off = (l==0 ? 0 : l==1 ? 1 : l==2 ? 4 : 9);
      for (int i = lane; i < 128*d; i += 64){
        const int u = i / d;
        const int k = i - u*d;
        const float v = sh_xs[wave][e4][u] * sh_tpw[wave][e4][l*128 + u]
                      * sh_ea[wave][e4][off + k];
        atomicAdd(&mrow[128*off + i], v);
      }
    }
  }
}

// ---------------------------------------------------------------- K3: tinv + demb per node
__global__ __launch_bounds__(128) void k_demb(const float* __restrict__ rho,
                                              const float* __restrict__ Wsin,
                                              float* __restrict__ demb,
                                              float* __restrict__ tinv){
  const int n = blockIdx.x, u = threadIdx.x;
  const float r = rho[n];
  if (u == 0) tinv[n] = 1.f / (r + 1.f);
  __shared__ float semb[32];
  if (u < 16){
    const float freq = expf(-0.28782313662425572f * (float)u);  // ln(100)/16
    const float ang  = r * freq;
    semb[u]      = sinf(ang);
    semb[u + 16] = cosf(ang);
  }
  __syncthreads();
  float acc = 0.f;
  #pragma unroll
  for (int j = 0; j < 32; ++j) acc += semb[j] * Wsin[j*128 + u];
  demb[n*128 + u] = acc;
}

// ---------------------------------------------------------------- K5: out_l[(n,k),w] = sum_c z[(n,k),c] * WC_l[c,w]
// z[(n,k), u*10+a] = (msg[n, 128*OFF + u*D + k]*tinv[n] + (L==0)*demb[n,u]) * attrs[n,a]
// 64-row x 128-col tile, K-chunks of 80; 256 threads: tw=tid&31 (4 w each), tr=tid>>5 (8 rows each)
template<int L, int D>
__global__ __launch_bounds__(256) void k_final(const float* __restrict__ msg,
                                               const float* __restrict__ tinv,
                                               const float* __restrict__ demb,
                                               const float* __restrict__ attrs,
                                               const float* __restrict__ WC,
                                               float* __restrict__ out){
  constexpr int OFF  = (L==0 ? 0 : L==1 ? 1 : L==2 ? 4 : 9);
  constexpr int ROWS = N_NODES * D;
  const int r0  = blockIdx.x * 64;
  const int tid = threadIdx.x;
  const int tw  = tid & 31;
  const int tr  = tid >> 5;

  alignas(16) __shared__ float zs[80][64];
  alignas(16) __shared__ float bs[80*128];

  float acc[8][4];
  #pragma unroll
  for (int i = 0; i < 8; ++i)
    #pragma unroll
    for (int j = 0; j < 4; ++j) acc[i][j] = 0.f;

  for (int c0 = 0; c0 < 1280; c0 += 80){
    // stage B chunk: 80 x 128 contiguous floats of WC_l
    const float4* src = (const float4*)(WC + ((size_t)L*1280 + c0) * 128);
    float4* dst = (float4*)bs;
    #pragma unroll
    for (int j = 0; j < 10; ++j) dst[tid + j*256] = src[tid + j*256];

    // build z chunk
    for (int j = tid; j < 80*64; j += 256){
      const int cc = j >> 6, rl = j & 63;
      const int gr = r0 + rl;
      float val = 0.f;
      if (gr < ROWS){
        const int n = gr / D;
        const int k = gr - n*D;
        const int c = c0 + cc;
        const int u = c / 10;
        const int a = c - u*10;
        float m = msg[(size_t)n*2048 + 128*OFF + u*D + k] * tinv[n];
        if (L == 0) m += demb[n*128 + u];
        val = m * attrs[n*10 + a];
      }
      zs[cc][rl] = val;
    }
    __syncthreads();

    for (int cc = 0; cc < 80; ++cc){
      const float4 bv = *(const float4*)&bs[cc*128 + tw*4];
      const float4 za = *(const float4*)&zs[cc][tr*8];
      const float4 zb = *(const float4*)&zs[cc][tr*8 + 4];
      const float zr[8] = {za.x, za.y, za.z, za.w, zb.x, zb.y, zb.z, zb.w};
      #pragma unroll
      for (int i = 0; i < 8; ++i){
        acc[i][0] += zr[i] * bv.x;
        acc[i][1] += zr[i] * bv.y;
        acc[i][2] += zr[i] * bv.z;
        acc[i][3] += zr[i] * bv.w;
      }
    }
    __syncthreads();
  }

  // epilogue: out[n*2048 + w*16 + OFF + k]
  #pragma unroll
  for (int i = 0; i < 8; ++i){
    const int gr = r0 + tr*8 + i;
    if (gr < ROWS){
      const int n = gr / D;
      const int k = gr - n*D;
      float* op = out + (size_t)n*2048 + OFF + k;
      #pragma unroll
      for (int j = 0; j < 4; ++j) op[(tw*4 + j) * 16] = acc[i][j];
    }
  }
}

// ----------------------------------------------------------------
extern "C" void kernel_launch(void* const* d_in, const int* in_sizes, int n_in,
                              void* d_out, int out_size, void* d_ws, size_t ws_size,
                              hipStream_t stream){
  const float* node_attrs = (const float*)d_in[0];
  const float* node_feats = (const float*)d_in[1];
  const float* edge_attrs = (const float*)d_in[2];
  const float* edge_feats = (const float*)d_in[3];
  const int*   edge_index = (const int*)d_in[4];
  const float* W_up  = (const float*)d_in[5];
  const float* Wr1   = (const float*)d_in[6];
  const float* Wr2   = (const float*)d_in[7];
  const float* Wr3   = (const float*)d_in[8];
  const float* Wr4   = (const float*)d_in[9];
  const float* Wd    = (const float*)d_in[10];
  const float* Wsin  = (const float*)d_in[11];
  const float* Wlin  = (const float*)d_in[12];
  const float* Wskip = (const float*)d_in[13];
  float* out = (float*)d_out;

  float* ws   = (float*)d_ws;
  float* msg  = ws;                         // 20,480,000
  float* x    = msg  + 20480000;            //  1,280,000
  float* WC   = x    + 1280000;             //    655,360
  float* demb = WC   + 655360;              //  1,280,000
  float* tinv = demb + 1280000;             //     10,000
  float* rho  = tinv + 10000;               //     10,000

  hipMemsetAsync(msg, 0, (size_t)20480000 * sizeof(float), stream);
  hipMemsetAsync(rho, 0, (size_t)10000 * sizeof(float), stream);

  k_node_up<<<N_NODES, 128, 0, stream>>>(node_feats, W_up, x);
  k_wc<<<512, 256, 0, stream>>>(Wlin, Wskip, WC);
  k_edge<<<N_EDGES/16, 256, 0, stream>>>(edge_feats, edge_attrs, edge_index, x,
                                         Wr1, Wr2, Wr3, Wr4, Wd, msg, rho);
  k_demb<<<N_NODES, 128, 0, stream>>>(rho, Wsin, demb, tinv);

  k_final<0,1><<<(N_NODES*1 + 63)/64, 256, 0, stream>>>(msg, tinv, demb, node_attrs, WC, out);
  k_final<1,3><<<(N_NODES*3 + 63)/64, 256, 0, stream>>>(msg, tinv, demb, node_attrs, WC, out);
  k_final<2,5><<<(N_NODES*5 + 63)/64, 256, 0, stream>>>(msg, tinv, demb, node_attrs, WC, out);
  k_final<3,7><<<(N_NODES*7 + 63)/64, 256, 0, stream>>>(msg, tinv, demb, node_attrs, WC, out);
}

// Round 2
// 2100.310 us; speedup vs baseline: 1.1193x; 1.1193x over previous
//
#include <hip/hip_runtime.h>
#include <hip/hip_bf16.h>

#define N_NODES 10000
#define N_EDGES 160000

// ws layout:
//   msg   [20,480,000] f32   (N * 2048), layout msg[n][u*16 + sk], sk=OFF_l+k
//   x     [ 1,280,000] f32   (N * 128)
//   WC    [   655,360] f32   (4 * 1280 * 128), c = u*10+a major
//   cnt   [10,000] i32 | off [10,016] i32 | cur [10,000] i32 | elist [160,000] i32

__device__ __forceinline__ float silu_f(float v){ return v / (1.f + expf(-v)); }

// ---------------------------------------------------------------- K1: x = nf @ Wup/sqrt(128)
__global__ __launch_bounds__(128) void k_node_up(const float* __restrict__ nf,
                                                 const float* __restrict__ Wup,
                                                 float* __restrict__ x){
  const int n = blockIdx.x, u = threadIdx.x;
  __shared__ float row[128];
  row[u] = nf[n*128 + u];
  __syncthreads();
  float acc = 0.f;
  #pragma unroll 16
  for (int k = 0; k < 128; ++k) acc += row[k] * Wup[k*128 + u];
  x[n*128 + u] = acc * 0.08838834764831843f;   // 1/sqrt(128)
}

// ---------------------------------------------------------------- K1b: WC[l,u,a,w] = sum_v Wlin[l,u,v]*Wskip[l,v,a,w] * 1/sqrt(128*1280)
__global__ __launch_bounds__(256) void k_wc(const float* __restrict__ Wlin,
                                            const float* __restrict__ Wskip,
                                            float* __restrict__ WC){
  const int lu = blockIdx.x;           // l*128 + u
  const int l  = lu >> 7;
  __shared__ float wl[128];
  if (threadIdx.x < 128) wl[threadIdx.x] = Wlin[lu*128 + threadIdx.x];
  __syncthreads();
  const float* Wsk = Wskip + (size_t)l * 163840;   // [v][a][w] = v*1280 + a*128 + w
  for (int i = threadIdx.x; i < 1280; i += 256){   // i = a*128 + w
    float acc = 0.f;
    #pragma unroll 16
    for (int v = 0; v < 128; ++v) acc += wl[v] * Wsk[v*1280 + i];
    WC[(size_t)lu*1280 + i] = acc * 0.0024705294220065465f;  // 1/sqrt(128*1280)
  }
}

// ---------------------------------------------------------------- CSR build
__global__ __launch_bounds__(256) void k_count(const int* __restrict__ eidx,
                                               int* __restrict__ cnt){
  const int e = blockIdx.x * 256 + threadIdx.x;
  if (e < N_EDGES) atomicAdd(&cnt[eidx[N_EDGES + e]], 1);
}

__global__ __launch_bounds__(256) void k_scan(const int* __restrict__ cnt,
                                              int* __restrict__ off,
                                              int* __restrict__ cur){
  __shared__ int sums[256];
  const int t = threadIdx.x;
  const int base = t * 40;
  int s = 0;
  for (int i = 0; i < 40; ++i){
    const int idx = base + i;
    if (idx < N_NODES) s += cnt[idx];
  }
  sums[t] = s;
  __syncthreads();
  for (int st = 1; st < 256; st <<= 1){
    const int v = (t >= st) ? sums[t - st] : 0;
    __syncthreads();
    sums[t] += v;
    __syncthreads();
  }
  int pre = (t > 0) ? sums[t - 1] : 0;
  for (int i = 0; i < 40; ++i){
    const int idx = base + i;
    if (idx < N_NODES){
      off[idx] = pre; cur[idx] = pre;
      pre += cnt[idx];
    }
  }
  if (t == 255) off[N_NODES] = sums[255];
}

__global__ __launch_bounds__(256) void k_bucket(const int* __restrict__ eidx,
                                                int* __restrict__ cur,
                                                int* __restrict__ elist){
  const int e = blockIdx.x * 256 + threadIdx.x;
  if (e < N_EDGES){
    const int pos = atomicAdd(&cur[eidx[N_EDGES + e]], 1);
    elist[pos] = e;
  }
}

// ---------------------------------------------------------------- K2: gather — block per node
// groups of 16 edges; wave w owns slots w*4..w*4+3 (MLP + tpw);
// all 256 threads register-accumulate 2048 outputs (u=tid&127, h=tid>>7)
__global__ __launch_bounds__(256) void k_gather(const float* __restrict__ ef,
                                                const float* __restrict__ ea,
                                                const int*   __restrict__ eidx,
                                                const float* __restrict__ x,
                                                const float* __restrict__ Wr1,
                                                const float* __restrict__ Wr2,
                                                const float* __restrict__ Wr3,
                                                const float* __restrict__ Wr4,
                                                const float* __restrict__ Wd,
                                                const float* __restrict__ Wsin,
                                                const int*   __restrict__ off,
                                                const int*   __restrict__ elist,
                                                float* __restrict__ msg){
  const int n    = blockIdx.x;
  const int tid  = threadIdx.x;
  const int wave = tid >> 6, lane = tid & 63;
  const int beg  = off[n], end = off[n + 1];
  const int ngrp = (end - beg + 15) >> 4;

  __shared__ float s_h[4][64];
  __shared__ float s_g[4][64];
  __shared__ float s_h3[4][4][64];
  alignas(16) __shared__ float s_xs[16][128];
  alignas(16) __shared__ float s_w2[16][512];
  alignas(16) __shared__ float s_sh[16][16];
  __shared__ float s_dd[16];
  __shared__ float s_rho;
  __shared__ float s_emb[32];

  if (tid == 0) s_rho = 0.f;

  const int u = tid & 127;       // output mul channel
  const int h = tid >> 7;        // sh half: h=0 -> sk 0..7, h=1 -> sk 8..15
  float acc[8];
  #pragma unroll
  for (int j = 0; j < 8; ++j) acc[j] = 0.f;

  for (int grp = 0; grp < ngrp; ++grp){
    // ---- MLP phase: each wave processes its 4 slots sequentially
    for (int e4 = 0; e4 < 4; ++e4){
      const int slot  = wave*4 + e4;
      const int p     = beg + grp*16 + slot;
      const bool valid = (p < end);
      int e = 0; if (valid) e = elist[p];

      float efv[8];
      #pragma unroll
      for (int i = 0; i < 8; ++i) efv[i] = valid ? ef[e*8 + i] : 0.f;

      float a1 = 0.f;
      #pragma unroll
      for (int i = 0; i < 8; ++i) a1 += efv[i] * Wr1[i*64 + lane];
      s_h[wave][lane] = silu_f(a1 * 0.3535533905932738f);
      __syncthreads();

      float a2 = 0.f;
      #pragma unroll 8
      for (int i = 0; i < 64; ++i) a2 += s_h[wave][i] * Wr2[i*64 + lane];
      s_g[wave][lane] = silu_f(a2 * 0.125f);
      __syncthreads();

      float a3 = 0.f;
      #pragma unroll 8
      for (int i = 0; i < 64; ++i) a3 += s_g[wave][i] * Wr3[i*64 + lane];
      s_h3[wave][e4][lane] = silu_f(a3 * 0.125f);   // zero when invalid (efv=0 chain)

      if (lane == 0){
        float dd = 0.f;
        #pragma unroll
        for (int i = 0; i < 8; ++i) dd += efv[i] * Wd[i];
        s_dd[slot] = valid ? tanhf(dd * dd) : 0.f;
      }
      const int snd = valid ? eidx[e] : 0;
      s_xs[slot][lane]      = x[snd*128 + lane];
      s_xs[slot][lane + 64] = x[snd*128 + 64 + lane];
      if (lane < 16) s_sh[slot][lane] = valid ? ea[e*16 + lane] : 0.f;
      __syncthreads();
    }

    // ---- tpw for the wave's 4 slots, Wr4 amortized 4x; w2 = xs*tpw
    float acct[2][4][4];
    #pragma unroll
    for (int cf = 0; cf < 2; ++cf)
      #pragma unroll
      for (int jj = 0; jj < 4; ++jj)
        #pragma unroll
        for (int e4 = 0; e4 < 4; ++e4) acct[cf][jj][e4] = 0.f;

    for (int i = 0; i < 64; ++i){
      const float h0 = s_h3[wave][0][i];
      const float h1 = s_h3[wave][1][i];
      const float h2 = s_h3[wave][2][i];
      const float h3v= s_h3[wave][3][i];
      #pragma unroll
      for (int cf = 0; cf < 2; ++cf){
        const float4 wv = *(const float4*)&Wr4[i*512 + cf*256 + lane*4];
        const float wj[4] = {wv.x, wv.y, wv.z, wv.w};
        #pragma unroll
        for (int jj = 0; jj < 4; ++jj){
          acct[cf][jj][0] += h0 * wj[jj];
          acct[cf][jj][1] += h1 * wj[jj];
          acct[cf][jj][2] += h2 * wj[jj];
          acct[cf][jj][3] += h3v * wj[jj];
        }
      }
    }
    #pragma unroll
    for (int e4 = 0; e4 < 4; ++e4){
      const int slot = wave*4 + e4;
      #pragma unroll
      for (int cf = 0; cf < 2; ++cf){
        const int c0 = cf*256 + lane*4;
        float4 wv;
        wv.x = acct[cf][0][e4] * 0.125f * s_xs[slot][(c0+0) & 127];
        wv.y = acct[cf][1][e4] * 0.125f * s_xs[slot][(c0+1) & 127];
        wv.z = acct[cf][2][e4] * 0.125f * s_xs[slot][(c0+2) & 127];
        wv.w = acct[cf][3][e4] * 0.125f * s_xs[slot][(c0+3) & 127];
        *(float4*)&s_w2[slot][c0] = wv;
      }
    }
    __syncthreads();

    // ---- accumulate the 16 staged edges into registers
    if (h == 0){
      #pragma unroll
      for (int slot = 0; slot < 16; ++slot){
        const float wa = s_w2[slot][u];          // l=0
        const float wb = s_w2[slot][128 + u];    // l=1
        const float wc = s_w2[slot][256 + u];    // l=2
        const float4 sa = *(const float4*)&s_sh[slot][0];
        const float4 sb = *(const float4*)&s_sh[slot][4];
        acc[0] += wa * sa.x;
        acc[1] += wb * sa.y;  acc[2] += wb * sa.z;  acc[3] += wb * sa.w;
        acc[4] += wc * sb.x;  acc[5] += wc * sb.y;
        acc[6] += wc * sb.z;  acc[7] += wc * sb.w;
      }
    } else {
      #pragma unroll
      for (int slot = 0; slot < 16; ++slot){
        const float wc = s_w2[slot][256 + u];    // l=2
        const float wd = s_w2[slot][384 + u];    // l=3
        const float4 sa = *(const float4*)&s_sh[slot][8];
        const float4 sb = *(const float4*)&s_sh[slot][12];
        acc[0] += wc * sa.x;
        acc[1] += wd * sa.y;  acc[2] += wd * sa.z;  acc[3] += wd * sa.w;
        acc[4] += wd * sb.x;  acc[5] += wd * sb.y;
        acc[6] += wd * sb.z;  acc[7] += wd * sb.w;
      }
    }
    __syncthreads();
    if (tid == 0){
      float r = 0.f;
      #pragma unroll
      for (int s2 = 0; s2 < 16; ++s2) r += s_dd[s2];
      s_rho += r;
    }
    __syncthreads();
  }

  // ---- epilogue: normalize, demb, write
  const float rho  = s_rho;
  const float tinv = 1.f / (rho + 1.f);
  if (tid < 16){
    const float fr  = expf(-0.28782313662425572f * (float)tid);  // ln(100)/16
    const float ang = rho * fr;
    s_emb[tid]      = sinf(ang);
    s_emb[tid + 16] = cosf(ang);
  }
  __syncthreads();
  float db = 0.f;
  if (h == 0){
    #pragma unroll
    for (int jj = 0; jj < 32; ++jj) db += s_emb[jj] * Wsin[jj*128 + u];
  }
  #pragma unroll
  for (int j = 0; j < 8; ++j) acc[j] *= tinv;
  if (h == 0) acc[0] += db;

  float* mp = msg + (size_t)n*2048 + u*16 + h*8;
  float4 o1 = {acc[0], acc[1], acc[2], acc[3]};
  float4 o2 = {acc[4], acc[5], acc[6], acc[7]};
  *(float4*)mp       = o1;
  *(float4*)(mp + 4) = o2;
}

// ---------------------------------------------------------------- K5: out_l[(n,k),w] = sum_c z[(n,k),c] * WC_l[c,w]
// z[(n,k), u*10+a] = msg[n, u*16 + OFF + k] * attrs[n,a]
template<int L, int D>
__global__ __launch_bounds__(256) void k_final(const float* __restrict__ msg,
                                               const float* __restrict__ attrs,
                                               const float* __restrict__ WC,
                                               float* __restrict__ out){
  constexpr int OFF  = (L==0 ? 0 : L==1 ? 1 : L==2 ? 4 : 9);
  constexpr int ROWS = N_NODES * D;
  const int r0  = blockIdx.x * 64;
  const int tid = threadIdx.x;
  const int tw  = tid & 31;
  const int tr  = tid >> 5;

  alignas(16) __shared__ float zs[80][64];
  alignas(16) __shared__ float bs[80*128];

  float acc[8][4];
  #pragma unroll
  for (int i = 0; i < 8; ++i)
    #pragma unroll
    for (int j = 0; j < 4; ++j) acc[i][j] = 0.f;

  for (int c0 = 0; c0 < 1280; c0 += 80){
    const float4* src = (const float4*)(WC + ((size_t)L*1280 + c0) * 128);
    float4* dst = (float4*)bs;
    #pragma unroll
    for (int j = 0; j < 10; ++j) dst[tid + j*256] = src[tid + j*256];

    for (int j = tid; j < 80*64; j += 256){
      const int cc = j >> 6, rl = j & 63;
      const int gr = r0 + rl;
      float val = 0.f;
      if (gr < ROWS){
        const int n = gr / D;
        const int k = gr - n*D;
        const int c = c0 + cc;
        const int u = c / 10;
        const int a = c - u*10;
        val = msg[(size_t)n*2048 + u*16 + OFF + k] * attrs[n*10 + a];
      }
      zs[cc][rl] = val;
    }
    __syncthreads();

    for (int cc = 0; cc < 80; ++cc){
      const float4 bv = *(const float4*)&bs[cc*128 + tw*4];
      const float4 za = *(const float4*)&zs[cc][tr*8];
      const float4 zb = *(const float4*)&zs[cc][tr*8 + 4];
      const float zr[8] = {za.x, za.y, za.z, za.w, zb.x, zb.y, zb.z, zb.w};
      #pragma unroll
      for (int i = 0; i < 8; ++i){
        acc[i][0] += zr[i] * bv.x;
        acc[i][1] += zr[i] * bv.y;
        acc[i][2] += zr[i] * bv.z;
        acc[i][3] += zr[i] * bv.w;
      }
    }
    __syncthreads();
  }

  #pragma unroll
  for (int i = 0; i < 8; ++i){
    const int gr = r0 + tr*8 + i;
    if (gr < ROWS){
      const int n = gr / D;
      const int k = gr - n*D;
      float* op = out + (size_t)n*2048 + OFF + k;
      #pragma unroll
      for (int j = 0; j < 4; ++j) op[(tw*4 + j) * 16] = acc[i][j];
    }
  }
}

// ----------------------------------------------------------------
extern "C" void kernel_launch(void* const* d_in, const int* in_sizes, int n_in,
                              void* d_out, int out_size, void* d_ws, size_t ws_size,
                              hipStream_t stream){
  const float* node_attrs = (const float*)d_in[0];
  const float* node_feats = (const float*)d_in[1];
  const float* edge_attrs = (const float*)d_in[2];
  const float* edge_feats = (const float*)d_in[3];
  const int*   edge_index = (const int*)d_in[4];
  const float* W_up  = (const float*)d_in[5];
  const float* Wr1   = (const float*)d_in[6];
  const float* Wr2   = (const float*)d_in[7];
  const float* Wr3   = (const float*)d_in[8];
  const float* Wr4   = (const float*)d_in[9];
  const float* Wd    = (const float*)d_in[10];
  const float* Wsin  = (const float*)d_in[11];
  const float* Wlin  = (const float*)d_in[12];
  const float* Wskip = (const float*)d_in[13];
  float* out = (float*)d_out;

  float* ws    = (float*)d_ws;
  float* msg   = ws;                        // 20,480,000
  float* x     = msg + 20480000;            //  1,280,000
  float* WC    = x   + 1280000;             //    655,360
  int*   cnt   = (int*)(WC + 655360);       //     10,000
  int*   off   = cnt + 10000;               //     10,016
  int*   cur   = off + 10016;               //     10,000
  int*   elist = cur + 10000;               //    160,000

  hipMemsetAsync(cnt, 0, (size_t)10000 * sizeof(int), stream);

  k_node_up<<<N_NODES, 128, 0, stream>>>(node_feats, W_up, x);
  k_wc<<<512, 256, 0, stream>>>(Wlin, Wskip, WC);

  k_count <<<(N_EDGES + 255)/256, 256, 0, stream>>>(edge_index, cnt);
  k_scan  <<<1, 256, 0, stream>>>(cnt, off, cur);
  k_bucket<<<(N_EDGES + 255)/256, 256, 0, stream>>>(edge_index, cur, elist);

  k_gather<<<N_NODES, 256, 0, stream>>>(edge_feats, edge_attrs, edge_index, x,
                                        Wr1, Wr2, Wr3, Wr4, Wd, Wsin,
                                        off, elist, msg);

  k_final<0,1><<<(N_NODES*1 + 63)/64, 256, 0, stream>>>(msg, node_attrs, WC, out);
  k_final<1,3><<<(N_NODES*3 + 63)/64, 256, 0, stream>>>(msg, node_attrs, WC, out);
  k_final<2,5><<<(N_NODES*5 + 63)/64, 256, 0, stream>>>(msg, node_attrs, WC, out);
  k_final<3,7><<<(N_NODES*7 + 63)/64, 256, 0, stream>>>(msg, node_attrs, WC, out);
}

// Round 3
// 954.782 us; speedup vs baseline: 2.4621x; 2.1998x over previous
//
#include <hip/hip_runtime.h>
#include <hip/hip_bf16.h>

#define N_NODES 10000
#define N_EDGES 160000

typedef _Float16 h8 __attribute__((ext_vector_type(8)));
typedef _Float16 h2 __attribute__((ext_vector_type(2)));
typedef float f32x4 __attribute__((ext_vector_type(4)));

__device__ __forceinline__ float silu_f(float v){ return v / (1.f + expf(-v)); }

// ---------------------------------------------------------------- K1: x = nf @ Wup/sqrt(128)
__global__ __launch_bounds__(128) void k_node_up(const float* __restrict__ nf,
                                                 const float* __restrict__ Wup,
                                                 float* __restrict__ x){
  const int n = blockIdx.x, u = threadIdx.x;
  __shared__ float row[128];
  row[u] = nf[n*128 + u];
  __syncthreads();
  float acc = 0.f;
  #pragma unroll 16
  for (int k = 0; k < 128; ++k) acc += row[k] * Wup[k*128 + u];
  x[n*128 + u] = acc * 0.08838834764831843f;   // 1/sqrt(128)
}

// ---------------------------------------------------------------- K1b: WC16T[l][w][a*128+u] = sum_v Wlin[l,u,v]*Wskip[l,v,a,w] * scale (fp16)
__global__ __launch_bounds__(256) void k_wc(const float* __restrict__ Wlin,
                                            const float* __restrict__ Wskip,
                                            _Float16* __restrict__ WC16T){
  const int lu = blockIdx.x;           // l*128 + u
  const int l  = lu >> 7, u = lu & 127;
  __shared__ float wl[128];
  if (threadIdx.x < 128) wl[threadIdx.x] = Wlin[lu*128 + threadIdx.x];
  __syncthreads();
  const float* Wsk = Wskip + (size_t)l * 163840;   // [v][a][w] = v*1280 + a*128 + w
  for (int i = threadIdx.x; i < 1280; i += 256){   // i = a*128 + w
    float acc = 0.f;
    #pragma unroll 16
    for (int v = 0; v < 128; ++v) acc += wl[v] * Wsk[v*1280 + i];
    const int a = i >> 7, w = i & 127;
    WC16T[((size_t)l*128 + w)*1280 + a*128 + u] =
        (_Float16)(acc * 0.0024705294220065465f);  // 1/sqrt(128*1280)
  }
}

// ---------------------------------------------------------------- CSR build
__global__ __launch_bounds__(256) void k_count(const int* __restrict__ eidx,
                                               int* __restrict__ cnt){
  const int e = blockIdx.x * 256 + threadIdx.x;
  if (e < N_EDGES) atomicAdd(&cnt[eidx[N_EDGES + e]], 1);
}

__global__ __launch_bounds__(256) void k_scan(const int* __restrict__ cnt,
                                              int* __restrict__ off,
                                              int* __restrict__ cur){
  __shared__ int sums[256];
  const int t = threadIdx.x;
  const int base = t * 40;
  int s = 0;
  for (int i = 0; i < 40; ++i){
    const int idx = base + i;
    if (idx < N_NODES) s += cnt[idx];
  }
  sums[t] = s;
  __syncthreads();
  for (int st = 1; st < 256; st <<= 1){
    const int v = (t >= st) ? sums[t - st] : 0;
    __syncthreads();
    sums[t] += v;
    __syncthreads();
  }
  int pre = (t > 0) ? sums[t - 1] : 0;
  for (int i = 0; i < 40; ++i){
    const int idx = base + i;
    if (idx < N_NODES){
      off[idx] = pre; cur[idx] = pre;
      pre += cnt[idx];
    }
  }
  if (t == 255) off[N_NODES] = sums[255];
}

__global__ __launch_bounds__(256) void k_bucket(const int* __restrict__ eidx,
                                                int* __restrict__ cur,
                                                int* __restrict__ elist){
  const int e = blockIdx.x * 256 + threadIdx.x;
  if (e < N_EDGES){
    const int pos = atomicAdd(&cur[eidx[N_EDGES + e]], 1);
    elist[pos] = e;
  }
}

// ---------------------------------------------------------------- K2: edge-parallel MLP + tpw + w2 (fp16) + dd
// 256 threads, 32 edges/block, grid 5000
__global__ __launch_bounds__(256) void k_edge_mlp(const float* __restrict__ ef,
                                                  const int*   __restrict__ eidx,
                                                  const float* __restrict__ x,
                                                  const float* __restrict__ Wr1,
                                                  const float* __restrict__ Wr2,
                                                  const float* __restrict__ Wr3,
                                                  const float* __restrict__ Wr4,
                                                  const float* __restrict__ Wd,
                                                  _Float16* __restrict__ w2h,
                                                  float* __restrict__ dd){
  const int tid = threadIdx.x;
  const int E0  = blockIdx.x * 32;

  __shared__ float s_ef[32][9];
  __shared__ float s_W1[8][64];
  __shared__ float s_W23[64][68];
  __shared__ float s_h[32][68];
  __shared__ float s_g[32][68];
  __shared__ float s_h3T[64][40];
  alignas(16) __shared__ float s_xs[32][128];

  // ---- stage ef, W1, W2, xs
  { const int e = tid >> 3, i = tid & 7;
    s_ef[e][i] = ef[(E0 + e)*8 + i]; }
  for (int j = tid; j < 512; j += 256) s_W1[j >> 6][j & 63] = Wr1[j];
  for (int j = tid; j < 4096; j += 256) s_W23[j >> 6][j & 63] = Wr2[j];
  for (int j = tid; j < 4096; j += 256){
    const int e = j >> 7, i = j & 127;
    s_xs[e][i] = x[eidx[E0 + e]*128 + i];
  }
  __syncthreads();

  const int e = tid >> 3, g = tid & 7;   // edge, unit-group

  // ---- dd (32 threads)
  if (tid < 32){
    float s = 0.f;
    #pragma unroll
    for (int i = 0; i < 8; ++i) s += s_ef[tid][i] * Wd[i];
    dd[E0 + tid] = tanhf(s * s);
  }

  // ---- layer 1: h = silu(ef@W1 / sqrt(8))
  {
    float hv[8] = {0,0,0,0,0,0,0,0};
    #pragma unroll
    for (int i = 0; i < 8; ++i){
      const float ev = s_ef[e][i];
      const float4 wa = *(const float4*)&s_W1[i][g*8];
      const float4 wb = *(const float4*)&s_W1[i][g*8 + 4];
      hv[0] += ev*wa.x; hv[1] += ev*wa.y; hv[2] += ev*wa.z; hv[3] += ev*wa.w;
      hv[4] += ev*wb.x; hv[5] += ev*wb.y; hv[6] += ev*wb.z; hv[7] += ev*wb.w;
    }
    float4 o1, o2;
    o1.x = silu_f(hv[0]*0.3535533905932738f); o1.y = silu_f(hv[1]*0.3535533905932738f);
    o1.z = silu_f(hv[2]*0.3535533905932738f); o1.w = silu_f(hv[3]*0.3535533905932738f);
    o2.x = silu_f(hv[4]*0.3535533905932738f); o2.y = silu_f(hv[5]*0.3535533905932738f);
    o2.z = silu_f(hv[6]*0.3535533905932738f); o2.w = silu_f(hv[7]*0.3535533905932738f);
    *(float4*)&s_h[e][g*8]     = o1;
    *(float4*)&s_h[e][g*8 + 4] = o2;
  }
  __syncthreads();

  // ---- layer 2: g = silu(h@W2 / 8)
  {
    float hv[8] = {0,0,0,0,0,0,0,0};
    #pragma unroll 8
    for (int i = 0; i < 64; ++i){
      const float ev = s_h[e][i];
      const float4 wa = *(const float4*)&s_W23[i][g*8];
      const float4 wb = *(const float4*)&s_W23[i][g*8 + 4];
      hv[0] += ev*wa.x; hv[1] += ev*wa.y; hv[2] += ev*wa.z; hv[3] += ev*wa.w;
      hv[4] += ev*wb.x; hv[5] += ev*wb.y; hv[6] += ev*wb.z; hv[7] += ev*wb.w;
    }
    float4 o1, o2;
    o1.x = silu_f(hv[0]*0.125f); o1.y = silu_f(hv[1]*0.125f);
    o1.z = silu_f(hv[2]*0.125f); o1.w = silu_f(hv[3]*0.125f);
    o2.x = silu_f(hv[4]*0.125f); o2.y = silu_f(hv[5]*0.125f);
    o2.z = silu_f(hv[6]*0.125f); o2.w = silu_f(hv[7]*0.125f);
    *(float4*)&s_g[e][g*8]     = o1;
    *(float4*)&s_g[e][g*8 + 4] = o2;
  }
  __syncthreads();
  // restage W3 over W2
  for (int j = tid; j < 4096; j += 256) s_W23[j >> 6][j & 63] = Wr3[j];
  __syncthreads();

  // ---- layer 3: h3 = silu(g@W3 / 8), stored transposed
  {
    float hv[8] = {0,0,0,0,0,0,0,0};
    #pragma unroll 8
    for (int i = 0; i < 64; ++i){
      const float ev = s_g[e][i];
      const float4 wa = *(const float4*)&s_W23[i][g*8];
      const float4 wb = *(const float4*)&s_W23[i][g*8 + 4];
      hv[0] += ev*wa.x; hv[1] += ev*wa.y; hv[2] += ev*wa.z; hv[3] += ev*wa.w;
      hv[4] += ev*wb.x; hv[5] += ev*wb.y; hv[6] += ev*wb.z; hv[7] += ev*wb.w;
    }
    #pragma unroll
    for (int j = 0; j < 8; ++j) s_h3T[g*8 + j][e] = silu_f(hv[j]*0.125f);
  }
  __syncthreads();

  // ---- tpw = h3@W4/8; w2 = xs*tpw (fp16 out). thread: eh=tid>>6 (8 edges), ch=tid&63 (8 c's)
  {
    const int eh = tid >> 6, ch = tid & 63;
    const int c0 = ch * 8;
    float acc[8][8];   // [je][jc]
    #pragma unroll
    for (int a = 0; a < 8; ++a)
      #pragma unroll
      for (int b = 0; b < 8; ++b) acc[a][b] = 0.f;

    for (int i = 0; i < 64; ++i){
      const float4 wv0 = *(const float4*)&Wr4[i*512 + c0];
      const float4 wv1 = *(const float4*)&Wr4[i*512 + c0 + 4];
      const float4 ha  = *(const float4*)&s_h3T[i][eh*8];
      const float4 hb  = *(const float4*)&s_h3T[i][eh*8 + 4];
      const float hv[8] = {ha.x, ha.y, ha.z, ha.w, hb.x, hb.y, hb.z, hb.w};
      #pragma unroll
      for (int je = 0; je < 8; ++je){
        acc[je][0] += hv[je]*wv0.x; acc[je][1] += hv[je]*wv0.y;
        acc[je][2] += hv[je]*wv0.z; acc[je][3] += hv[je]*wv0.w;
        acc[je][4] += hv[je]*wv1.x; acc[je][5] += hv[je]*wv1.y;
        acc[je][6] += hv[je]*wv1.z; acc[je][7] += hv[je]*wv1.w;
      }
    }
    const int u0 = c0 & 127;
    #pragma unroll
    for (int je = 0; je < 8; ++je){
      const int ee = eh*8 + je;
      const float4 xa = *(const float4*)&s_xs[ee][u0];
      const float4 xb = *(const float4*)&s_xs[ee][u0 + 4];
      const float xv[8] = {xa.x, xa.y, xa.z, xa.w, xb.x, xb.y, xb.z, xb.w};
      h8 ov;
      #pragma unroll
      for (int jc = 0; jc < 8; ++jc)
        ov[jc] = (_Float16)(acc[je][jc] * 0.125f * xv[jc]);
      *(h8*)&w2h[(size_t)(E0 + ee)*512 + c0] = ov;
    }
  }
}

// ---------------------------------------------------------------- K3: gather per node (CSR), register accumulate, fused rho/demb
__global__ __launch_bounds__(256) void k_gather(const float* __restrict__ ea,
                                                const _Float16* __restrict__ w2h,
                                                const float* __restrict__ dd,
                                                const float* __restrict__ Wsin,
                                                const int* __restrict__ off,
                                                const int* __restrict__ elist,
                                                float* __restrict__ msg){
  const int n = blockIdx.x, tid = threadIdx.x;
  const int beg = off[n], end = off[n + 1];
  const int ngrp = (end - beg + 15) >> 4;

  alignas(16) __shared__ _Float16 s_w2[16][512];
  alignas(16) __shared__ float s_sh[16][16];
  __shared__ float s_dd[16];
  __shared__ int   s_el[16];
  __shared__ float s_emb[32];
  __shared__ float s_rho;
  if (tid == 0) s_rho = 0.f;

  const int u = tid & 127, h = tid >> 7;
  float acc[8] = {0,0,0,0,0,0,0,0};

  for (int grp = 0; grp < ngrp; ++grp){
    if (tid < 16){
      const int p = beg + grp*16 + tid;
      s_el[tid] = (p < end) ? elist[p] : -1;
    }
    __syncthreads();
    #pragma unroll
    for (int c2 = 0; c2 < 4; ++c2){
      const int chunk = c2*256 + tid;
      const int slot = chunk >> 6, part = chunk & 63;
      const int e = s_el[slot];
      h8 v = {};
      if (e >= 0) v = *(const h8*)&w2h[(size_t)e*512 + part*8];
      *(h8*)&s_w2[slot][part*8] = v;
    }
    { const int slot = tid >> 4, j = tid & 15;
      const int e = s_el[slot];
      s_sh[slot][j] = (e >= 0) ? ea[e*16 + j] : 0.f; }
    if (tid < 16){
      const int e = s_el[tid];
      s_dd[tid] = (e >= 0) ? dd[e] : 0.f;
    }
    __syncthreads();

    if (h == 0){
      #pragma unroll
      for (int slot = 0; slot < 16; ++slot){
        const float wa = (float)s_w2[slot][u];
        const float wb = (float)s_w2[slot][128 + u];
        const float wc = (float)s_w2[slot][256 + u];
        const float4 sa = *(const float4*)&s_sh[slot][0];
        const float4 sb = *(const float4*)&s_sh[slot][4];
        acc[0] += wa * sa.x;
        acc[1] += wb * sa.y;  acc[2] += wb * sa.z;  acc[3] += wb * sa.w;
        acc[4] += wc * sb.x;  acc[5] += wc * sb.y;
        acc[6] += wc * sb.z;  acc[7] += wc * sb.w;
      }
    } else {
      #pragma unroll
      for (int slot = 0; slot < 16; ++slot){
        const float wc = (float)s_w2[slot][256 + u];
        const float wd = (float)s_w2[slot][384 + u];
        const float4 sa = *(const float4*)&s_sh[slot][8];
        const float4 sb = *(const float4*)&s_sh[slot][12];
        acc[0] += wc * sa.x;
        acc[1] += wd * sa.y;  acc[2] += wd * sa.z;  acc[3] += wd * sa.w;
        acc[4] += wd * sb.x;  acc[5] += wd * sb.y;
        acc[6] += wd * sb.z;  acc[7] += wd * sb.w;
      }
    }
    if (tid == 0){
      float r = 0.f;
      #pragma unroll
      for (int s2 = 0; s2 < 16; ++s2) r += s_dd[s2];
      s_rho += r;
    }
    __syncthreads();
  }

  // ---- epilogue: rho, tinv, demb, write msg[n][sk][u]
  const float rho  = s_rho;
  const float tinv = 1.f / (rho + 1.f);
  if (tid < 16){
    const float fr  = expf(-0.28782313662425572f * (float)tid);  // ln(100)/16
    const float ang = rho * fr;
    s_emb[tid]      = sinf(ang);
    s_emb[tid + 16] = cosf(ang);
  }
  __syncthreads();
  float db = 0.f;
  if (h == 0){
    #pragma unroll
    for (int j = 0; j < 32; ++j) db += s_emb[j] * Wsin[j*128 + u];
  }
  #pragma unroll
  for (int j = 0; j < 8; ++j){
    float v = acc[j] * tinv;
    if (h == 0 && j == 0) v += db;
    msg[(size_t)n*2048 + (h*8 + j)*128 + u] = v;
  }
}

// ---------------------------------------------------------------- K4: fused final GEMM via fp16 MFMA
// block = 16 nodes x all 16 sk rows; 512 threads = 8 waves, wave w: sk {2w, 2w+1}
__global__ __launch_bounds__(512) void k_final(const float* __restrict__ msg,
                                               const float* __restrict__ attrs,
                                               const _Float16* __restrict__ WC16T,
                                               float* __restrict__ out){
  const int tid = threadIdx.x;
  const int n0  = blockIdx.x * 16;

  alignas(16) __shared__ _Float16 zsh[16 * 2088];   // [n][sk*128+u], stride 2088
  __shared__ _Float16 attrh[16][16];

  // stage msg -> fp16 LDS
  {
    const int n = tid >> 5, q = tid & 31;
    const float2* src = (const float2*)(msg + (size_t)(n0 + n) * 2048);
    #pragma unroll
    for (int i = 0; i < 32; ++i){
      const float2 v = src[i*32 + q];
      h2 p; p[0] = (_Float16)v.x; p[1] = (_Float16)v.y;
      *(h2*)&zsh[n*2088 + (i*32 + q)*2] = p;
    }
  }
  if (tid < 160) attrh[tid/10][tid - (tid/10)*10] = (_Float16)attrs[n0*10 + tid];
  __syncthreads();

  const int wid = tid >> 6, lane = tid & 63;
  const int nl = lane & 15, kg = lane >> 4;
  const int skA = wid*2, skB = skA + 1;
  const int lA = (skA == 0) ? 0 : (skA < 4 ? 1 : (skA < 9 ? 2 : 3));
  const int lB = (skB < 4) ? 1 : (skB < 9 ? 2 : 3);
  const bool same = (lA == lB);
  const _Float16* __restrict__ BA = WC16T + (size_t)lA * 163840;
  const _Float16* __restrict__ BB = WC16T + (size_t)lB * 163840;

  f32x4 accA[8], accB[8];
  #pragma unroll
  for (int i = 0; i < 8; ++i){ accA[i] = (f32x4){0,0,0,0}; accB[i] = (f32x4){0,0,0,0}; }

  for (int c0 = 0; c0 < 1280; c0 += 32){
    const int a  = c0 >> 7;
    const int u0 = (c0 & 127) + (kg << 3);
    const h8 mA = *(const h8*)&zsh[nl*2088 + skA*128 + u0];
    const h8 mB = *(const h8*)&zsh[nl*2088 + skB*128 + u0];
    const _Float16 av = attrh[nl][a];
    h8 avv;
    #pragma unroll
    for (int j = 0; j < 8; ++j) avv[j] = av;
    const h8 zA = mA * avv;
    const h8 zB = mB * avv;
    const int boff = c0 + (kg << 3);
    #pragma unroll
    for (int nt = 0; nt < 8; ++nt){
      const h8 bA = *(const h8*)&BA[(size_t)(nt*16 + nl)*1280 + boff];
      accA[nt] = __builtin_amdgcn_mfma_f32_16x16x32_f16(zA, bA, accA[nt], 0, 0, 0);
      const h8 bB = same ? bA : *(const h8*)&BB[(size_t)(nt*16 + nl)*1280 + boff];
      accB[nt] = __builtin_amdgcn_mfma_f32_16x16x32_f16(zB, bB, accB[nt], 0, 0, 0);
    }
  }

  // epilogue: D frag: col = lane&15 (w within tile), row = kg*4 + r (node local)
  #pragma unroll
  for (int nt = 0; nt < 8; ++nt){
    const int w = nt*16 + nl;
    #pragma unroll
    for (int r = 0; r < 4; ++r){
      const size_t base = (size_t)(n0 + kg*4 + r)*2048 + w*16;
      out[base + skA] = accA[nt][r];
      out[base + skB] = accB[nt][r];
    }
  }
}

// ----------------------------------------------------------------
extern "C" void kernel_launch(void* const* d_in, const int* in_sizes, int n_in,
                              void* d_out, int out_size, void* d_ws, size_t ws_size,
                              hipStream_t stream){
  const float* node_attrs = (const float*)d_in[0];
  const float* node_feats = (const float*)d_in[1];
  const float* edge_attrs = (const float*)d_in[2];
  const float* edge_feats = (const float*)d_in[3];
  const int*   edge_index = (const int*)d_in[4];
  const float* W_up  = (const float*)d_in[5];
  const float* Wr1   = (const float*)d_in[6];
  const float* Wr2   = (const float*)d_in[7];
  const float* Wr3   = (const float*)d_in[8];
  const float* Wr4   = (const float*)d_in[9];
  const float* Wd    = (const float*)d_in[10];
  const float* Wsin  = (const float*)d_in[11];
  const float* Wlin  = (const float*)d_in[12];
  const float* Wskip = (const float*)d_in[13];
  float* out = (float*)d_out;

  _Float16* w2h  = (_Float16*)d_ws;                 // 81,920,000 halfs
  float* msg     = (float*)(w2h + 81920000);        // 20,480,000 f32
  float* x       = msg + 20480000;                  //  1,280,000 f32
  float* ddv     = x + 1280000;                     //    160,000 f32
  _Float16* WC16T= (_Float16*)(ddv + 160000);       //    655,360 halfs
  int* cnt   = (int*)(WC16T + 655360);              //     10,000
  int* off   = cnt + 10000;                         //     10,016
  int* cur   = off + 10016;                         //     10,000
  int* elist = cur + 10000;                         //    160,000

  hipMemsetAsync(cnt, 0, (size_t)10000 * sizeof(int), stream);

  k_node_up<<<N_NODES, 128, 0, stream>>>(node_feats, W_up, x);
  k_wc<<<512, 256, 0, stream>>>(Wlin, Wskip, WC16T);

  k_count <<<(N_EDGES + 255)/256, 256, 0, stream>>>(edge_index, cnt);
  k_scan  <<<1, 256, 0, stream>>>(cnt, off, cur);
  k_bucket<<<(N_EDGES + 255)/256, 256, 0, stream>>>(edge_index, cur, elist);

  k_edge_mlp<<<N_EDGES/32, 256, 0, stream>>>(edge_feats, edge_index, x,
                                             Wr1, Wr2, Wr3, Wr4, Wd, w2h, ddv);

  k_gather<<<N_NODES, 256, 0, stream>>>(edge_attrs, w2h, ddv, Wsin,
                                        off, elist, msg);

  k_final<<<N_NODES/16, 512, 0, stream>>>(msg, node_attrs, WC16T, out);
}

// Round 4
// 723.850 us; speedup vs baseline: 3.2477x; 1.3190x over previous
//
#include <hip/hip_runtime.h>
#include <hip/hip_bf16.h>

#define N_NODES 10000
#define N_EDGES 160000

typedef _Float16 h8 __attribute__((ext_vector_type(8)));
typedef _Float16 h2 __attribute__((ext_vector_type(2)));
typedef float f32x4 __attribute__((ext_vector_type(4)));

__device__ __forceinline__ float silu_f(float v){ return v / (1.f + expf(-v)); }

// ---------------------------------------------------------------- K1: x = nf @ Wup/sqrt(128)
__global__ __launch_bounds__(128) void k_node_up(const float* __restrict__ nf,
                                                 const float* __restrict__ Wup,
                                                 float* __restrict__ x){
  const int n = blockIdx.x, u = threadIdx.x;
  __shared__ float row[128];
  row[u] = nf[n*128 + u];
  __syncthreads();
  float acc = 0.f;
  #pragma unroll 16
  for (int k = 0; k < 128; ++k) acc += row[k] * Wup[k*128 + u];
  x[n*128 + u] = acc * 0.08838834764831843f;   // 1/sqrt(128)
}

// ---------------------------------------------------------------- K1b: WC16T[l][w][a*128+u] = sum_v Wlin[l,u,v]*Wskip[l,v,a,w] * scale (fp16)
__global__ __launch_bounds__(256) void k_wc(const float* __restrict__ Wlin,
                                            const float* __restrict__ Wskip,
                                            _Float16* __restrict__ WC16T){
  const int lu = blockIdx.x;           // l*128 + u
  const int l  = lu >> 7, u = lu & 127;
  __shared__ float wl[128];
  if (threadIdx.x < 128) wl[threadIdx.x] = Wlin[lu*128 + threadIdx.x];
  __syncthreads();
  const float* Wsk = Wskip + (size_t)l * 163840;   // [v][a][w] = v*1280 + a*128 + w
  for (int i = threadIdx.x; i < 1280; i += 256){   // i = a*128 + w
    float acc = 0.f;
    #pragma unroll 16
    for (int v = 0; v < 128; ++v) acc += wl[v] * Wsk[v*1280 + i];
    const int a = i >> 7, w = i & 127;
    WC16T[((size_t)l*128 + w)*1280 + a*128 + u] =
        (_Float16)(acc * 0.0024705294220065465f);  // 1/sqrt(128*1280)
  }
}

// ---------------------------------------------------------------- CSR build
__global__ __launch_bounds__(256) void k_count(const int* __restrict__ eidx,
                                               int* __restrict__ cnt){
  const int e = blockIdx.x * 256 + threadIdx.x;
  if (e < N_EDGES) atomicAdd(&cnt[eidx[N_EDGES + e]], 1);
}

__global__ __launch_bounds__(256) void k_scan(const int* __restrict__ cnt,
                                              int* __restrict__ off,
                                              int* __restrict__ cur){
  __shared__ int sums[256];
  const int t = threadIdx.x;
  const int base = t * 40;
  int s = 0;
  for (int i = 0; i < 40; ++i){
    const int idx = base + i;
    if (idx < N_NODES) s += cnt[idx];
  }
  sums[t] = s;
  __syncthreads();
  for (int st = 1; st < 256; st <<= 1){
    const int v = (t >= st) ? sums[t - st] : 0;
    __syncthreads();
    sums[t] += v;
    __syncthreads();
  }
  int pre = (t > 0) ? sums[t - 1] : 0;
  for (int i = 0; i < 40; ++i){
    const int idx = base + i;
    if (idx < N_NODES){
      off[idx] = pre; cur[idx] = pre;
      pre += cnt[idx];
    }
  }
  if (t == 255) off[N_NODES] = sums[255];
}

__global__ __launch_bounds__(256) void k_bucket(const int* __restrict__ eidx,
                                                int* __restrict__ cur,
                                                int* __restrict__ elist){
  const int e = blockIdx.x * 256 + threadIdx.x;
  if (e < N_EDGES){
    const int pos = atomicAdd(&cur[eidx[N_EDGES + e]], 1);
    elist[pos] = e;
  }
}

// ---------------------------------------------------------------- K2: edge-parallel MLP + tpw + w2 (fp16) + dd
// 256 threads, 32 edges/block, grid 5000
__global__ __launch_bounds__(256) void k_edge_mlp(const float* __restrict__ ef,
                                                  const int*   __restrict__ eidx,
                                                  const float* __restrict__ x,
                                                  const float* __restrict__ Wr1,
                                                  const float* __restrict__ Wr2,
                                                  const float* __restrict__ Wr3,
                                                  const float* __restrict__ Wr4,
                                                  const float* __restrict__ Wd,
                                                  _Float16* __restrict__ w2h,
                                                  float* __restrict__ dd){
  const int tid = threadIdx.x;
  const int E0  = blockIdx.x * 32;

  __shared__ float s_ef[32][9];
  __shared__ float s_W1[8][64];
  __shared__ float s_W23[64][68];
  __shared__ float s_h[32][68];
  __shared__ float s_g[32][68];
  __shared__ float s_h3T[64][40];
  alignas(16) __shared__ float s_xs[32][128];

  // ---- stage ef, W1, W2, xs
  { const int e = tid >> 3, i = tid & 7;
    s_ef[e][i] = ef[(E0 + e)*8 + i]; }
  for (int j = tid; j < 512; j += 256) s_W1[j >> 6][j & 63] = Wr1[j];
  for (int j = tid; j < 4096; j += 256) s_W23[j >> 6][j & 63] = Wr2[j];
  for (int j = tid; j < 4096; j += 256){
    const int e = j >> 7, i = j & 127;
    s_xs[e][i] = x[eidx[E0 + e]*128 + i];
  }
  __syncthreads();

  const int e = tid >> 3, g = tid & 7;   // edge, unit-group

  // ---- dd (32 threads)
  if (tid < 32){
    float s = 0.f;
    #pragma unroll
    for (int i = 0; i < 8; ++i) s += s_ef[tid][i] * Wd[i];
    dd[E0 + tid] = tanhf(s * s);
  }

  // ---- layer 1: h = silu(ef@W1 / sqrt(8))
  {
    float hv[8] = {0,0,0,0,0,0,0,0};
    #pragma unroll
    for (int i = 0; i < 8; ++i){
      const float ev = s_ef[e][i];
      const float4 wa = *(const float4*)&s_W1[i][g*8];
      const float4 wb = *(const float4*)&s_W1[i][g*8 + 4];
      hv[0] += ev*wa.x; hv[1] += ev*wa.y; hv[2] += ev*wa.z; hv[3] += ev*wa.w;
      hv[4] += ev*wb.x; hv[5] += ev*wb.y; hv[6] += ev*wb.z; hv[7] += ev*wb.w;
    }
    float4 o1, o2;
    o1.x = silu_f(hv[0]*0.3535533905932738f); o1.y = silu_f(hv[1]*0.3535533905932738f);
    o1.z = silu_f(hv[2]*0.3535533905932738f); o1.w = silu_f(hv[3]*0.3535533905932738f);
    o2.x = silu_f(hv[4]*0.3535533905932738f); o2.y = silu_f(hv[5]*0.3535533905932738f);
    o2.z = silu_f(hv[6]*0.3535533905932738f); o2.w = silu_f(hv[7]*0.3535533905932738f);
    *(float4*)&s_h[e][g*8]     = o1;
    *(float4*)&s_h[e][g*8 + 4] = o2;
  }
  __syncthreads();

  // ---- layer 2: g = silu(h@W2 / 8)
  {
    float hv[8] = {0,0,0,0,0,0,0,0};
    #pragma unroll 8
    for (int i = 0; i < 64; ++i){
      const float ev = s_h[e][i];
      const float4 wa = *(const float4*)&s_W23[i][g*8];
      const float4 wb = *(const float4*)&s_W23[i][g*8 + 4];
      hv[0] += ev*wa.x; hv[1] += ev*wa.y; hv[2] += ev*wa.z; hv[3] += ev*wa.w;
      hv[4] += ev*wb.x; hv[5] += ev*wb.y; hv[6] += ev*wb.z; hv[7] += ev*wb.w;
    }
    float4 o1, o2;
    o1.x = silu_f(hv[0]*0.125f); o1.y = silu_f(hv[1]*0.125f);
    o1.z = silu_f(hv[2]*0.125f); o1.w = silu_f(hv[3]*0.125f);
    o2.x = silu_f(hv[4]*0.125f); o2.y = silu_f(hv[5]*0.125f);
    o2.z = silu_f(hv[6]*0.125f); o2.w = silu_f(hv[7]*0.125f);
    *(float4*)&s_g[e][g*8]     = o1;
    *(float4*)&s_g[e][g*8 + 4] = o2;
  }
  __syncthreads();
  // restage W3 over W2
  for (int j = tid; j < 4096; j += 256) s_W23[j >> 6][j & 63] = Wr3[j];
  __syncthreads();

  // ---- layer 3: h3 = silu(g@W3 / 8), stored transposed
  {
    float hv[8] = {0,0,0,0,0,0,0,0};
    #pragma unroll 8
    for (int i = 0; i < 64; ++i){
      const float ev = s_g[e][i];
      const float4 wa = *(const float4*)&s_W23[i][g*8];
      const float4 wb = *(const float4*)&s_W23[i][g*8 + 4];
      hv[0] += ev*wa.x; hv[1] += ev*wa.y; hv[2] += ev*wa.z; hv[3] += ev*wa.w;
      hv[4] += ev*wb.x; hv[5] += ev*wb.y; hv[6] += ev*wb.z; hv[7] += ev*wb.w;
    }
    #pragma unroll
    for (int j = 0; j < 8; ++j) s_h3T[g*8 + j][e] = silu_f(hv[j]*0.125f);
  }
  __syncthreads();

  // ---- tpw = h3@W4/8; w2 = xs*tpw (fp16 out). thread: eh=tid>>6 (8 edges), ch=tid&63 (8 c's)
  {
    const int eh = tid >> 6, ch = tid & 63;
    const int c0 = ch * 8;
    float acc[8][8];   // [je][jc]
    #pragma unroll
    for (int a = 0; a < 8; ++a)
      #pragma unroll
      for (int b = 0; b < 8; ++b) acc[a][b] = 0.f;

    for (int i = 0; i < 64; ++i){
      const float4 wv0 = *(const float4*)&Wr4[i*512 + c0];
      const float4 wv1 = *(const float4*)&Wr4[i*512 + c0 + 4];
      const float4 ha  = *(const float4*)&s_h3T[i][eh*8];
      const float4 hb  = *(const float4*)&s_h3T[i][eh*8 + 4];
      const float hv[8] = {ha.x, ha.y, ha.z, ha.w, hb.x, hb.y, hb.z, hb.w};
      #pragma unroll
      for (int je = 0; je < 8; ++je){
        acc[je][0] += hv[je]*wv0.x; acc[je][1] += hv[je]*wv0.y;
        acc[je][2] += hv[je]*wv0.z; acc[je][3] += hv[je]*wv0.w;
        acc[je][4] += hv[je]*wv1.x; acc[je][5] += hv[je]*wv1.y;
        acc[je][6] += hv[je]*wv1.z; acc[je][7] += hv[je]*wv1.w;
      }
    }
    const int u0 = c0 & 127;
    #pragma unroll
    for (int je = 0; je < 8; ++je){
      const int ee = eh*8 + je;
      const float4 xa = *(const float4*)&s_xs[ee][u0];
      const float4 xb = *(const float4*)&s_xs[ee][u0 + 4];
      const float xv[8] = {xa.x, xa.y, xa.z, xa.w, xb.x, xb.y, xb.z, xb.w};
      h8 ov;
      #pragma unroll
      for (int jc = 0; jc < 8; ++jc)
        ov[jc] = (_Float16)(acc[je][jc] * 0.125f * xv[jc]);
      *(h8*)&w2h[(size_t)(E0 + ee)*512 + c0] = ov;
    }
  }
}

// ---------------------------------------------------------------- K3: gather per node (CSR), register accumulate, fused rho/demb
__global__ __launch_bounds__(256) void k_gather(const float* __restrict__ ea,
                                                const _Float16* __restrict__ w2h,
                                                const float* __restrict__ dd,
                                                const float* __restrict__ Wsin,
                                                const int* __restrict__ off,
                                                const int* __restrict__ elist,
                                                float* __restrict__ msg){
  const int n = blockIdx.x, tid = threadIdx.x;
  const int beg = off[n], end = off[n + 1];
  const int ngrp = (end - beg + 15) >> 4;

  alignas(16) __shared__ _Float16 s_w2[16][512];
  alignas(16) __shared__ float s_sh[16][16];
  __shared__ float s_dd[16];
  __shared__ int   s_el[16];
  __shared__ float s_emb[32];
  __shared__ float s_rho;
  if (tid == 0) s_rho = 0.f;

  const int u = tid & 127, h = tid >> 7;
  float acc[8] = {0,0,0,0,0,0,0,0};

  for (int grp = 0; grp < ngrp; ++grp){
    if (tid < 16){
      const int p = beg + grp*16 + tid;
      s_el[tid] = (p < end) ? elist[p] : -1;
    }
    __syncthreads();
    #pragma unroll
    for (int c2 = 0; c2 < 4; ++c2){
      const int chunk = c2*256 + tid;
      const int slot = chunk >> 6, part = chunk & 63;
      const int e = s_el[slot];
      h8 v = {};
      if (e >= 0) v = *(const h8*)&w2h[(size_t)e*512 + part*8];
      *(h8*)&s_w2[slot][part*8] = v;
    }
    { const int slot = tid >> 4, j = tid & 15;
      const int e = s_el[slot];
      s_sh[slot][j] = (e >= 0) ? ea[e*16 + j] : 0.f; }
    if (tid < 16){
      const int e = s_el[tid];
      s_dd[tid] = (e >= 0) ? dd[e] : 0.f;
    }
    __syncthreads();

    if (h == 0){
      #pragma unroll
      for (int slot = 0; slot < 16; ++slot){
        const float wa = (float)s_w2[slot][u];
        const float wb = (float)s_w2[slot][128 + u];
        const float wc = (float)s_w2[slot][256 + u];
        const float4 sa = *(const float4*)&s_sh[slot][0];
        const float4 sb = *(const float4*)&s_sh[slot][4];
        acc[0] += wa * sa.x;
        acc[1] += wb * sa.y;  acc[2] += wb * sa.z;  acc[3] += wb * sa.w;
        acc[4] += wc * sb.x;  acc[5] += wc * sb.y;
        acc[6] += wc * sb.z;  acc[7] += wc * sb.w;
      }
    } else {
      #pragma unroll
      for (int slot = 0; slot < 16; ++slot){
        const float wc = (float)s_w2[slot][256 + u];
        const float wd = (float)s_w2[slot][384 + u];
        const float4 sa = *(const float4*)&s_sh[slot][8];
        const float4 sb = *(const float4*)&s_sh[slot][12];
        acc[0] += wc * sa.x;
        acc[1] += wd * sa.y;  acc[2] += wd * sa.z;  acc[3] += wd * sa.w;
        acc[4] += wd * sb.x;  acc[5] += wd * sb.y;
        acc[6] += wd * sb.z;  acc[7] += wd * sb.w;
      }
    }
    if (tid == 0){
      float r = 0.f;
      #pragma unroll
      for (int s2 = 0; s2 < 16; ++s2) r += s_dd[s2];
      s_rho += r;
    }
    __syncthreads();
  }

  // ---- epilogue: rho, tinv, demb, write msg[n][sk][u]
  const float rho  = s_rho;
  const float tinv = 1.f / (rho + 1.f);
  if (tid < 16){
    const float fr  = expf(-0.28782313662425572f * (float)tid);  // ln(100)/16
    const float ang = rho * fr;
    s_emb[tid]      = sinf(ang);
    s_emb[tid + 16] = cosf(ang);
  }
  __syncthreads();
  float db = 0.f;
  if (h == 0){
    #pragma unroll
    for (int j = 0; j < 32; ++j) db += s_emb[j] * Wsin[j*128 + u];
  }
  #pragma unroll
  for (int j = 0; j < 8; ++j){
    float v = acc[j] * tinv;
    if (h == 0 && j == 0) v += db;
    msg[(size_t)n*2048 + (h*8 + j)*128 + u] = v;
  }
}

// ---------------------------------------------------------------- K4: final GEMM, 128x128 LDS-staged MFMA tile per l
// rows r = n*D + k; A[r][c=a*128+u] = fp16(msg[n][OFF+k][u]) * fp16(attr[n][a])
// B^T[w][c] = WC16T[l][w][a*128+u]; out[n*2048 + w*16 + OFF + k]
template<int L, int D>
__global__ __launch_bounds__(256) void k_final(const float* __restrict__ msg,
                                               const float* __restrict__ attrs,
                                               const _Float16* __restrict__ WC16T,
                                               float* __restrict__ out){
  constexpr int OFF  = (L==0 ? 0 : L==1 ? 1 : L==2 ? 4 : 9);
  constexpr int ROWS = N_NODES * D;
  const int r0  = blockIdx.x * 128;
  const int tid = threadIdx.x;

  alignas(16) __shared__ _Float16 sA[128*128];     // [row][u], chunk-XOR swizzled
  alignas(16) __shared__ _Float16 sB[2][64*128];   // [buf][w][cc], chunk-XOR swizzled
  __shared__ _Float16 sAttr[128*10];

  // ---- stage A panel (once) ----
  {
    const int rl = tid >> 1, half = tid & 1;
    const int gr = r0 + rl;
    h8 vals[8];
    if (gr < ROWS){
      const int n = gr / D, k = gr - n*D;
      const float4* src = (const float4*)(msg + (size_t)n*2048 + (size_t)(OFF+k)*128 + half*64);
      #pragma unroll
      for (int j = 0; j < 8; ++j){
        const float4 v0 = src[j*2], v1 = src[j*2+1];
        h8 hv;
        hv[0]=(_Float16)v0.x; hv[1]=(_Float16)v0.y; hv[2]=(_Float16)v0.z; hv[3]=(_Float16)v0.w;
        hv[4]=(_Float16)v1.x; hv[5]=(_Float16)v1.y; hv[6]=(_Float16)v1.z; hv[7]=(_Float16)v1.w;
        vals[j] = hv;
      }
    } else {
      #pragma unroll
      for (int j = 0; j < 8; ++j) vals[j] = (h8){};
    }
    #pragma unroll
    for (int j = 0; j < 8; ++j){
      const int cu = half*8 + j;
      const int cs = (cu & 8) | ((cu & 7) ^ (rl & 7));
      *(h8*)&sA[rl*128 + cs*8] = vals[j];
    }
  }
  // ---- stage attrs per row ----
  for (int i = tid; i < 1280; i += 256){
    const int rl = i / 10, aa = i - rl*10;
    const int gr = r0 + rl;
    sAttr[i] = (gr < ROWS) ? (_Float16)attrs[(gr / D)*10 + aa] : (_Float16)0.f;
  }
  // ---- stage B chunk 0 ----
  {
    const int w = tid >> 1, part = tid & 1;
    const _Float16* src = WC16T + ((size_t)L*128 + w)*1280 + part*32;
    #pragma unroll
    for (int j = 0; j < 4; ++j){
      const h8 v = *(const h8*)(src + j*8);
      const int cc = part*4 + j;
      *(h8*)&sB[0][w*64 + (cc ^ (w & 7))*8] = v;
    }
  }
  __syncthreads();

  const int wid = tid >> 6, lane = tid & 63;
  const int wm = wid >> 1, wn = wid & 1;
  const int li = lane & 15, kg = lane >> 4;

  f32x4 acc[4][4];
  #pragma unroll
  for (int m = 0; m < 4; ++m)
    #pragma unroll
    for (int nn = 0; nn < 4; ++nn) acc[m][nn] = (f32x4){0,0,0,0};

  for (int step = 0; step < 20; ++step){
    const int cur = step & 1;
    const bool more = (step + 1 < 20);
    // prefetch next B chunk into regs (write-late after MFMA)
    h8 pre[4];
    if (more){
      const int a2 = (step+1) >> 1, u02 = ((step+1) & 1) << 6;
      const _Float16* src = WC16T + ((size_t)L*128 + (tid>>1))*1280 + a2*128 + u02 + (tid&1)*32;
      #pragma unroll
      for (int j = 0; j < 4; ++j) pre[j] = *(const h8*)(src + j*8);
    }

    const int a  = step >> 1;
    const int uh = (step & 1) << 3;   // chunk base within A row (0 or 8)

    h8 afr[4][2], bfr[4][2];
    #pragma unroll
    for (int m = 0; m < 4; ++m){
      const int row = wm*64 + m*16 + li;
      const _Float16 av = sAttr[row*10 + a];
      h8 avx;
      #pragma unroll
      for (int j = 0; j < 8; ++j) avx[j] = av;
      #pragma unroll
      for (int s = 0; s < 2; ++s){
        const int ca = uh + s*4 + kg;
        const int cs = (ca & 8) | ((ca & 7) ^ (row & 7));
        const h8 mA = *(const h8*)&sA[row*128 + cs*8];
        afr[m][s] = mA * avx;
      }
    }
    #pragma unroll
    for (int nn = 0; nn < 4; ++nn){
      const int w = wn*64 + nn*16 + li;
      #pragma unroll
      for (int s = 0; s < 2; ++s){
        const int cb = s*4 + kg;
        bfr[nn][s] = *(const h8*)&sB[cur][w*64 + ((cb ^ (w & 7)))*8];
      }
    }
    #pragma unroll
    for (int s = 0; s < 2; ++s)
      #pragma unroll
      for (int m = 0; m < 4; ++m)
        #pragma unroll
        for (int nn = 0; nn < 4; ++nn)
          acc[m][nn] = __builtin_amdgcn_mfma_f32_16x16x32_f16(afr[m][s], bfr[nn][s], acc[m][nn], 0, 0, 0);

    if (more){
      const int w = tid >> 1, part = tid & 1;
      #pragma unroll
      for (int j = 0; j < 4; ++j){
        const int cc = part*4 + j;
        *(h8*)&sB[cur ^ 1][w*64 + (cc ^ (w & 7))*8] = pre[j];
      }
    }
    __syncthreads();
  }

  // ---- epilogue: D frag col = li (w within 16-tile), row = kg*4 + rr ----
  #pragma unroll
  for (int m = 0; m < 4; ++m){
    const int rbase = r0 + wm*64 + m*16 + kg*4;
    #pragma unroll
    for (int rr = 0; rr < 4; ++rr){
      const int gr = rbase + rr;
      if (gr < ROWS){
        const int n = gr / D, k = gr - n*D;
        float* op = out + (size_t)n*2048 + OFF + k;
        #pragma unroll
        for (int nn = 0; nn < 4; ++nn){
          const int w = wn*64 + nn*16 + li;
          op[w*16] = acc[m][nn][rr];
        }
      }
    }
  }
}

// ----------------------------------------------------------------
extern "C" void kernel_launch(void* const* d_in, const int* in_sizes, int n_in,
                              void* d_out, int out_size, void* d_ws, size_t ws_size,
                              hipStream_t stream){
  const float* node_attrs = (const float*)d_in[0];
  const float* node_feats = (const float*)d_in[1];
  const float* edge_attrs = (const float*)d_in[2];
  const float* edge_feats = (const float*)d_in[3];
  const int*   edge_index = (const int*)d_in[4];
  const float* W_up  = (const float*)d_in[5];
  const float* Wr1   = (const float*)d_in[6];
  const float* Wr2   = (const float*)d_in[7];
  const float* Wr3   = (const float*)d_in[8];
  const float* Wr4   = (const float*)d_in[9];
  const float* Wd    = (const float*)d_in[10];
  const float* Wsin  = (const float*)d_in[11];
  const float* Wlin  = (const float*)d_in[12];
  const float* Wskip = (const float*)d_in[13];
  float* out = (float*)d_out;

  _Float16* w2h  = (_Float16*)d_ws;                 // 81,920,000 halfs
  float* msg     = (float*)(w2h + 81920000);        // 20,480,000 f32
  float* x       = msg + 20480000;                  //  1,280,000 f32
  float* ddv     = x + 1280000;                     //    160,000 f32
  _Float16* WC16T= (_Float16*)(ddv + 160000);       //    655,360 halfs
  int* cnt   = (int*)(WC16T + 655360);              //     10,000
  int* off   = cnt + 10000;                         //     10,016
  int* cur   = off + 10016;                         //     10,000
  int* elist = cur + 10000;                         //    160,000

  hipMemsetAsync(cnt, 0, (size_t)10000 * sizeof(int), stream);

  k_node_up<<<N_NODES, 128, 0, stream>>>(node_feats, W_up, x);
  k_wc<<<512, 256, 0, stream>>>(Wlin, Wskip, WC16T);

  k_count <<<(N_EDGES + 255)/256, 256, 0, stream>>>(edge_index, cnt);
  k_scan  <<<1, 256, 0, stream>>>(cnt, off, cur);
  k_bucket<<<(N_EDGES + 255)/256, 256, 0, stream>>>(edge_index, cur, elist);

  k_edge_mlp<<<N_EDGES/32, 256, 0, stream>>>(edge_feats, edge_index, x,
                                             Wr1, Wr2, Wr3, Wr4, Wd, w2h, ddv);

  k_gather<<<N_NODES, 256, 0, stream>>>(edge_attrs, w2h, ddv, Wsin,
                                        off, elist, msg);

  k_final<0,1><<<(N_NODES*1 + 127)/128, 256, 0, stream>>>(msg, node_attrs, WC16T, out);
  k_final<1,3><<<(N_NODES*3 + 127)/128, 256, 0, stream>>>(msg, node_attrs, WC16T, out);
  k_final<2,5><<<(N_NODES*5 + 127)/128, 256, 0, stream>>>(msg, node_attrs, WC16T, out);
  k_final<3,7><<<(N_NODES*7 + 127)/128, 256, 0, stream>>>(msg, node_attrs, WC16T, out);
}

// Round 5
// 555.875 us; speedup vs baseline: 4.2290x; 1.3022x over previous
//
#include <hip/hip_runtime.h>
#include <hip/hip_bf16.h>

#define N_NODES 10000
#define N_EDGES 160000

typedef _Float16 h8 __attribute__((ext_vector_type(8)));
typedef _Float16 h4 __attribute__((ext_vector_type(4)));
typedef _Float16 h2 __attribute__((ext_vector_type(2)));
typedef float f32x4 __attribute__((ext_vector_type(4)));

__device__ __forceinline__ float silu_f(float v){ return v / (1.f + expf(-v)); }

// ---------------------------------------------------------------- K1: x = nf @ Wup/sqrt(128)
__global__ __launch_bounds__(128) void k_node_up(const float* __restrict__ nf,
                                                 const float* __restrict__ Wup,
                                                 float* __restrict__ x){
  const int n = blockIdx.x, u = threadIdx.x;
  __shared__ float row[128];
  row[u] = nf[n*128 + u];
  __syncthreads();
  float acc = 0.f;
  #pragma unroll 16
  for (int k = 0; k < 128; ++k) acc += row[k] * Wup[k*128 + u];
  x[n*128 + u] = acc * 0.08838834764831843f;   // 1/sqrt(128)
}

// ---------------------------------------------------------------- K1b: WC16T[l][w][a*128+u]
__global__ __launch_bounds__(256) void k_wc(const float* __restrict__ Wlin,
                                            const float* __restrict__ Wskip,
                                            _Float16* __restrict__ WC16T){
  const int lu = blockIdx.x;           // l*128 + u
  const int l  = lu >> 7, u = lu & 127;
  __shared__ float wl[128];
  if (threadIdx.x < 128) wl[threadIdx.x] = Wlin[lu*128 + threadIdx.x];
  __syncthreads();
  const float* Wsk = Wskip + (size_t)l * 163840;   // [v][a][w]
  for (int i = threadIdx.x; i < 1280; i += 256){   // i = a*128 + w
    float acc = 0.f;
    #pragma unroll 16
    for (int v = 0; v < 128; ++v) acc += wl[v] * Wsk[v*1280 + i];
    const int a = i >> 7, w = i & 127;
    WC16T[((size_t)l*128 + w)*1280 + a*128 + u] =
        (_Float16)(acc * 0.0024705294220065465f);  // 1/sqrt(128*1280)
  }
}

// ---------------------------------------------------------------- K1c: pre-transposed fp16 radial weights (scale folded)
__global__ __launch_bounds__(256) void k_prep(const float* __restrict__ Wr2,
                                              const float* __restrict__ Wr3,
                                              const float* __restrict__ Wr4,
                                              _Float16* __restrict__ Wr2T,
                                              _Float16* __restrict__ Wr3T,
                                              _Float16* __restrict__ Wr4T){
  const int idx = blockIdx.x*256 + threadIdx.x;   // 0..40959
  if (idx < 4096){
    const int n = idx >> 6, k = idx & 63;
    Wr2T[idx] = (_Float16)(Wr2[k*64 + n] * 0.125f);
  } else if (idx < 8192){
    const int j = idx - 4096;
    const int n = j >> 6, k = j & 63;
    Wr3T[j] = (_Float16)(Wr3[k*64 + n] * 0.125f);
  } else if (idx < 40960){
    const int j = idx - 8192;
    const int n = j >> 6, k = j & 63;
    Wr4T[j] = (_Float16)(Wr4[k*512 + n] * 0.125f);
  }
}

// ---------------------------------------------------------------- CSR build
__global__ __launch_bounds__(256) void k_count(const int* __restrict__ eidx,
                                               int* __restrict__ cnt){
  const int e = blockIdx.x * 256 + threadIdx.x;
  if (e < N_EDGES) atomicAdd(&cnt[eidx[N_EDGES + e]], 1);
}

__global__ __launch_bounds__(256) void k_scan(const int* __restrict__ cnt,
                                              int* __restrict__ off,
                                              int* __restrict__ cur){
  __shared__ int sums[256];
  const int t = threadIdx.x;
  const int base = t * 40;
  int s = 0;
  for (int i = 0; i < 40; ++i){
    const int idx = base + i;
    if (idx < N_NODES) s += cnt[idx];
  }
  sums[t] = s;
  __syncthreads();
  for (int st = 1; st < 256; st <<= 1){
    const int v = (t >= st) ? sums[t - st] : 0;
    __syncthreads();
    sums[t] += v;
    __syncthreads();
  }
  int pre = (t > 0) ? sums[t - 1] : 0;
  for (int i = 0; i < 40; ++i){
    const int idx = base + i;
    if (idx < N_NODES){
      off[idx] = pre; cur[idx] = pre;
      pre += cnt[idx];
    }
  }
  if (t == 255) off[N_NODES] = sums[255];
}

__global__ __launch_bounds__(256) void k_bucket(const int* __restrict__ eidx,
                                                int* __restrict__ cur,
                                                int* __restrict__ elist){
  const int e = blockIdx.x * 256 + threadIdx.x;
  if (e < N_EDGES){
    const int pos = atomicAdd(&cur[eidx[N_EDGES + e]], 1);
    elist[pos] = e;
  }
}

// ---------------------------------------------------------------- K2: edge MLP via MFMA, 64 edges/block
// All GEMMs as D[n][e] = WrT[n][k] (A) x act[e][k] (B) so D-frag (col=e) chains into next B-frag.
__global__ __launch_bounds__(256) void k_edge_mlp(const float* __restrict__ ef,
                                                  const int*   __restrict__ eidx,
                                                  const float* __restrict__ x,
                                                  const float* __restrict__ Wr1,
                                                  const float* __restrict__ Wd,
                                                  const _Float16* __restrict__ Wr2T,
                                                  const _Float16* __restrict__ Wr3T,
                                                  const _Float16* __restrict__ Wr4T,
                                                  _Float16* __restrict__ w2h,
                                                  float* __restrict__ dd){
  const int tid = threadIdx.x;
  const int E0  = blockIdx.x * 64;

  __shared__ float s_ef[64][8];                    // 2 KB
  __shared__ float s_w1[8][64];                    // 2 KB
  alignas(16) __shared__ _Float16 s_xs[64][136];   // 17.4 KB (pad to 136 for bank spread)
  alignas(16) __shared__ _Float16 s_actA[64][64];  // 8 KB, [e][k] chunk-XOR swizzled
  alignas(16) __shared__ _Float16 s_actB[64][64];  // 8 KB

  // ---- stage ef, W1, xs(fp16)
  for (int j = tid; j < 512; j += 256) s_ef[j >> 3][j & 7] = ef[E0*8 + j];
  for (int j = tid; j < 512; j += 256) s_w1[j >> 6][j & 63] = Wr1[j];
  {
    const int e = tid >> 2, q = tid & 3;
    const int snd = eidx[E0 + e];
    const float4* xp = (const float4*)(x + (size_t)snd*128 + q*32);
    #pragma unroll
    for (int j = 0; j < 8; ++j){
      const float4 v = xp[j];
      h4 hv; hv[0]=(_Float16)v.x; hv[1]=(_Float16)v.y; hv[2]=(_Float16)v.z; hv[3]=(_Float16)v.w;
      *(h4*)&s_xs[e][q*32 + j*4] = hv;
    }
  }
  __syncthreads();

  // ---- dd
  if (tid < 64){
    float s = 0.f;
    #pragma unroll
    for (int i = 0; i < 8; ++i) s += s_ef[tid][i] * Wd[i];
    dd[E0 + tid] = tanhf(s*s);
  }

  // ---- L1 (VALU, K=8): h1[e][n] -> s_actA
  {
    const int e = tid >> 2, ng = tid & 3;
    float hv[16];
    #pragma unroll
    for (int j = 0; j < 16; ++j) hv[j] = 0.f;
    #pragma unroll
    for (int k = 0; k < 8; ++k){
      const float ev = s_ef[e][k] * 0.3535533905932738f;
      #pragma unroll
      for (int j = 0; j < 16; ++j) hv[j] += ev * s_w1[k][ng*16 + j];
    }
    #pragma unroll
    for (int c2 = 0; c2 < 2; ++c2){
      h8 o;
      #pragma unroll
      for (int j = 0; j < 8; ++j) o[j] = (_Float16)silu_f(hv[c2*8 + j]);
      const int chunk = (ng*2 + c2) ^ (e & 7);
      *(h8*)&s_actA[e][chunk*8] = o;
    }
  }
  __syncthreads();

  const int lane = tid & 63, wid = tid >> 6;
  const int li = lane & 15, kg = lane >> 4;

  // ---- L2 MFMA: g = silu(Wr2T @ h1^T); wave wid owns n-tile wid
  {
    h8 af[2];
    #pragma unroll
    for (int s = 0; s < 2; ++s)
      af[s] = *(const h8*)&Wr2T[(size_t)(wid*16 + li)*64 + s*32 + kg*8];
    #pragma unroll
    for (int nt = 0; nt < 4; ++nt){
      const int e = nt*16 + li;
      f32x4 acc = (f32x4){0,0,0,0};
      #pragma unroll
      for (int s = 0; s < 2; ++s){
        const h8 bf = *(const h8*)&s_actA[e][((s*4 + kg) ^ (e & 7))*8];
        acc = __builtin_amdgcn_mfma_f32_16x16x32_f16(af[s], bf, acc, 0, 0, 0);
      }
      #pragma unroll
      for (int r = 0; r < 4; ++r){
        const int n = wid*16 + kg*4 + r;
        s_actB[e][((n >> 3) ^ (e & 7))*8 + (n & 7)] = (_Float16)silu_f(acc[r]);
      }
    }
  }
  __syncthreads();

  // ---- L3 MFMA: h3 = silu(Wr3T @ g^T)
  {
    h8 af[2];
    #pragma unroll
    for (int s = 0; s < 2; ++s)
      af[s] = *(const h8*)&Wr3T[(size_t)(wid*16 + li)*64 + s*32 + kg*8];
    #pragma unroll
    for (int nt = 0; nt < 4; ++nt){
      const int e = nt*16 + li;
      f32x4 acc = (f32x4){0,0,0,0};
      #pragma unroll
      for (int s = 0; s < 2; ++s){
        const h8 bf = *(const h8*)&s_actB[e][((s*4 + kg) ^ (e & 7))*8];
        acc = __builtin_amdgcn_mfma_f32_16x16x32_f16(af[s], bf, acc, 0, 0, 0);
      }
      #pragma unroll
      for (int r = 0; r < 4; ++r){
        const int n = wid*16 + kg*4 + r;
        s_actA[e][((n >> 3) ^ (e & 7))*8 + (n & 7)] = (_Float16)silu_f(acc[r]);
      }
    }
  }
  __syncthreads();

  // ---- tpw MFMA: D[c][e] = Wr4T[c][k] x h3[e][k]; then w2 = tpw*xs -> w2h[e][c]
  #pragma unroll
  for (int p = 0; p < 2; ++p){
    h8 bf[4][2];
    #pragma unroll
    for (int nt = 0; nt < 4; ++nt){
      const int e = nt*16 + li;
      #pragma unroll
      for (int s = 0; s < 2; ++s)
        bf[nt][s] = *(const h8*)&s_actA[e][((s*4 + kg) ^ (e & 7))*8];
    }
    #pragma unroll
    for (int mt = 0; mt < 4; ++mt){
      const int nbase = wid*128 + p*64 + mt*16;
      h8 af[2];
      #pragma unroll
      for (int s = 0; s < 2; ++s)
        af[s] = *(const h8*)&Wr4T[(size_t)(nbase + li)*64 + s*32 + kg*8];
      f32x4 acc[4];
      #pragma unroll
      for (int nt = 0; nt < 4; ++nt){
        acc[nt] = (f32x4){0,0,0,0};
        #pragma unroll
        for (int s = 0; s < 2; ++s)
          acc[nt] = __builtin_amdgcn_mfma_f32_16x16x32_f16(af[s], bf[nt][s], acc[nt], 0, 0, 0);
      }
      const int c0 = nbase + kg*4;
      const int u0 = c0 & 127;
      #pragma unroll
      for (int nt = 0; nt < 4; ++nt){
        const int e = nt*16 + li;
        const h4 xv = *(const h4*)&s_xs[e][u0];
        h4 ov;
        #pragma unroll
        for (int r = 0; r < 4; ++r) ov[r] = (_Float16)acc[nt][r] * xv[r];
        *(h4*)&w2h[(size_t)(E0 + e)*512 + c0] = ov;
      }
    }
  }
}

// ---------------------------------------------------------------- K3: gather per node (CSR), register accumulate, fused rho/demb
__global__ __launch_bounds__(256) void k_gather(const float* __restrict__ ea,
                                                const _Float16* __restrict__ w2h,
                                                const float* __restrict__ dd,
                                                const float* __restrict__ Wsin,
                                                const int* __restrict__ off,
                                                const int* __restrict__ elist,
                                                float* __restrict__ msg){
  const int n = blockIdx.x, tid = threadIdx.x;
  const int beg = off[n], end = off[n + 1];
  const int ngrp = (end - beg + 15) >> 4;

  alignas(16) __shared__ _Float16 s_w2[16][512];
  alignas(16) __shared__ float s_sh[16][16];
  __shared__ float s_dd[16];
  __shared__ int   s_el[16];
  __shared__ float s_emb[32];
  __shared__ float s_rho;
  if (tid == 0) s_rho = 0.f;

  const int u = tid & 127, h = tid >> 7;
  float acc[8] = {0,0,0,0,0,0,0,0};

  for (int grp = 0; grp < ngrp; ++grp){
    if (tid < 16){
      const int p = beg + grp*16 + tid;
      s_el[tid] = (p < end) ? elist[p] : -1;
    }
    __syncthreads();
    #pragma unroll
    for (int c2 = 0; c2 < 4; ++c2){
      const int chunk = c2*256 + tid;
      const int slot = chunk >> 6, part = chunk & 63;
      const int e = s_el[slot];
      h8 v = {};
      if (e >= 0) v = *(const h8*)&w2h[(size_t)e*512 + part*8];
      *(h8*)&s_w2[slot][part*8] = v;
    }
    { const int slot = tid >> 4, j = tid & 15;
      const int e = s_el[slot];
      s_sh[slot][j] = (e >= 0) ? ea[e*16 + j] : 0.f; }
    if (tid < 16){
      const int e = s_el[tid];
      s_dd[tid] = (e >= 0) ? dd[e] : 0.f;
    }
    __syncthreads();

    if (h == 0){
      #pragma unroll
      for (int slot = 0; slot < 16; ++slot){
        const float wa = (float)s_w2[slot][u];
        const float wb = (float)s_w2[slot][128 + u];
        const float wc = (float)s_w2[slot][256 + u];
        const float4 sa = *(const float4*)&s_sh[slot][0];
        const float4 sb = *(const float4*)&s_sh[slot][4];
        acc[0] += wa * sa.x;
        acc[1] += wb * sa.y;  acc[2] += wb * sa.z;  acc[3] += wb * sa.w;
        acc[4] += wc * sb.x;  acc[5] += wc * sb.y;
        acc[6] += wc * sb.z;  acc[7] += wc * sb.w;
      }
    } else {
      #pragma unroll
      for (int slot = 0; slot < 16; ++slot){
        const float wc = (float)s_w2[slot][256 + u];
        const float wd = (float)s_w2[slot][384 + u];
        const float4 sa = *(const float4*)&s_sh[slot][8];
        const float4 sb = *(const float4*)&s_sh[slot][12];
        acc[0] += wc * sa.x;
        acc[1] += wd * sa.y;  acc[2] += wd * sa.z;  acc[3] += wd * sa.w;
        acc[4] += wd * sb.x;  acc[5] += wd * sb.y;
        acc[6] += wd * sb.z;  acc[7] += wd * sb.w;
      }
    }
    if (tid == 0){
      float r = 0.f;
      #pragma unroll
      for (int s2 = 0; s2 < 16; ++s2) r += s_dd[s2];
      s_rho += r;
    }
    __syncthreads();
  }

  // ---- epilogue
  const float rho  = s_rho;
  const float tinv = 1.f / (rho + 1.f);
  if (tid < 16){
    const float fr  = expf(-0.28782313662425572f * (float)tid);  // ln(100)/16
    const float ang = rho * fr;
    s_emb[tid]      = sinf(ang);
    s_emb[tid + 16] = cosf(ang);
  }
  __syncthreads();
  float db = 0.f;
  if (h == 0){
    #pragma unroll
    for (int j = 0; j < 32; ++j) db += s_emb[j] * Wsin[j*128 + u];
  }
  #pragma unroll
  for (int j = 0; j < 8; ++j){
    float v = acc[j] * tinv;
    if (h == 0 && j == 0) v += db;
    msg[(size_t)n*2048 + (h*8 + j)*128 + u] = v;
  }
}

// ---------------------------------------------------------------- K4: final GEMM, 128x128 LDS-staged MFMA tile per l
template<int L, int D>
__global__ __launch_bounds__(256) void k_final(const float* __restrict__ msg,
                                               const float* __restrict__ attrs,
                                               const _Float16* __restrict__ WC16T,
                                               float* __restrict__ out){
  constexpr int OFF  = (L==0 ? 0 : L==1 ? 1 : L==2 ? 4 : 9);
  constexpr int ROWS = N_NODES * D;
  const int r0  = blockIdx.x * 128;
  const int tid = threadIdx.x;

  alignas(16) __shared__ _Float16 sA[128*128];
  alignas(16) __shared__ _Float16 sB[2][64*128];
  __shared__ _Float16 sAttr[128*10];

  {
    const int rl = tid >> 1, half = tid & 1;
    const int gr = r0 + rl;
    h8 vals[8];
    if (gr < ROWS){
      const int n = gr / D, k = gr - n*D;
      const float4* src = (const float4*)(msg + (size_t)n*2048 + (size_t)(OFF+k)*128 + half*64);
      #pragma unroll
      for (int j = 0; j < 8; ++j){
        const float4 v0 = src[j*2], v1 = src[j*2+1];
        h8 hv;
        hv[0]=(_Float16)v0.x; hv[1]=(_Float16)v0.y; hv[2]=(_Float16)v0.z; hv[3]=(_Float16)v0.w;
        hv[4]=(_Float16)v1.x; hv[5]=(_Float16)v1.y; hv[6]=(_Float16)v1.z; hv[7]=(_Float16)v1.w;
        vals[j] = hv;
      }
    } else {
      #pragma unroll
      for (int j = 0; j < 8; ++j) vals[j] = (h8){};
    }
    #pragma unroll
    for (int j = 0; j < 8; ++j){
      const int cu = half*8 + j;
      const int cs = (cu & 8) | ((cu & 7) ^ (rl & 7));
      *(h8*)&sA[rl*128 + cs*8] = vals[j];
    }
  }
  for (int i = tid; i < 1280; i += 256){
    const int rl = i / 10, aa = i - rl*10;
    const int gr = r0 + rl;
    sAttr[i] = (gr < ROWS) ? (_Float16)attrs[(gr / D)*10 + aa] : (_Float16)0.f;
  }
  {
    const int w = tid >> 1, part = tid & 1;
    const _Float16* src = WC16T + ((size_t)L*128 + w)*1280 + part*32;
    #pragma unroll
    for (int j = 0; j < 4; ++j){
      const h8 v = *(const h8*)(src + j*8);
      const int cc = part*4 + j;
      *(h8*)&sB[0][w*64 + (cc ^ (w & 7))*8] = v;
    }
  }
  __syncthreads();

  const int wid = tid >> 6, lane = tid & 63;
  const int wm = wid >> 1, wn = wid & 1;
  const int li = lane & 15, kg = lane >> 4;

  f32x4 acc[4][4];
  #pragma unroll
  for (int m = 0; m < 4; ++m)
    #pragma unroll
    for (int nn = 0; nn < 4; ++nn) acc[m][nn] = (f32x4){0,0,0,0};

  for (int step = 0; step < 20; ++step){
    const int cur = step & 1;
    const bool more = (step + 1 < 20);
    h8 pre[4];
    if (more){
      const int a2 = (step+1) >> 1, u02 = ((step+1) & 1) << 6;
      const _Float16* src = WC16T + ((size_t)L*128 + (tid>>1))*1280 + a2*128 + u02 + (tid&1)*32;
      #pragma unroll
      for (int j = 0; j < 4; ++j) pre[j] = *(const h8*)(src + j*8);
    }

    const int a  = step >> 1;
    const int uh = (step & 1) << 3;

    h8 afr[4][2], bfr[4][2];
    #pragma unroll
    for (int m = 0; m < 4; ++m){
      const int row = wm*64 + m*16 + li;
      const _Float16 av = sAttr[row*10 + a];
      h8 avx;
      #pragma unroll
      for (int j = 0; j < 8; ++j) avx[j] = av;
      #pragma unroll
      for (int s = 0; s < 2; ++s){
        const int ca = uh + s*4 + kg;
        const int cs = (ca & 8) | ((ca & 7) ^ (row & 7));
        const h8 mA = *(const h8*)&sA[row*128 + cs*8];
        afr[m][s] = mA * avx;
      }
    }
    #pragma unroll
    for (int nn = 0; nn < 4; ++nn){
      const int w = wn*64 + nn*16 + li;
      #pragma unroll
      for (int s = 0; s < 2; ++s){
        const int cb = s*4 + kg;
        bfr[nn][s] = *(const h8*)&sB[cur][w*64 + ((cb ^ (w & 7)))*8];
      }
    }
    #pragma unroll
    for (int s = 0; s < 2; ++s)
      #pragma unroll
      for (int m = 0; m < 4; ++m)
        #pragma unroll
        for (int nn = 0; nn < 4; ++nn)
          acc[m][nn] = __builtin_amdgcn_mfma_f32_16x16x32_f16(afr[m][s], bfr[nn][s], acc[m][nn], 0, 0, 0);

    if (more){
      const int w = tid >> 1, part = tid & 1;
      #pragma unroll
      for (int j = 0; j < 4; ++j){
        const int cc = part*4 + j;
        *(h8*)&sB[cur ^ 1][w*64 + (cc ^ (w & 7))*8] = pre[j];
      }
    }
    __syncthreads();
  }

  #pragma unroll
  for (int m = 0; m < 4; ++m){
    const int rbase = r0 + wm*64 + m*16 + kg*4;
    #pragma unroll
    for (int rr = 0; rr < 4; ++rr){
      const int gr = rbase + rr;
      if (gr < ROWS){
        const int n = gr / D, k = gr - n*D;
        float* op = out + (size_t)n*2048 + OFF + k;
        #pragma unroll
        for (int nn = 0; nn < 4; ++nn){
          const int w = wn*64 + nn*16 + li;
          op[w*16] = acc[m][nn][rr];
        }
      }
    }
  }
}

// ----------------------------------------------------------------
extern "C" void kernel_launch(void* const* d_in, const int* in_sizes, int n_in,
                              void* d_out, int out_size, void* d_ws, size_t ws_size,
                              hipStream_t stream){
  const float* node_attrs = (const float*)d_in[0];
  const float* node_feats = (const float*)d_in[1];
  const float* edge_attrs = (const float*)d_in[2];
  const float* edge_feats = (const float*)d_in[3];
  const int*   edge_index = (const int*)d_in[4];
  const float* W_up  = (const float*)d_in[5];
  const float* Wr1   = (const float*)d_in[6];
  const float* Wr2   = (const float*)d_in[7];
  const float* Wr3   = (const float*)d_in[8];
  const float* Wr4   = (const float*)d_in[9];
  const float* Wd    = (const float*)d_in[10];
  const float* Wsin  = (const float*)d_in[11];
  const float* Wlin  = (const float*)d_in[12];
  const float* Wskip = (const float*)d_in[13];
  float* out = (float*)d_out;

  _Float16* w2h  = (_Float16*)d_ws;                 // 81,920,000 halfs
  float* msg     = (float*)(w2h + 81920000);        // 20,480,000 f32
  float* x       = msg + 20480000;                  //  1,280,000 f32
  float* ddv     = x + 1280000;                     //    160,000 f32
  _Float16* WC16T= (_Float16*)(ddv + 160000);       //    655,360 halfs
  int* cnt   = (int*)(WC16T + 655360);              //     10,000
  int* off   = cnt + 10000;                         //     10,016
  int* cur   = off + 10016;                         //     10,000
  int* elist = cur + 10000;                         //    160,000
  _Float16* Wr2T = (_Float16*)(elist + 160000);     //      4,096 halfs
  _Float16* Wr3T = Wr2T + 4096;                     //      4,096 halfs
  _Float16* Wr4T = Wr3T + 4096;                     //     32,768 halfs

  hipMemsetAsync(cnt, 0, (size_t)10000 * sizeof(int), stream);

  k_node_up<<<N_NODES, 128, 0, stream>>>(node_feats, W_up, x);
  k_wc<<<512, 256, 0, stream>>>(Wlin, Wskip, WC16T);
  k_prep<<<160, 256, 0, stream>>>(Wr2, Wr3, Wr4, Wr2T, Wr3T, Wr4T);

  k_count <<<(N_EDGES + 255)/256, 256, 0, stream>>>(edge_index, cnt);
  k_scan  <<<1, 256, 0, stream>>>(cnt, off, cur);
  k_bucket<<<(N_EDGES + 255)/256, 256, 0, stream>>>(edge_index, cur, elist);

  k_edge_mlp<<<N_EDGES/64, 256, 0, stream>>>(edge_feats, edge_index, x,
                                             Wr1, Wd, Wr2T, Wr3T, Wr4T, w2h, ddv);

  k_gather<<<N_NODES, 256, 0, stream>>>(edge_attrs, w2h, ddv, Wsin,
                                        off, elist, msg);

  k_final<0,1><<<(N_NODES*1 + 127)/128, 256, 0, stream>>>(msg, node_attrs, WC16T, out);
  k_final<1,3><<<(N_NODES*3 + 127)/128, 256, 0, stream>>>(msg, node_attrs, WC16T, out);
  k_final<2,5><<<(N_NODES*5 + 127)/128, 256, 0, stream>>>(msg, node_attrs, WC16T, out);
  k_final<3,7><<<(N_NODES*7 + 127)/128, 256, 0, stream>>>(msg, node_attrs, WC16T, out);
}

// Round 6
// 450.629 us; speedup vs baseline: 5.2167x; 1.2336x over previous
//
#include <hip/hip_runtime.h>
#include <hip/hip_bf16.h>

#define N_NODES 10000
#define N_EDGES 160000

typedef _Float16 h8 __attribute__((ext_vector_type(8)));
typedef _Float16 h4 __attribute__((ext_vector_type(4)));
typedef float f32x4 __attribute__((ext_vector_type(4)));

__device__ __forceinline__ float silu_f(float v){ return v / (1.f + expf(-v)); }

// ---------------------------------------------------------------- K1: x = nf @ Wup/sqrt(128) via MFMA, 64 nodes/block
__global__ __launch_bounds__(256) void k_node_up(const float* __restrict__ nf,
                                                 const _Float16* __restrict__ WupT,
                                                 float* __restrict__ x){
  const int n0 = blockIdx.x * 64;
  const int tid = threadIdx.x;
  alignas(16) __shared__ _Float16 s_nf[64*128];
  alignas(16) __shared__ _Float16 s_wt[128*128];

  {
    const int rl = tid >> 2, part = tid & 3;
    const int gr = n0 + rl;
    #pragma unroll
    for (int j = 0; j < 4; ++j){
      const int cu = part*4 + j;
      h8 hv = (h8){};
      if (gr < N_NODES){
        const float4 v0 = *(const float4*)(nf + (size_t)gr*128 + cu*8);
        const float4 v1 = *(const float4*)(nf + (size_t)gr*128 + cu*8 + 4);
        hv[0]=(_Float16)v0.x; hv[1]=(_Float16)v0.y; hv[2]=(_Float16)v0.z; hv[3]=(_Float16)v0.w;
        hv[4]=(_Float16)v1.x; hv[5]=(_Float16)v1.y; hv[6]=(_Float16)v1.z; hv[7]=(_Float16)v1.w;
      }
      const int cs = (cu & 8) | ((cu & 7) ^ (rl & 7));
      *(h8*)&s_nf[rl*128 + cs*8] = hv;
    }
  }
  {
    const int rl = tid >> 1, part = tid & 1;
    #pragma unroll
    for (int j = 0; j < 8; ++j){
      const int cu = part*8 + j;
      const h8 v = *(const h8*)&WupT[(size_t)rl*128 + cu*8];
      const int cs = (cu & 8) | ((cu & 7) ^ (rl & 7));
      *(h8*)&s_wt[rl*128 + cs*8] = v;
    }
  }
  __syncthreads();

  const int wid = tid >> 6, lane = tid & 63;
  const int li = lane & 15, kg = lane >> 4;

  f32x4 acc[8];
  #pragma unroll
  for (int i = 0; i < 8; ++i) acc[i] = (f32x4){0,0,0,0};

  const int row = wid*16 + li;
  #pragma unroll
  for (int s = 0; s < 4; ++s){
    const int ca = s*4 + kg;
    const int csA = (ca & 8) | ((ca & 7) ^ (row & 7));
    const h8 af = *(const h8*)&s_nf[row*128 + csA*8];
    #pragma unroll
    for (int nt = 0; nt < 8; ++nt){
      const int u = nt*16 + li;
      const int csB = (ca & 8) | ((ca & 7) ^ (u & 7));
      const h8 bf = *(const h8*)&s_wt[u*128 + csB*8];
      acc[nt] = __builtin_amdgcn_mfma_f32_16x16x32_f16(af, bf, acc[nt], 0, 0, 0);
    }
  }
  #pragma unroll
  for (int nt = 0; nt < 8; ++nt){
    #pragma unroll
    for (int r = 0; r < 4; ++r){
      const int gr = n0 + wid*16 + kg*4 + r;
      if (gr < N_NODES) x[(size_t)gr*128 + nt*16 + li] = acc[nt][r];
    }
  }
}

// ---------------------------------------------------------------- K1b: WC16T[l][w][a*128+u]
__global__ __launch_bounds__(256) void k_wc(const float* __restrict__ Wlin,
                                            const float* __restrict__ Wskip,
                                            _Float16* __restrict__ WC16T){
  const int lu = blockIdx.x;           // l*128 + u
  const int l  = lu >> 7, u = lu & 127;
  __shared__ float wl[128];
  if (threadIdx.x < 128) wl[threadIdx.x] = Wlin[lu*128 + threadIdx.x];
  __syncthreads();
  const float* Wsk = Wskip + (size_t)l * 163840;   // [v][a][w]
  for (int i = threadIdx.x; i < 1280; i += 256){   // i = a*128 + w
    float acc = 0.f;
    #pragma unroll 16
    for (int v = 0; v < 128; ++v) acc += wl[v] * Wsk[v*1280 + i];
    const int a = i >> 7, w = i & 127;
    WC16T[((size_t)l*128 + w)*1280 + a*128 + u] =
        (_Float16)(acc * 0.0024705294220065465f);  // 1/sqrt(128*1280)
  }
}

// ---------------------------------------------------------------- K1c: pre-transposed fp16 weights (scales folded)
__global__ __launch_bounds__(256) void k_prep(const float* __restrict__ Wr2,
                                              const float* __restrict__ Wr3,
                                              const float* __restrict__ Wr4,
                                              const float* __restrict__ Wup,
                                              _Float16* __restrict__ Wr2T,
                                              _Float16* __restrict__ Wr3T,
                                              _Float16* __restrict__ Wr4T,
                                              _Float16* __restrict__ WupT){
  const int idx = blockIdx.x*256 + threadIdx.x;
  if (idx < 4096){
    const int n = idx >> 6, k = idx & 63;
    Wr2T[idx] = (_Float16)(Wr2[k*64 + n] * 0.125f);
  } else if (idx < 8192){
    const int j = idx - 4096;
    const int n = j >> 6, k = j & 63;
    Wr3T[j] = (_Float16)(Wr3[k*64 + n] * 0.125f);
  } else if (idx < 40960){
    const int j = idx - 8192;
    const int n = j >> 6, k = j & 63;
    Wr4T[j] = (_Float16)(Wr4[k*512 + n] * 0.125f);
  } else if (idx < 57344){
    const int j = idx - 40960;
    const int u = j >> 7, k = j & 127;
    WupT[j] = (_Float16)(Wup[k*128 + u] * 0.08838834764831843f);
  }
}

// ---------------------------------------------------------------- CSR build
__global__ __launch_bounds__(256) void k_count(const int* __restrict__ eidx,
                                               int* __restrict__ cnt){
  const int e = blockIdx.x * 256 + threadIdx.x;
  if (e < N_EDGES) atomicAdd(&cnt[eidx[N_EDGES + e]], 1);
}

__global__ __launch_bounds__(256) void k_scan(const int* __restrict__ cnt,
                                              int* __restrict__ off,
                                              int* __restrict__ cur){
  __shared__ int sums[256];
  const int t = threadIdx.x;
  const int base = t * 40;
  int s = 0;
  for (int i = 0; i < 40; ++i){
    const int idx = base + i;
    if (idx < N_NODES) s += cnt[idx];
  }
  sums[t] = s;
  __syncthreads();
  for (int st = 1; st < 256; st <<= 1){
    const int v = (t >= st) ? sums[t - st] : 0;
    __syncthreads();
    sums[t] += v;
    __syncthreads();
  }
  int pre = (t > 0) ? sums[t - 1] : 0;
  for (int i = 0; i < 40; ++i){
    const int idx = base + i;
    if (idx < N_NODES){
      off[idx] = pre; cur[idx] = pre;
      pre += cnt[idx];
    }
  }
  if (t == 255) off[N_NODES] = sums[255];
}

__global__ __launch_bounds__(256) void k_bucket(const int* __restrict__ eidx,
                                                int* __restrict__ cur,
                                                int* __restrict__ elist){
  const int e = blockIdx.x * 256 + threadIdx.x;
  if (e < N_EDGES){
    const int pos = atomicAdd(&cur[eidx[N_EDGES + e]], 1);
    elist[pos] = e;
  }
}

// ---------------------------------------------------------------- K2: edge MLP via MFMA, 64 CSR-ordered edges/block
// w2h/dd written at CSR position -> k_gather streams sequentially.
__global__ __launch_bounds__(256) void k_edge_mlp(const float* __restrict__ ef,
                                                  const int*   __restrict__ eidx,
                                                  const int*   __restrict__ elist,
                                                  const float* __restrict__ x,
                                                  const float* __restrict__ Wr1,
                                                  const float* __restrict__ Wd,
                                                  const _Float16* __restrict__ Wr2T,
                                                  const _Float16* __restrict__ Wr3T,
                                                  const _Float16* __restrict__ Wr4T,
                                                  _Float16* __restrict__ w2h,
                                                  float* __restrict__ dd){
  const int tid = threadIdx.x;
  const int E0  = blockIdx.x * 64;

  __shared__ int   s_eid[64];
  __shared__ float s_ef[64][8];
  __shared__ float s_w1[8][64];
  alignas(16) __shared__ _Float16 s_xs[64][136];
  alignas(16) __shared__ _Float16 s_actA[64][64];
  alignas(16) __shared__ _Float16 s_actB[64][64];

  if (tid < 64) s_eid[tid] = elist[E0 + tid];
  __syncthreads();

  for (int j = tid; j < 512; j += 256){
    const int e = j >> 3, i = j & 7;
    s_ef[e][i] = ef[(size_t)s_eid[e]*8 + i];
  }
  for (int j = tid; j < 512; j += 256) s_w1[j >> 6][j & 63] = Wr1[j];
  {
    const int e = tid >> 2, q = tid & 3;
    const int snd = eidx[s_eid[e]];
    const float4* xp = (const float4*)(x + (size_t)snd*128 + q*32);
    #pragma unroll
    for (int j = 0; j < 8; ++j){
      const float4 v = xp[j];
      h4 hv; hv[0]=(_Float16)v.x; hv[1]=(_Float16)v.y; hv[2]=(_Float16)v.z; hv[3]=(_Float16)v.w;
      *(h4*)&s_xs[e][q*32 + j*4] = hv;
    }
  }
  __syncthreads();

  // ---- dd (CSR position)
  if (tid < 64){
    float s = 0.f;
    #pragma unroll
    for (int i = 0; i < 8; ++i) s += s_ef[tid][i] * Wd[i];
    dd[E0 + tid] = tanhf(s*s);
  }

  // ---- L1 (VALU, K=8)
  {
    const int e = tid >> 2, ng = tid & 3;
    float hv[16];
    #pragma unroll
    for (int j = 0; j < 16; ++j) hv[j] = 0.f;
    #pragma unroll
    for (int k = 0; k < 8; ++k){
      const float ev = s_ef[e][k] * 0.3535533905932738f;
      #pragma unroll
      for (int j = 0; j < 16; ++j) hv[j] += ev * s_w1[k][ng*16 + j];
    }
    #pragma unroll
    for (int c2 = 0; c2 < 2; ++c2){
      h8 o;
      #pragma unroll
      for (int j = 0; j < 8; ++j) o[j] = (_Float16)silu_f(hv[c2*8 + j]);
      const int chunk = (ng*2 + c2) ^ (e & 7);
      *(h8*)&s_actA[e][chunk*8] = o;
    }
  }
  __syncthreads();

  const int lane = tid & 63, wid = tid >> 6;
  const int li = lane & 15, kg = lane >> 4;

  // ---- L2 MFMA
  {
    h8 af[2];
    #pragma unroll
    for (int s = 0; s < 2; ++s)
      af[s] = *(const h8*)&Wr2T[(size_t)(wid*16 + li)*64 + s*32 + kg*8];
    #pragma unroll
    for (int nt = 0; nt < 4; ++nt){
      const int e = nt*16 + li;
      f32x4 acc = (f32x4){0,0,0,0};
      #pragma unroll
      for (int s = 0; s < 2; ++s){
        const h8 bf = *(const h8*)&s_actA[e][((s*4 + kg) ^ (e & 7))*8];
        acc = __builtin_amdgcn_mfma_f32_16x16x32_f16(af[s], bf, acc, 0, 0, 0);
      }
      #pragma unroll
      for (int r = 0; r < 4; ++r){
        const int n = wid*16 + kg*4 + r;
        s_actB[e][((n >> 3) ^ (e & 7))*8 + (n & 7)] = (_Float16)silu_f(acc[r]);
      }
    }
  }
  __syncthreads();

  // ---- L3 MFMA
  {
    h8 af[2];
    #pragma unroll
    for (int s = 0; s < 2; ++s)
      af[s] = *(const h8*)&Wr3T[(size_t)(wid*16 + li)*64 + s*32 + kg*8];
    #pragma unroll
    for (int nt = 0; nt < 4; ++nt){
      const int e = nt*16 + li;
      f32x4 acc = (f32x4){0,0,0,0};
      #pragma unroll
      for (int s = 0; s < 2; ++s){
        const h8 bf = *(const h8*)&s_actB[e][((s*4 + kg) ^ (e & 7))*8];
        acc = __builtin_amdgcn_mfma_f32_16x16x32_f16(af[s], bf, acc, 0, 0, 0);
      }
      #pragma unroll
      for (int r = 0; r < 4; ++r){
        const int n = wid*16 + kg*4 + r;
        s_actA[e][((n >> 3) ^ (e & 7))*8 + (n & 7)] = (_Float16)silu_f(acc[r]);
      }
    }
  }
  __syncthreads();

  // ---- tpw MFMA + xs multiply + store
  #pragma unroll
  for (int p = 0; p < 2; ++p){
    h8 bf[4][2];
    #pragma unroll
    for (int nt = 0; nt < 4; ++nt){
      const int e = nt*16 + li;
      #pragma unroll
      for (int s = 0; s < 2; ++s)
        bf[nt][s] = *(const h8*)&s_actA[e][((s*4 + kg) ^ (e & 7))*8];
    }
    #pragma unroll
    for (int mt = 0; mt < 4; ++mt){
      const int nbase = wid*128 + p*64 + mt*16;
      h8 af[2];
      #pragma unroll
      for (int s = 0; s < 2; ++s)
        af[s] = *(const h8*)&Wr4T[(size_t)(nbase + li)*64 + s*32 + kg*8];
      f32x4 acc[4];
      #pragma unroll
      for (int nt = 0; nt < 4; ++nt){
        acc[nt] = (f32x4){0,0,0,0};
        #pragma unroll
        for (int s = 0; s < 2; ++s)
          acc[nt] = __builtin_amdgcn_mfma_f32_16x16x32_f16(af[s], bf[nt][s], acc[nt], 0, 0, 0);
      }
      const int c0 = nbase + kg*4;
      const int u0 = c0 & 127;
      #pragma unroll
      for (int nt = 0; nt < 4; ++nt){
        const int e = nt*16 + li;
        const h4 xv = *(const h4*)&s_xs[e][u0];
        h4 ov;
        #pragma unroll
        for (int r = 0; r < 4; ++r) ov[r] = (_Float16)acc[nt][r] * xv[r];
        *(h4*)&w2h[(size_t)(E0 + e)*512 + c0] = ov;
      }
    }
  }
}

// ---------------------------------------------------------------- K3: gather per node — sequential CSR streams
__global__ __launch_bounds__(256) void k_gather(const float* __restrict__ ea,
                                                const _Float16* __restrict__ w2h,
                                                const float* __restrict__ dd,
                                                const float* __restrict__ Wsin,
                                                const int* __restrict__ off,
                                                const int* __restrict__ elist,
                                                float* __restrict__ msg){
  const int n = blockIdx.x, tid = threadIdx.x;
  const int beg = off[n], end = off[n + 1];
  const int ngrp = (end - beg + 15) >> 4;

  alignas(16) __shared__ _Float16 s_w2[16][512];
  alignas(16) __shared__ float s_sh[16][16];
  __shared__ float s_dd[16];
  __shared__ int   s_el[16];
  __shared__ float s_emb[32];
  __shared__ float s_rho;
  if (tid == 0) s_rho = 0.f;

  const int u = tid & 127, h = tid >> 7;
  float acc[8] = {0,0,0,0,0,0,0,0};

  for (int grp = 0; grp < ngrp; ++grp){
    const int pbase = beg + grp*16;
    if (tid < 16){
      const int p = pbase + tid;
      s_el[tid] = (p < end) ? elist[p] : -1;
      s_dd[tid] = (p < end) ? dd[p] : 0.f;
    }
    #pragma unroll
    for (int c2 = 0; c2 < 4; ++c2){
      const int chunk = c2*256 + tid;
      const int slot = chunk >> 6, part = chunk & 63;
      const int p = pbase + slot;
      h8 v = {};
      if (p < end) v = *(const h8*)&w2h[(size_t)p*512 + part*8];
      *(h8*)&s_w2[slot][part*8] = v;
    }
    __syncthreads();
    { const int slot = tid >> 4, j = tid & 15;
      const int e = s_el[slot];
      s_sh[slot][j] = (e >= 0) ? ea[(size_t)e*16 + j] : 0.f; }
    __syncthreads();

    if (h == 0){
      #pragma unroll
      for (int slot = 0; slot < 16; ++slot){
        const float wa = (float)s_w2[slot][u];
        const float wb = (float)s_w2[slot][128 + u];
        const float wc = (float)s_w2[slot][256 + u];
        const float4 sa = *(const float4*)&s_sh[slot][0];
        const float4 sb = *(const float4*)&s_sh[slot][4];
        acc[0] += wa * sa.x;
        acc[1] += wb * sa.y;  acc[2] += wb * sa.z;  acc[3] += wb * sa.w;
        acc[4] += wc * sb.x;  acc[5] += wc * sb.y;
        acc[6] += wc * sb.z;  acc[7] += wc * sb.w;
      }
    } else {
      #pragma unroll
      for (int slot = 0; slot < 16; ++slot){
        const float wc = (float)s_w2[slot][256 + u];
        const float wd = (float)s_w2[slot][384 + u];
        const float4 sa = *(const float4*)&s_sh[slot][8];
        const float4 sb = *(const float4*)&s_sh[slot][12];
        acc[0] += wc * sa.x;
        acc[1] += wd * sa.y;  acc[2] += wd * sa.z;  acc[3] += wd * sa.w;
        acc[4] += wd * sb.x;  acc[5] += wd * sb.y;
        acc[6] += wd * sb.z;  acc[7] += wd * sb.w;
      }
    }
    __syncthreads();
  }

  // rho reduce from s_dd? dd accumulated across groups in registers instead:
  // (simple version: recompute sum over the node's dd range with 64 lanes)
  float rsum = 0.f;
  for (int p = beg + tid; p < end; p += 256) rsum += dd[p];
  // block reduce rsum via LDS
  __shared__ float s_red[256];
  s_red[tid] = rsum;
  __syncthreads();
  for (int st = 128; st > 0; st >>= 1){
    if (tid < st) s_red[tid] += s_red[tid + st];
    __syncthreads();
  }
  const float rho  = s_red[0];
  const float tinv = 1.f / (rho + 1.f);
  if (tid < 16){
    const float fr  = expf(-0.28782313662425572f * (float)tid);  // ln(100)/16
    const float ang = rho * fr;
    s_emb[tid]      = sinf(ang);
    s_emb[tid + 16] = cosf(ang);
  }
  __syncthreads();
  float db = 0.f;
  if (h == 0){
    #pragma unroll
    for (int j = 0; j < 32; ++j) db += s_emb[j] * Wsin[j*128 + u];
  }
  #pragma unroll
  for (int j = 0; j < 8; ++j){
    float v = acc[j] * tinv;
    if (h == 0 && j == 0) v += db;
    msg[(size_t)n*2048 + (h*8 + j)*128 + u] = v;
  }
}

// ---------------------------------------------------------------- K4: final GEMM -> dense outD_l[row][w]
template<int L, int D>
__global__ __launch_bounds__(256) void k_final(const float* __restrict__ msg,
                                               const float* __restrict__ attrs,
                                               const _Float16* __restrict__ WC16T,
                                               float* __restrict__ outD){
  constexpr int OFF  = (L==0 ? 0 : L==1 ? 1 : L==2 ? 4 : 9);
  constexpr int ROWS = N_NODES * D;
  const int r0  = blockIdx.x * 128;
  const int tid = threadIdx.x;

  alignas(16) __shared__ _Float16 sA[128*128];
  alignas(16) __shared__ _Float16 sB[2][64*128];
  __shared__ _Float16 sAttr[128*10];

  {
    const int rl = tid >> 1, half = tid & 1;
    const int gr = r0 + rl;
    h8 vals[8];
    if (gr < ROWS){
      const int n = gr / D, k = gr - n*D;
      const float4* src = (const float4*)(msg + (size_t)n*2048 + (size_t)(OFF+k)*128 + half*64);
      #pragma unroll
      for (int j = 0; j < 8; ++j){
        const float4 v0 = src[j*2], v1 = src[j*2+1];
        h8 hv;
        hv[0]=(_Float16)v0.x; hv[1]=(_Float16)v0.y; hv[2]=(_Float16)v0.z; hv[3]=(_Float16)v0.w;
        hv[4]=(_Float16)v1.x; hv[5]=(_Float16)v1.y; hv[6]=(_Float16)v1.z; hv[7]=(_Float16)v1.w;
        vals[j] = hv;
      }
    } else {
      #pragma unroll
      for (int j = 0; j < 8; ++j) vals[j] = (h8){};
    }
    #pragma unroll
    for (int j = 0; j < 8; ++j){
      const int cu = half*8 + j;
      const int cs = (cu & 8) | ((cu & 7) ^ (rl & 7));
      *(h8*)&sA[rl*128 + cs*8] = vals[j];
    }
  }
  for (int i = tid; i < 1280; i += 256){
    const int rl = i / 10, aa = i - rl*10;
    const int gr = r0 + rl;
    sAttr[i] = (gr < ROWS) ? (_Float16)attrs[(gr / D)*10 + aa] : (_Float16)0.f;
  }
  {
    const int w = tid >> 1, part = tid & 1;
    const _Float16* src = WC16T + ((size_t)L*128 + w)*1280 + part*32;
    #pragma unroll
    for (int j = 0; j < 4; ++j){
      const h8 v = *(const h8*)(src + j*8);
      const int cc = part*4 + j;
      *(h8*)&sB[0][w*64 + (cc ^ (w & 7))*8] = v;
    }
  }
  __syncthreads();

  const int wid = tid >> 6, lane = tid & 63;
  const int wm = wid >> 1, wn = wid & 1;
  const int li = lane & 15, kg = lane >> 4;

  f32x4 acc[4][4];
  #pragma unroll
  for (int m = 0; m < 4; ++m)
    #pragma unroll
    for (int nn = 0; nn < 4; ++nn) acc[m][nn] = (f32x4){0,0,0,0};

  for (int step = 0; step < 20; ++step){
    const int cur = step & 1;
    const bool more = (step + 1 < 20);
    h8 pre[4];
    if (more){
      const int a2 = (step+1) >> 1, u02 = ((step+1) & 1) << 6;
      const _Float16* src = WC16T + ((size_t)L*128 + (tid>>1))*1280 + a2*128 + u02 + (tid&1)*32;
      #pragma unroll
      for (int j = 0; j < 4; ++j) pre[j] = *(const h8*)(src + j*8);
    }

    const int a  = step >> 1;
    const int uh = (step & 1) << 3;

    h8 afr[4][2], bfr[4][2];
    #pragma unroll
    for (int m = 0; m < 4; ++m){
      const int row = wm*64 + m*16 + li;
      const _Float16 av = sAttr[row*10 + a];
      h8 avx;
      #pragma unroll
      for (int j = 0; j < 8; ++j) avx[j] = av;
      #pragma unroll
      for (int s = 0; s < 2; ++s){
        const int ca = uh + s*4 + kg;
        const int cs = (ca & 8) | ((ca & 7) ^ (row & 7));
        const h8 mA = *(const h8*)&sA[row*128 + cs*8];
        afr[m][s] = mA * avx;
      }
    }
    #pragma unroll
    for (int nn = 0; nn < 4; ++nn){
      const int w = wn*64 + nn*16 + li;
      #pragma unroll
      for (int s = 0; s < 2; ++s){
        const int cb = s*4 + kg;
        bfr[nn][s] = *(const h8*)&sB[cur][w*64 + ((cb ^ (w & 7)))*8];
      }
    }
    #pragma unroll
    for (int s = 0; s < 2; ++s)
      #pragma unroll
      for (int m = 0; m < 4; ++m)
        #pragma unroll
        for (int nn = 0; nn < 4; ++nn)
          acc[m][nn] = __builtin_amdgcn_mfma_f32_16x16x32_f16(afr[m][s], bfr[nn][s], acc[m][nn], 0, 0, 0);

    if (more){
      const int w = tid >> 1, part = tid & 1;
      #pragma unroll
      for (int j = 0; j < 4; ++j){
        const int cc = part*4 + j;
        *(h8*)&sB[cur ^ 1][w*64 + (cc ^ (w & 7))*8] = pre[j];
      }
    }
    __syncthreads();
  }

  // dense coalesced epilogue
  #pragma unroll
  for (int m = 0; m < 4; ++m){
    const int rbase = r0 + wm*64 + m*16 + kg*4;
    #pragma unroll
    for (int rr = 0; rr < 4; ++rr){
      const int gr = rbase + rr;
      if (gr < ROWS){
        float* op = outD + (size_t)gr*128;
        #pragma unroll
        for (int nn = 0; nn < 4; ++nn)
          op[wn*64 + nn*16 + li] = acc[m][nn][rr];
      }
    }
  }
}

// ---------------------------------------------------------------- K5: merge dense outD_l into out[n][w][sk] full lines
__global__ __launch_bounds__(256) void k_merge(const float* __restrict__ outD,
                                               float* __restrict__ out){
  const int n0 = blockIdx.x * 4;
  const int tid = threadIdx.x;
  __shared__ float lds[4*16*132];   // [nloc][sk][w] stride 132

  // l=0: 4 rows
  {
    const float4* src = (const float4*)(outD + (size_t)n0*128);
    for (int j = tid; j < 128; j += 256){
      const int row = j >> 5, c4 = j & 31;        // row = nloc, sk=0
      *(float4*)&lds[(row*16 + 0)*132 + c4*4] = src[j];
    }
  }
  // l=1: 12 rows
  {
    const float4* src = (const float4*)(outD + 1280000 + (size_t)n0*3*128);
    for (int j = tid; j < 384; j += 256){
      const int row = j >> 5, c4 = j & 31;
      const int nloc = row/3, k = row - nloc*3;
      *(float4*)&lds[(nloc*16 + 1 + k)*132 + c4*4] = src[j];
    }
  }
  // l=2: 20 rows
  {
    const float4* src = (const float4*)(outD + 5120000 + (size_t)n0*5*128);
    for (int j = tid; j < 640; j += 256){
      const int row = j >> 5, c4 = j & 31;
      const int nloc = row/5, k = row - nloc*5;
      *(float4*)&lds[(nloc*16 + 4 + k)*132 + c4*4] = src[j];
    }
  }
  // l=3: 28 rows
  {
    const float4* src = (const float4*)(outD + 11520000 + (size_t)n0*7*128);
    for (int j = tid; j < 896; j += 256){
      const int row = j >> 5, c4 = j & 31;
      const int nloc = row/7, k = row - nloc*7;
      *(float4*)&lds[(nloc*16 + 9 + k)*132 + c4*4] = src[j];
    }
  }
  __syncthreads();

  for (int j = tid; j < 2048; j += 256){
    const int nloc = j >> 9, q = j & 511;
    const int w = q >> 2, s0 = (q & 3) << 2;
    float4 v;
    v.x = lds[(nloc*16 + s0 + 0)*132 + w];
    v.y = lds[(nloc*16 + s0 + 1)*132 + w];
    v.z = lds[(nloc*16 + s0 + 2)*132 + w];
    v.w = lds[(nloc*16 + s0 + 3)*132 + w];
    *(float4*)&out[(size_t)(n0 + nloc)*2048 + q*4] = v;
  }
}

// ----------------------------------------------------------------
extern "C" void kernel_launch(void* const* d_in, const int* in_sizes, int n_in,
                              void* d_out, int out_size, void* d_ws, size_t ws_size,
                              hipStream_t stream){
  const float* node_attrs = (const float*)d_in[0];
  const float* node_feats = (const float*)d_in[1];
  const float* edge_attrs = (const float*)d_in[2];
  const float* edge_feats = (const float*)d_in[3];
  const int*   edge_index = (const int*)d_in[4];
  const float* W_up  = (const float*)d_in[5];
  const float* Wr1   = (const float*)d_in[6];
  const float* Wr2   = (const float*)d_in[7];
  const float* Wr3   = (const float*)d_in[8];
  const float* Wr4   = (const float*)d_in[9];
  const float* Wd    = (const float*)d_in[10];
  const float* Wsin  = (const float*)d_in[11];
  const float* Wlin  = (const float*)d_in[12];
  const float* Wskip = (const float*)d_in[13];
  float* out = (float*)d_out;

  _Float16* w2h  = (_Float16*)d_ws;                 // 81,920,000 halfs (reused as outD)
  float* msg     = (float*)(w2h + 81920000);        // 20,480,000 f32
  float* x       = msg + 20480000;                  //  1,280,000 f32
  float* ddv     = x + 1280000;                     //    160,000 f32
  _Float16* WC16T= (_Float16*)(ddv + 160000);       //    655,360 halfs
  int* cnt   = (int*)(WC16T + 655360);              //     10,000
  int* off   = cnt + 10000;                         //     10,016
  int* cur   = off + 10016;                         //     10,000
  int* elist = cur + 10000;                         //    160,000
  _Float16* Wr2T = (_Float16*)(elist + 160000);     //      4,096 halfs
  _Float16* Wr3T = Wr2T + 4096;                     //      4,096 halfs
  _Float16* Wr4T = Wr3T + 4096;                     //     32,768 halfs
  _Float16* WupT = Wr4T + 32768;                    //     16,384 halfs
  float* outD = (float*)w2h;                        // alias: dead after k_gather

  hipMemsetAsync(cnt, 0, (size_t)10000 * sizeof(int), stream);

  k_prep<<<224, 256, 0, stream>>>(Wr2, Wr3, Wr4, W_up, Wr2T, Wr3T, Wr4T, WupT);
  k_node_up<<<157, 256, 0, stream>>>(node_feats, WupT, x);
  k_wc<<<512, 256, 0, stream>>>(Wlin, Wskip, WC16T);

  k_count <<<(N_EDGES + 255)/256, 256, 0, stream>>>(edge_index, cnt);
  k_scan  <<<1, 256, 0, stream>>>(cnt, off, cur);
  k_bucket<<<(N_EDGES + 255)/256, 256, 0, stream>>>(edge_index, cur, elist);

  k_edge_mlp<<<N_EDGES/64, 256, 0, stream>>>(edge_feats, edge_index, elist, x,
                                             Wr1, Wd, Wr2T, Wr3T, Wr4T, w2h, ddv);

  k_gather<<<N_NODES, 256, 0, stream>>>(edge_attrs, w2h, ddv, Wsin,
                                        off, elist, msg);

  k_final<0,1><<<(N_NODES*1 + 127)/128, 256, 0, stream>>>(msg, node_attrs, WC16T, outD);
  k_final<1,3><<<(N_NODES*3 + 127)/128, 256, 0, stream>>>(msg, node_attrs, WC16T, outD + 1280000);
  k_final<2,5><<<(N_NODES*5 + 127)/128, 256, 0, stream>>>(msg, node_attrs, WC16T, outD + 5120000);
  k_final<3,7><<<(N_NODES*7 + 127)/128, 256, 0, stream>>>(msg, node_attrs, WC16T, outD + 11520000);

  k_merge<<<2500, 256, 0, stream>>>(outD, out);
}

// Round 7
// 415.714 us; speedup vs baseline: 5.6549x; 1.0840x over previous
//
#include <hip/hip_runtime.h>
#include <hip/hip_bf16.h>

#define N_NODES 10000
#define N_EDGES 160000

typedef _Float16 h8 __attribute__((ext_vector_type(8)));
typedef _Float16 h4 __attribute__((ext_vector_type(4)));
typedef float f32x4 __attribute__((ext_vector_type(4)));

__device__ __forceinline__ float silu_f(float v){ return v / (1.f + expf(-v)); }

// ---------------------------------------------------------------- K1: x = nf @ Wup/sqrt(128) via MFMA, 64 nodes/block
__global__ __launch_bounds__(256) void k_node_up(const float* __restrict__ nf,
                                                 const _Float16* __restrict__ WupT,
                                                 float* __restrict__ x){
  const int n0 = blockIdx.x * 64;
  const int tid = threadIdx.x;
  alignas(16) __shared__ _Float16 s_nf[64*128];
  alignas(16) __shared__ _Float16 s_wt[128*128];

  {
    const int rl = tid >> 2, part = tid & 3;
    const int gr = n0 + rl;
    #pragma unroll
    for (int j = 0; j < 4; ++j){
      const int cu = part*4 + j;
      h8 hv = (h8){};
      if (gr < N_NODES){
        const float4 v0 = *(const float4*)(nf + (size_t)gr*128 + cu*8);
        const float4 v1 = *(const float4*)(nf + (size_t)gr*128 + cu*8 + 4);
        hv[0]=(_Float16)v0.x; hv[1]=(_Float16)v0.y; hv[2]=(_Float16)v0.z; hv[3]=(_Float16)v0.w;
        hv[4]=(_Float16)v1.x; hv[5]=(_Float16)v1.y; hv[6]=(_Float16)v1.z; hv[7]=(_Float16)v1.w;
      }
      const int cs = (cu & 8) | ((cu & 7) ^ (rl & 7));
      *(h8*)&s_nf[rl*128 + cs*8] = hv;
    }
  }
  {
    const int rl = tid >> 1, part = tid & 1;
    #pragma unroll
    for (int j = 0; j < 8; ++j){
      const int cu = part*8 + j;
      const h8 v = *(const h8*)&WupT[(size_t)rl*128 + cu*8];
      const int cs = (cu & 8) | ((cu & 7) ^ (rl & 7));
      *(h8*)&s_wt[rl*128 + cs*8] = v;
    }
  }
  __syncthreads();

  const int wid = tid >> 6, lane = tid & 63;
  const int li = lane & 15, kg = lane >> 4;

  f32x4 acc[8];
  #pragma unroll
  for (int i = 0; i < 8; ++i) acc[i] = (f32x4){0,0,0,0};

  const int row = wid*16 + li;
  #pragma unroll
  for (int s = 0; s < 4; ++s){
    const int ca = s*4 + kg;
    const int csA = (ca & 8) | ((ca & 7) ^ (row & 7));
    const h8 af = *(const h8*)&s_nf[row*128 + csA*8];
    #pragma unroll
    for (int nt = 0; nt < 8; ++nt){
      const int u = nt*16 + li;
      const int csB = (ca & 8) | ((ca & 7) ^ (u & 7));
      const h8 bf = *(const h8*)&s_wt[u*128 + csB*8];
      acc[nt] = __builtin_amdgcn_mfma_f32_16x16x32_f16(af, bf, acc[nt], 0, 0, 0);
    }
  }
  #pragma unroll
  for (int nt = 0; nt < 8; ++nt){
    #pragma unroll
    for (int r = 0; r < 4; ++r){
      const int gr = n0 + wid*16 + kg*4 + r;
      if (gr < N_NODES) x[(size_t)gr*128 + nt*16 + li] = acc[nt][r];
    }
  }
}

// ---------------------------------------------------------------- K1b: WC16T[l][w][a*128+u]
__global__ __launch_bounds__(256) void k_wc(const float* __restrict__ Wlin,
                                            const float* __restrict__ Wskip,
                                            _Float16* __restrict__ WC16T){
  const int lu = blockIdx.x;           // l*128 + u
  const int l  = lu >> 7, u = lu & 127;
  __shared__ float wl[128];
  if (threadIdx.x < 128) wl[threadIdx.x] = Wlin[lu*128 + threadIdx.x];
  __syncthreads();
  const float* Wsk = Wskip + (size_t)l * 163840;   // [v][a][w]
  for (int i = threadIdx.x; i < 1280; i += 256){   // i = a*128 + w
    float acc = 0.f;
    #pragma unroll 16
    for (int v = 0; v < 128; ++v) acc += wl[v] * Wsk[v*1280 + i];
    const int a = i >> 7, w = i & 127;
    WC16T[((size_t)l*128 + w)*1280 + a*128 + u] =
        (_Float16)(acc * 0.0024705294220065465f);  // 1/sqrt(128*1280)
  }
}

// ---------------------------------------------------------------- K1c: pre-transposed fp16 weights (scales folded)
__global__ __launch_bounds__(256) void k_prep(const float* __restrict__ Wr2,
                                              const float* __restrict__ Wr3,
                                              const float* __restrict__ Wr4,
                                              const float* __restrict__ Wup,
                                              _Float16* __restrict__ Wr2T,
                                              _Float16* __restrict__ Wr3T,
                                              _Float16* __restrict__ Wr4T,
                                              _Float16* __restrict__ WupT){
  const int idx = blockIdx.x*256 + threadIdx.x;
  if (idx < 4096){
    const int n = idx >> 6, k = idx & 63;
    Wr2T[idx] = (_Float16)(Wr2[k*64 + n] * 0.125f);
  } else if (idx < 8192){
    const int j = idx - 4096;
    const int n = j >> 6, k = j & 63;
    Wr3T[j] = (_Float16)(Wr3[k*64 + n] * 0.125f);
  } else if (idx < 40960){
    const int j = idx - 8192;
    const int n = j >> 6, k = j & 63;
    Wr4T[j] = (_Float16)(Wr4[k*512 + n] * 0.125f);
  } else if (idx < 57344){
    const int j = idx - 40960;
    const int u = j >> 7, k = j & 127;
    WupT[j] = (_Float16)(Wup[k*128 + u] * 0.08838834764831843f);
  }
}

// ---------------------------------------------------------------- CSR build
__global__ __launch_bounds__(256) void k_count(const int* __restrict__ eidx,
                                               int* __restrict__ cnt){
  const int e = blockIdx.x * 256 + threadIdx.x;
  if (e < N_EDGES) atomicAdd(&cnt[eidx[N_EDGES + e]], 1);
}

__global__ __launch_bounds__(256) void k_scan(const int* __restrict__ cnt,
                                              int* __restrict__ off,
                                              int* __restrict__ cur){
  __shared__ int sums[256];
  const int t = threadIdx.x;
  const int base = t * 40;
  int s = 0;
  for (int i = 0; i < 40; ++i){
    const int idx = base + i;
    if (idx < N_NODES) s += cnt[idx];
  }
  sums[t] = s;
  __syncthreads();
  for (int st = 1; st < 256; st <<= 1){
    const int v = (t >= st) ? sums[t - st] : 0;
    __syncthreads();
    sums[t] += v;
    __syncthreads();
  }
  int pre = (t > 0) ? sums[t - 1] : 0;
  for (int i = 0; i < 40; ++i){
    const int idx = base + i;
    if (idx < N_NODES){
      off[idx] = pre; cur[idx] = pre;
      pre += cnt[idx];
    }
  }
  if (t == 255) off[N_NODES] = sums[255];
}

__global__ __launch_bounds__(256) void k_bucket(const int* __restrict__ eidx,
                                                int* __restrict__ cur,
                                                int* __restrict__ elist,
                                                int* __restrict__ esnd){
  const int e = blockIdx.x * 256 + threadIdx.x;
  if (e < N_EDGES){
    const int pos = atomicAdd(&cur[eidx[N_EDGES + e]], 1);
    elist[pos] = e;
    esnd[pos]  = eidx[e];
  }
}

// ---------------------------------------------------------------- K2: FUSED edge MLP + gather. Block owns 4 whole nodes.
// Per 32-edge group: MLP (MFMA) -> s_w2[32][512]; accumulate into per-node regs.
__global__ __launch_bounds__(256) void k_fused(const float* __restrict__ ef,
                                               const float* __restrict__ ea,
                                               const float* __restrict__ x,
                                               const float* __restrict__ Wr1,
                                               const float* __restrict__ Wd,
                                               const _Float16* __restrict__ Wr2T,
                                               const _Float16* __restrict__ Wr3T,
                                               const _Float16* __restrict__ Wr4T,
                                               const float* __restrict__ Wsin,
                                               const int* __restrict__ off,
                                               const int* __restrict__ elist,
                                               const int* __restrict__ esnd,
                                               float* __restrict__ msg){
  const int n0 = blockIdx.x * 4;
  const int tid = threadIdx.x;
  const int lane = tid & 63, wid = tid >> 6;
  const int li = lane & 15, kg = lane >> 4;
  const int u = tid & 127, h = tid >> 7;

  __shared__ int   s_eid[32];
  __shared__ float s_ef[32][8];
  __shared__ float s_w1[8][64];
  alignas(16) __shared__ _Float16 s_xs[32][136];
  alignas(16) __shared__ _Float16 s_actA[32][64];
  alignas(16) __shared__ _Float16 s_actB[32][64];
  alignas(16) __shared__ _Float16 s_w2[32][520];
  alignas(16) __shared__ float s_sh[32][16];
  __shared__ float s_dd[32];
  __shared__ float s_rho[4];
  __shared__ int   s_offs[5];
  __shared__ float s_emb[4][32];

  if (tid < 5) s_offs[tid] = off[n0 + tid];
  if (tid < 4) s_rho[tid] = 0.f;
  for (int j = tid; j < 512; j += 256) s_w1[j >> 6][j & 63] = Wr1[j];
  __syncthreads();

  const int beg = s_offs[0], end = s_offs[4];
  const int ngrp = (end - beg + 31) >> 5;

  float a0[8] = {0,0,0,0,0,0,0,0};
  float a1[8] = {0,0,0,0,0,0,0,0};
  float a2[8] = {0,0,0,0,0,0,0,0};
  float a3[8] = {0,0,0,0,0,0,0,0};

  for (int grp = 0; grp < ngrp; ++grp){
    const int pbase = beg + grp*32;

    if (tid < 32){
      const int p = pbase + tid;
      s_eid[tid] = (p < end) ? elist[p] : -1;
    }
    __syncthreads();

    // ---- stage ef, xs, sh
    {
      const int e = tid >> 3, i = tid & 7;
      const int eid = s_eid[e];
      s_ef[e][i] = (eid >= 0) ? ef[(size_t)eid*8 + i] : 0.f;
    }
    {
      const int e = tid >> 3, q = tid & 7;
      const int p = pbase + e;
      const int snd = (p < end) ? esnd[p] : 0;
      const float4* xp = (const float4*)(x + (size_t)snd*128 + q*16);
      #pragma unroll
      for (int j = 0; j < 4; ++j){
        const float4 v = xp[j];
        h4 hv; hv[0]=(_Float16)v.x; hv[1]=(_Float16)v.y; hv[2]=(_Float16)v.z; hv[3]=(_Float16)v.w;
        *(h4*)&s_xs[e][q*16 + j*4] = hv;
      }
    }
    #pragma unroll
    for (int c2 = 0; c2 < 2; ++c2){
      const int idx = c2*256 + tid;
      const int slot = idx >> 4, jj = idx & 15;
      const int eid = s_eid[slot];
      s_sh[slot][jj] = (eid >= 0) ? ea[(size_t)eid*16 + jj] : 0.f;
    }
    __syncthreads();

    // ---- dd
    if (tid < 32){
      float s = 0.f;
      #pragma unroll
      for (int i = 0; i < 8; ++i) s += s_ef[tid][i] * Wd[i];
      s_dd[tid] = tanhf(s*s);
    }

    // ---- L1 (VALU, K=8): 32e x 64n, thread owns (e, 8 n's)
    {
      const int e = tid >> 3, ng = tid & 7;
      float hv[8] = {0,0,0,0,0,0,0,0};
      #pragma unroll
      for (int k = 0; k < 8; ++k){
        const float ev = s_ef[e][k] * 0.3535533905932738f;
        #pragma unroll
        for (int j = 0; j < 8; ++j) hv[j] += ev * s_w1[k][ng*8 + j];
      }
      h8 o;
      #pragma unroll
      for (int j = 0; j < 8; ++j) o[j] = (_Float16)silu_f(hv[j]);
      *(h8*)&s_actA[e][(ng ^ (e & 7))*8] = o;
    }
    __syncthreads();

    // ---- L2 MFMA: 64n x 32e
    {
      h8 af[2];
      #pragma unroll
      for (int s = 0; s < 2; ++s)
        af[s] = *(const h8*)&Wr2T[(size_t)(wid*16 + li)*64 + s*32 + kg*8];
      #pragma unroll
      for (int nt = 0; nt < 2; ++nt){
        const int e = nt*16 + li;
        f32x4 acc = (f32x4){0,0,0,0};
        #pragma unroll
        for (int s = 0; s < 2; ++s){
          const h8 bf = *(const h8*)&s_actA[e][((s*4 + kg) ^ (e & 7))*8];
          acc = __builtin_amdgcn_mfma_f32_16x16x32_f16(af[s], bf, acc, 0, 0, 0);
        }
        #pragma unroll
        for (int r = 0; r < 4; ++r){
          const int n = wid*16 + kg*4 + r;
          s_actB[e][((n >> 3) ^ (e & 7))*8 + (n & 7)] = (_Float16)silu_f(acc[r]);
        }
      }
    }
    __syncthreads();

    // ---- L3 MFMA
    {
      h8 af[2];
      #pragma unroll
      for (int s = 0; s < 2; ++s)
        af[s] = *(const h8*)&Wr3T[(size_t)(wid*16 + li)*64 + s*32 + kg*8];
      #pragma unroll
      for (int nt = 0; nt < 2; ++nt){
        const int e = nt*16 + li;
        f32x4 acc = (f32x4){0,0,0,0};
        #pragma unroll
        for (int s = 0; s < 2; ++s){
          const h8 bf = *(const h8*)&s_actB[e][((s*4 + kg) ^ (e & 7))*8];
          acc = __builtin_amdgcn_mfma_f32_16x16x32_f16(af[s], bf, acc, 0, 0, 0);
        }
        #pragma unroll
        for (int r = 0; r < 4; ++r){
          const int n = wid*16 + kg*4 + r;
          s_actA[e][((n >> 3) ^ (e & 7))*8 + (n & 7)] = (_Float16)silu_f(acc[r]);
        }
      }
    }
    __syncthreads();

    // ---- tpw MFMA: 512c x 32e -> s_w2 = tpw*xs
    {
      h8 bf[2][2];
      #pragma unroll
      for (int nt = 0; nt < 2; ++nt){
        const int e = nt*16 + li;
        #pragma unroll
        for (int s = 0; s < 2; ++s)
          bf[nt][s] = *(const h8*)&s_actA[e][((s*4 + kg) ^ (e & 7))*8];
      }
      #pragma unroll
      for (int mt = 0; mt < 8; ++mt){
        const int nbase = wid*128 + mt*16;
        h8 af[2];
        #pragma unroll
        for (int s = 0; s < 2; ++s)
          af[s] = *(const h8*)&Wr4T[(size_t)(nbase + li)*64 + s*32 + kg*8];
        f32x4 acc[2];
        #pragma unroll
        for (int nt = 0; nt < 2; ++nt){
          acc[nt] = (f32x4){0,0,0,0};
          #pragma unroll
          for (int s = 0; s < 2; ++s)
            acc[nt] = __builtin_amdgcn_mfma_f32_16x16x32_f16(af[s], bf[nt][s], acc[nt], 0, 0, 0);
        }
        const int c0 = nbase + kg*4;
        const int u0 = c0 & 127;
        #pragma unroll
        for (int nt = 0; nt < 2; ++nt){
          const int e = nt*16 + li;
          const h4 xv = *(const h4*)&s_xs[e][u0];
          h4 ov;
          #pragma unroll
          for (int r = 0; r < 4; ++r) ov[r] = (_Float16)acc[nt][r] * xv[r];
          *(h4*)&s_w2[e][c0] = ov;
        }
      }
    }
    __syncthreads();

    // ---- accumulate into per-node registers (slot ranges from CSR offsets)
    int lo0 = s_offs[0] - pbase; lo0 = lo0 < 0 ? 0 : lo0;
    int hi0 = s_offs[1] - pbase; hi0 = hi0 > 32 ? 32 : (hi0 < 0 ? 0 : hi0);
    int lo1 = s_offs[1] - pbase; lo1 = lo1 < 0 ? 0 : lo1;
    int hi1 = s_offs[2] - pbase; hi1 = hi1 > 32 ? 32 : (hi1 < 0 ? 0 : hi1);
    int lo2 = s_offs[2] - pbase; lo2 = lo2 < 0 ? 0 : lo2;
    int hi2 = s_offs[3] - pbase; hi2 = hi2 > 32 ? 32 : (hi2 < 0 ? 0 : hi2);
    int lo3 = s_offs[3] - pbase; lo3 = lo3 < 0 ? 0 : lo3;
    int hi3 = s_offs[4] - pbase; hi3 = hi3 > 32 ? 32 : (hi3 < 0 ? 0 : hi3);

#define ACC_H0(A, LO, HI)                                            \
    for (int s = (LO); s < (HI); ++s){                               \
      const float wa  = (float)s_w2[s][u];                           \
      const float wb  = (float)s_w2[s][128 + u];                     \
      const float wcv = (float)s_w2[s][256 + u];                     \
      const float4 sa = *(const float4*)&s_sh[s][0];                 \
      const float4 sb = *(const float4*)&s_sh[s][4];                 \
      A[0] += wa*sa.x;                                               \
      A[1] += wb*sa.y;  A[2] += wb*sa.z;  A[3] += wb*sa.w;           \
      A[4] += wcv*sb.x; A[5] += wcv*sb.y;                            \
      A[6] += wcv*sb.z; A[7] += wcv*sb.w;                            \
    }
#define ACC_H1(A, LO, HI)                                            \
    for (int s = (LO); s < (HI); ++s){                               \
      const float wcv = (float)s_w2[s][256 + u];                     \
      const float wd  = (float)s_w2[s][384 + u];                     \
      const float4 sa = *(const float4*)&s_sh[s][8];                 \
      const float4 sb = *(const float4*)&s_sh[s][12];                \
      A[0] += wcv*sa.x;                                              \
      A[1] += wd*sa.y;  A[2] += wd*sa.z;  A[3] += wd*sa.w;           \
      A[4] += wd*sb.x;  A[5] += wd*sb.y;                             \
      A[6] += wd*sb.z;  A[7] += wd*sb.w;                             \
    }

    if (h == 0){
      ACC_H0(a0, lo0, hi0) ACC_H0(a1, lo1, hi1)
      ACC_H0(a2, lo2, hi2) ACC_H0(a3, lo3, hi3)
    } else {
      ACC_H1(a0, lo0, hi0) ACC_H1(a1, lo1, hi1)
      ACC_H1(a2, lo2, hi2) ACC_H1(a3, lo3, hi3)
    }

    if (tid < 4){
      int lo = s_offs[tid]     - pbase; lo = lo < 0 ? 0 : lo;
      int hi = s_offs[tid + 1] - pbase; hi = hi > 32 ? 32 : (hi < 0 ? 0 : hi);
      float r = 0.f;
      for (int s = lo; s < hi; ++s) r += s_dd[s];
      s_rho[tid] += r;
    }
    __syncthreads();
  }

  // ---- epilogue: per-node rho -> emb, tinv; write msg
  if (tid < 64){
    const int ni = tid >> 4, f = tid & 15;
    const float fr  = expf(-0.28782313662425572f * (float)f);  // ln(100)/16
    const float ang = s_rho[ni] * fr;
    s_emb[ni][f]      = sinf(ang);
    s_emb[ni][f + 16] = cosf(ang);
  }
  __syncthreads();

  float db0 = 0.f, db1 = 0.f, db2 = 0.f, db3 = 0.f;
  if (h == 0){
    #pragma unroll 8
    for (int j = 0; j < 32; ++j){
      const float wsv = Wsin[j*128 + u];
      db0 += s_emb[0][j]*wsv; db1 += s_emb[1][j]*wsv;
      db2 += s_emb[2][j]*wsv; db3 += s_emb[3][j]*wsv;
    }
  }
  const float t0 = 1.f/(s_rho[0]+1.f), t1 = 1.f/(s_rho[1]+1.f);
  const float t2 = 1.f/(s_rho[2]+1.f), t3 = 1.f/(s_rho[3]+1.f);
  #pragma unroll
  for (int j = 0; j < 8; ++j){
    float v0 = a0[j]*t0, v1 = a1[j]*t1, v2 = a2[j]*t2, v3 = a3[j]*t3;
    if (h == 0 && j == 0){ v0 += db0; v1 += db1; v2 += db2; v3 += db3; }
    const size_t base = (size_t)(h*8 + j)*128 + u;
    msg[(size_t)(n0+0)*2048 + base] = v0;
    msg[(size_t)(n0+1)*2048 + base] = v1;
    msg[(size_t)(n0+2)*2048 + base] = v2;
    msg[(size_t)(n0+3)*2048 + base] = v3;
  }
}

// ---------------------------------------------------------------- K4: final GEMM -> dense outD_l[row][w]
template<int L, int D>
__global__ __launch_bounds__(256) void k_final(const float* __restrict__ msg,
                                               const float* __restrict__ attrs,
                                               const _Float16* __restrict__ WC16T,
                                               float* __restrict__ outD){
  constexpr int OFF  = (L==0 ? 0 : L==1 ? 1 : L==2 ? 4 : 9);
  constexpr int ROWS = N_NODES * D;
  const int r0  = blockIdx.x * 128;
  const int tid = threadIdx.x;

  alignas(16) __shared__ _Float16 sA[128*128];
  alignas(16) __shared__ _Float16 sB[2][64*128];
  __shared__ _Float16 sAttr[128*10];

  {
    const int rl = tid >> 1, half = tid & 1;
    const int gr = r0 + rl;
    h8 vals[8];
    if (gr < ROWS){
      const int n = gr / D, k = gr - n*D;
      const float4* src = (const float4*)(msg + (size_t)n*2048 + (size_t)(OFF+k)*128 + half*64);
      #pragma unroll
      for (int j = 0; j < 8; ++j){
        const float4 v0 = src[j*2], v1 = src[j*2+1];
        h8 hv;
        hv[0]=(_Float16)v0.x; hv[1]=(_Float16)v0.y; hv[2]=(_Float16)v0.z; hv[3]=(_Float16)v0.w;
        hv[4]=(_Float16)v1.x; hv[5]=(_Float16)v1.y; hv[6]=(_Float16)v1.z; hv[7]=(_Float16)v1.w;
        vals[j] = hv;
      }
    } else {
      #pragma unroll
      for (int j = 0; j < 8; ++j) vals[j] = (h8){};
    }
    #pragma unroll
    for (int j = 0; j < 8; ++j){
      const int cu = half*8 + j;
      const int cs = (cu & 8) | ((cu & 7) ^ (rl & 7));
      *(h8*)&sA[rl*128 + cs*8] = vals[j];
    }
  }
  for (int i = tid; i < 1280; i += 256){
    const int rl = i / 10, aa = i - rl*10;
    const int gr = r0 + rl;
    sAttr[i] = (gr < ROWS) ? (_Float16)attrs[(gr / D)*10 + aa] : (_Float16)0.f;
  }
  {
    const int w = tid >> 1, part = tid & 1;
    const _Float16* src = WC16T + ((size_t)L*128 + w)*1280 + part*32;
    #pragma unroll
    for (int j = 0; j < 4; ++j){
      const h8 v = *(const h8*)(src + j*8);
      const int cc = part*4 + j;
      *(h8*)&sB[0][w*64 + (cc ^ (w & 7))*8] = v;
    }
  }
  __syncthreads();

  const int wid = tid >> 6, lane = tid & 63;
  const int wm = wid >> 1, wn = wid & 1;
  const int li = lane & 15, kg = lane >> 4;

  f32x4 acc[4][4];
  #pragma unroll
  for (int m = 0; m < 4; ++m)
    #pragma unroll
    for (int nn = 0; nn < 4; ++nn) acc[m][nn] = (f32x4){0,0,0,0};

  for (int step = 0; step < 20; ++step){
    const int cur = step & 1;
    const bool more = (step + 1 < 20);
    h8 pre[4];
    if (more){
      const int a2 = (step+1) >> 1, u02 = ((step+1) & 1) << 6;
      const _Float16* src = WC16T + ((size_t)L*128 + (tid>>1))*1280 + a2*128 + u02 + (tid&1)*32;
      #pragma unroll
      for (int j = 0; j < 4; ++j) pre[j] = *(const h8*)(src + j*8);
    }

    const int a  = step >> 1;
    const int uh = (step & 1) << 3;

    h8 afr[4][2], bfr[4][2];
    #pragma unroll
    for (int m = 0; m < 4; ++m){
      const int row = wm*64 + m*16 + li;
      const _Float16 av = sAttr[row*10 + a];
      h8 avx;
      #pragma unroll
      for (int j = 0; j < 8; ++j) avx[j] = av;
      #pragma unroll
      for (int s = 0; s < 2; ++s){
        const int ca = uh + s*4 + kg;
        const int cs = (ca & 8) | ((ca & 7) ^ (row & 7));
        const h8 mA = *(const h8*)&sA[row*128 + cs*8];
        afr[m][s] = mA * avx;
      }
    }
    #pragma unroll
    for (int nn = 0; nn < 4; ++nn){
      const int w = wn*64 + nn*16 + li;
      #pragma unroll
      for (int s = 0; s < 2; ++s){
        const int cb = s*4 + kg;
        bfr[nn][s] = *(const h8*)&sB[cur][w*64 + ((cb ^ (w & 7)))*8];
      }
    }
    #pragma unroll
    for (int s = 0; s < 2; ++s)
      #pragma unroll
      for (int m = 0; m < 4; ++m)
        #pragma unroll
        for (int nn = 0; nn < 4; ++nn)
          acc[m][nn] = __builtin_amdgcn_mfma_f32_16x16x32_f16(afr[m][s], bfr[nn][s], acc[m][nn], 0, 0, 0);

    if (more){
      const int w = tid >> 1, part = tid & 1;
      #pragma unroll
      for (int j = 0; j < 4; ++j){
        const int cc = part*4 + j;
        *(h8*)&sB[cur ^ 1][w*64 + (cc ^ (w & 7))*8] = pre[j];
      }
    }
    __syncthreads();
  }

  #pragma unroll
  for (int m = 0; m < 4; ++m){
    const int rbase = r0 + wm*64 + m*16 + kg*4;
    #pragma unroll
    for (int rr = 0; rr < 4; ++rr){
      const int gr = rbase + rr;
      if (gr < ROWS){
        float* op = outD + (size_t)gr*128;
        #pragma unroll
        for (int nn = 0; nn < 4; ++nn)
          op[wn*64 + nn*16 + li] = acc[m][nn][rr];
      }
    }
  }
}

// ---------------------------------------------------------------- K5: merge dense outD_l into out[n][w][sk] full lines
__global__ __launch_bounds__(256) void k_merge(const float* __restrict__ outD,
                                               float* __restrict__ out){
  const int n0 = blockIdx.x * 4;
  const int tid = threadIdx.x;
  __shared__ float lds[4*16*132];   // [nloc][sk][w] stride 132

  {
    const float4* src = (const float4*)(outD + (size_t)n0*128);
    for (int j = tid; j < 128; j += 256){
      const int row = j >> 5, c4 = j & 31;
      *(float4*)&lds[(row*16 + 0)*132 + c4*4] = src[j];
    }
  }
  {
    const float4* src = (const float4*)(outD + 1280000 + (size_t)n0*3*128);
    for (int j = tid; j < 384; j += 256){
      const int row = j >> 5, c4 = j & 31;
      const int nloc = row/3, k = row - nloc*3;
      *(float4*)&lds[(nloc*16 + 1 + k)*132 + c4*4] = src[j];
    }
  }
  {
    const float4* src = (const float4*)(outD + 5120000 + (size_t)n0*5*128);
    for (int j = tid; j < 640; j += 256){
      const int row = j >> 5, c4 = j & 31;
      const int nloc = row/5, k = row - nloc*5;
      *(float4*)&lds[(nloc*16 + 4 + k)*132 + c4*4] = src[j];
    }
  }
  {
    const float4* src = (const float4*)(outD + 11520000 + (size_t)n0*7*128);
    for (int j = tid; j < 896; j += 256){
      const int row = j >> 5, c4 = j & 31;
      const int nloc = row/7, k = row - nloc*7;
      *(float4*)&lds[(nloc*16 + 9 + k)*132 + c4*4] = src[j];
    }
  }
  __syncthreads();

  for (int j = tid; j < 2048; j += 256){
    const int nloc = j >> 9, q = j & 511;
    const int w = q >> 2, s0 = (q & 3) << 2;
    float4 v;
    v.x = lds[(nloc*16 + s0 + 0)*132 + w];
    v.y = lds[(nloc*16 + s0 + 1)*132 + w];
    v.z = lds[(nloc*16 + s0 + 2)*132 + w];
    v.w = lds[(nloc*16 + s0 + 3)*132 + w];
    *(float4*)&out[(size_t)(n0 + nloc)*2048 + q*4] = v;
  }
}

// ----------------------------------------------------------------
extern "C" void kernel_launch(void* const* d_in, const int* in_sizes, int n_in,
                              void* d_out, int out_size, void* d_ws, size_t ws_size,
                              hipStream_t stream){
  const float* node_attrs = (const float*)d_in[0];
  const float* node_feats = (const float*)d_in[1];
  const float* edge_attrs = (const float*)d_in[2];
  const float* edge_feats = (const float*)d_in[3];
  const int*   edge_index = (const int*)d_in[4];
  const float* W_up  = (const float*)d_in[5];
  const float* Wr1   = (const float*)d_in[6];
  const float* Wr2   = (const float*)d_in[7];
  const float* Wr3   = (const float*)d_in[8];
  const float* Wr4   = (const float*)d_in[9];
  const float* Wd    = (const float*)d_in[10];
  const float* Wsin  = (const float*)d_in[11];
  const float* Wlin  = (const float*)d_in[12];
  const float* Wskip = (const float*)d_in[13];
  float* out = (float*)d_out;

  float* outD    = (float*)d_ws;                    // 20,480,000 f32
  float* msg     = outD + 20480000;                 // 20,480,000 f32
  float* x       = msg + 20480000;                  //  1,280,000 f32
  _Float16* WC16T= (_Float16*)(x + 1280000);        //    655,360 halfs
  int* cnt   = (int*)(WC16T + 655360);              //     10,000
  int* off   = cnt + 10000;                         //     10,016
  int* cur   = off + 10016;                         //     10,000
  int* elist = cur + 10000;                         //    160,000
  int* esnd  = elist + 160000;                      //    160,000
  _Float16* Wr2T = (_Float16*)(esnd + 160000);      //      4,096 halfs
  _Float16* Wr3T = Wr2T + 4096;                     //      4,096 halfs
  _Float16* Wr4T = Wr3T + 4096;                     //     32,768 halfs
  _Float16* WupT = Wr4T + 32768;                    //     16,384 halfs

  hipMemsetAsync(cnt, 0, (size_t)10000 * sizeof(int), stream);

  k_prep<<<224, 256, 0, stream>>>(Wr2, Wr3, Wr4, W_up, Wr2T, Wr3T, Wr4T, WupT);
  k_node_up<<<157, 256, 0, stream>>>(node_feats, WupT, x);
  k_wc<<<512, 256, 0, stream>>>(Wlin, Wskip, WC16T);

  k_count <<<(N_EDGES + 255)/256, 256, 0, stream>>>(edge_index, cnt);
  k_scan  <<<1, 256, 0, stream>>>(cnt, off, cur);
  k_bucket<<<(N_EDGES + 255)/256, 256, 0, stream>>>(edge_index, cur, elist, esnd);

  k_fused<<<N_NODES/4, 256, 0, stream>>>(edge_feats, edge_attrs, x,
                                         Wr1, Wd, Wr2T, Wr3T, Wr4T, Wsin,
                                         off, elist, esnd, msg);

  k_final<0,1><<<(N_NODES*1 + 127)/128, 256, 0, stream>>>(msg, node_attrs, WC16T, outD);
  k_final<1,3><<<(N_NODES*3 + 127)/128, 256, 0, stream>>>(msg, node_attrs, WC16T, outD + 1280000);
  k_final<2,5><<<(N_NODES*5 + 127)/128, 256, 0, stream>>>(msg, node_attrs, WC16T, outD + 5120000);
  k_final<3,7><<<(N_NODES*7 + 127)/128, 256, 0, stream>>>(msg, node_attrs, WC16T, outD + 11520000);

  k_merge<<<2500, 256, 0, stream>>>(outD, out);
}

// Round 8
// 368.704 us; speedup vs baseline: 6.3759x; 1.1275x over previous
//
#include <hip/hip_runtime.h>
#include <hip/hip_bf16.h>

#define N_NODES 10000
#define N_EDGES 160000

typedef _Float16 h8 __attribute__((ext_vector_type(8)));
typedef _Float16 h4 __attribute__((ext_vector_type(4)));
typedef _Float16 h2 __attribute__((ext_vector_type(2)));
typedef float f32x4 __attribute__((ext_vector_type(4)));

__device__ __forceinline__ float silu_f(float v){ return v / (1.f + expf(-v)); }

// ---------------------------------------------------------------- K1: x = nf @ Wup/sqrt(128) via MFMA, 64 nodes/block
__global__ __launch_bounds__(256) void k_node_up(const float* __restrict__ nf,
                                                 const _Float16* __restrict__ WupT,
                                                 float* __restrict__ x){
  const int n0 = blockIdx.x * 64;
  const int tid = threadIdx.x;
  alignas(16) __shared__ _Float16 s_nf[64*128];
  alignas(16) __shared__ _Float16 s_wt[128*128];

  {
    const int rl = tid >> 2, part = tid & 3;
    const int gr = n0 + rl;
    #pragma unroll
    for (int j = 0; j < 4; ++j){
      const int cu = part*4 + j;
      h8 hv = (h8){};
      if (gr < N_NODES){
        const float4 v0 = *(const float4*)(nf + (size_t)gr*128 + cu*8);
        const float4 v1 = *(const float4*)(nf + (size_t)gr*128 + cu*8 + 4);
        hv[0]=(_Float16)v0.x; hv[1]=(_Float16)v0.y; hv[2]=(_Float16)v0.z; hv[3]=(_Float16)v0.w;
        hv[4]=(_Float16)v1.x; hv[5]=(_Float16)v1.y; hv[6]=(_Float16)v1.z; hv[7]=(_Float16)v1.w;
      }
      const int cs = (cu & 8) | ((cu & 7) ^ (rl & 7));
      *(h8*)&s_nf[rl*128 + cs*8] = hv;
    }
  }
  {
    const int rl = tid >> 1, part = tid & 1;
    #pragma unroll
    for (int j = 0; j < 8; ++j){
      const int cu = part*8 + j;
      const h8 v = *(const h8*)&WupT[(size_t)rl*128 + cu*8];
      const int cs = (cu & 8) | ((cu & 7) ^ (rl & 7));
      *(h8*)&s_wt[rl*128 + cs*8] = v;
    }
  }
  __syncthreads();

  const int wid = tid >> 6, lane = tid & 63;
  const int li = lane & 15, kg = lane >> 4;

  f32x4 acc[8];
  #pragma unroll
  for (int i = 0; i < 8; ++i) acc[i] = (f32x4){0,0,0,0};

  const int row = wid*16 + li;
  #pragma unroll
  for (int s = 0; s < 4; ++s){
    const int ca = s*4 + kg;
    const int csA = (ca & 8) | ((ca & 7) ^ (row & 7));
    const h8 af = *(const h8*)&s_nf[row*128 + csA*8];
    #pragma unroll
    for (int nt = 0; nt < 8; ++nt){
      const int u = nt*16 + li;
      const int csB = (ca & 8) | ((ca & 7) ^ (u & 7));
      const h8 bf = *(const h8*)&s_wt[u*128 + csB*8];
      acc[nt] = __builtin_amdgcn_mfma_f32_16x16x32_f16(af, bf, acc[nt], 0, 0, 0);
    }
  }
  #pragma unroll
  for (int nt = 0; nt < 8; ++nt){
    #pragma unroll
    for (int r = 0; r < 4; ++r){
      const int gr = n0 + wid*16 + kg*4 + r;
      if (gr < N_NODES) x[(size_t)gr*128 + nt*16 + li] = acc[nt][r];
    }
  }
}

// ---------------------------------------------------------------- K1b: WC16T[l][w][a*128+u]
__global__ __launch_bounds__(256) void k_wc(const float* __restrict__ Wlin,
                                            const float* __restrict__ Wskip,
                                            _Float16* __restrict__ WC16T){
  const int lu = blockIdx.x;           // l*128 + u
  const int l  = lu >> 7, u = lu & 127;
  __shared__ float wl[128];
  if (threadIdx.x < 128) wl[threadIdx.x] = Wlin[lu*128 + threadIdx.x];
  __syncthreads();
  const float* Wsk = Wskip + (size_t)l * 163840;   // [v][a][w]
  for (int i = threadIdx.x; i < 1280; i += 256){   // i = a*128 + w
    float acc = 0.f;
    #pragma unroll 16
    for (int v = 0; v < 128; ++v) acc += wl[v] * Wsk[v*1280 + i];
    const int a = i >> 7, w = i & 127;
    WC16T[((size_t)l*128 + w)*1280 + a*128 + u] =
        (_Float16)(acc * 0.0024705294220065465f);  // 1/sqrt(128*1280)
  }
}

// ---------------------------------------------------------------- K1c: pre-transposed fp16 weights (scales folded)
__global__ __launch_bounds__(256) void k_prep(const float* __restrict__ Wr2,
                                              const float* __restrict__ Wr3,
                                              const float* __restrict__ Wr4,
                                              const float* __restrict__ Wup,
                                              _Float16* __restrict__ Wr2T,
                                              _Float16* __restrict__ Wr3T,
                                              _Float16* __restrict__ Wr4T,
                                              _Float16* __restrict__ WupT){
  const int idx = blockIdx.x*256 + threadIdx.x;
  if (idx < 4096){
    const int n = idx >> 6, k = idx & 63;
    Wr2T[idx] = (_Float16)(Wr2[k*64 + n] * 0.125f);
  } else if (idx < 8192){
    const int j = idx - 4096;
    const int n = j >> 6, k = j & 63;
    Wr3T[j] = (_Float16)(Wr3[k*64 + n] * 0.125f);
  } else if (idx < 40960){
    const int j = idx - 8192;
    const int n = j >> 6, k = j & 63;
    Wr4T[j] = (_Float16)(Wr4[k*512 + n] * 0.125f);
  } else if (idx < 57344){
    const int j = idx - 40960;
    const int u = j >> 7, k = j & 127;
    WupT[j] = (_Float16)(Wup[k*128 + u] * 0.08838834764831843f);
  }
}

// ---------------------------------------------------------------- CSR build
__global__ __launch_bounds__(256) void k_count(const int* __restrict__ eidx,
                                               int* __restrict__ cnt){
  const int e = blockIdx.x * 256 + threadIdx.x;
  if (e < N_EDGES) atomicAdd(&cnt[eidx[N_EDGES + e]], 1);
}

__global__ __launch_bounds__(256) void k_scan(const int* __restrict__ cnt,
                                              int* __restrict__ off,
                                              int* __restrict__ cur){
  __shared__ int sums[256];
  const int t = threadIdx.x;
  const int base = t * 40;
  int s = 0;
  for (int i = 0; i < 40; ++i){
    const int idx = base + i;
    if (idx < N_NODES) s += cnt[idx];
  }
  sums[t] = s;
  __syncthreads();
  for (int st = 1; st < 256; st <<= 1){
    const int v = (t >= st) ? sums[t - st] : 0;
    __syncthreads();
    sums[t] += v;
    __syncthreads();
  }
  int pre = (t > 0) ? sums[t - 1] : 0;
  for (int i = 0; i < 40; ++i){
    const int idx = base + i;
    if (idx < N_NODES){
      off[idx] = pre; cur[idx] = pre;
      pre += cnt[idx];
    }
  }
  if (t == 255) off[N_NODES] = sums[255];
}

__global__ __launch_bounds__(256) void k_bucket(const int* __restrict__ eidx,
                                                int* __restrict__ cur,
                                                int* __restrict__ elist,
                                                int* __restrict__ esnd){
  const int e = blockIdx.x * 256 + threadIdx.x;
  if (e < N_EDGES){
    const int pos = atomicAdd(&cur[eidx[N_EDGES + e]], 1);
    elist[pos] = e;
    esnd[pos]  = eidx[e];
  }
}

// ---------------------------------------------------------------- K2: FUSED edge MLP + gather. Block owns 4 nodes, 16-edge groups.
__global__ __launch_bounds__(256) void k_fused(const float* __restrict__ ef,
                                               const float* __restrict__ ea,
                                               const float* __restrict__ x,
                                               const float* __restrict__ Wr1,
                                               const float* __restrict__ Wd,
                                               const _Float16* __restrict__ Wr2T,
                                               const _Float16* __restrict__ Wr3T,
                                               const _Float16* __restrict__ Wr4T,
                                               const float* __restrict__ Wsin,
                                               const int* __restrict__ off,
                                               const int* __restrict__ elist,
                                               const int* __restrict__ esnd,
                                               float* __restrict__ msg){
  const int n0 = blockIdx.x * 4;
  const int tid = threadIdx.x;
  const int lane = tid & 63, wid = tid >> 6;
  const int li = lane & 15, kg = lane >> 4;
  const int u2 = tid & 63, q = tid >> 6;   // accumulate mapping: u = 2*u2 + {0,1}, sk = q*4 + j

  __shared__ int   s_eid[16];
  __shared__ float s_ef[16][8];
  __shared__ float s_w1[8][64];
  alignas(16) __shared__ _Float16 s_xs[16][136];
  alignas(16) __shared__ _Float16 s_actA[16][64];
  alignas(16) __shared__ _Float16 s_actB[16][64];
  alignas(16) __shared__ _Float16 s_w2[16][520];
  alignas(16) __shared__ float s_sh[16][16];
  __shared__ float s_dd[16];
  __shared__ float s_rho[4];
  __shared__ int   s_offs[5];
  __shared__ float s_emb[4][32];

  if (tid < 5) s_offs[tid] = off[n0 + tid];
  if (tid < 4) s_rho[tid] = 0.f;
  for (int j = tid; j < 512; j += 256) s_w1[j >> 6][j & 63] = Wr1[j];
  __syncthreads();

  const int beg = s_offs[0], end = s_offs[4];
  const int ngrp = (end - beg + 15) >> 4;

  float a0[8] = {0,0,0,0,0,0,0,0};
  float a1[8] = {0,0,0,0,0,0,0,0};
  float a2[8] = {0,0,0,0,0,0,0,0};
  float a3[8] = {0,0,0,0,0,0,0,0};

  for (int grp = 0; grp < ngrp; ++grp){
    const int pbase = beg + grp*16;

    if (tid < 16) s_eid[tid] = (pbase + tid < end) ? elist[pbase + tid] : -1;
    __syncthreads();

    // ---- stage ef, sh, xs
    if (tid < 128){
      const int e = tid >> 3, i = tid & 7;
      const int eid = s_eid[e];
      s_ef[e][i] = (eid >= 0) ? ef[(size_t)eid*8 + i] : 0.f;
    }
    {
      const int slot = tid >> 4, jj = tid & 15;
      const int eid = s_eid[slot];
      s_sh[slot][jj] = (eid >= 0) ? ea[(size_t)eid*16 + jj] : 0.f;
    }
    {
      const int e = tid >> 4, qq = tid & 15;
      const int p = pbase + e;
      const int snd = (p < end) ? esnd[p] : 0;
      const float4* xp = (const float4*)(x + (size_t)snd*128 + qq*8);
      const float4 v0 = xp[0], v1 = xp[1];
      h4 ha, hb;
      ha[0]=(_Float16)v0.x; ha[1]=(_Float16)v0.y; ha[2]=(_Float16)v0.z; ha[3]=(_Float16)v0.w;
      hb[0]=(_Float16)v1.x; hb[1]=(_Float16)v1.y; hb[2]=(_Float16)v1.z; hb[3]=(_Float16)v1.w;
      *(h4*)&s_xs[e][qq*8]     = ha;
      *(h4*)&s_xs[e][qq*8 + 4] = hb;
    }
    __syncthreads();

    // ---- dd
    if (tid < 16){
      float s = 0.f;
      #pragma unroll
      for (int i = 0; i < 8; ++i) s += s_ef[tid][i] * Wd[i];
      s_dd[tid] = tanhf(s*s);
    }

    // ---- L1 (VALU, K=8): 16e x 64n; thread = (e, 4 n's)
    {
      const int e = tid >> 4, ng = tid & 15;
      float hv[4] = {0,0,0,0};
      #pragma unroll
      for (int k = 0; k < 8; ++k){
        const float ev = s_ef[e][k] * 0.3535533905932738f;
        #pragma unroll
        for (int j = 0; j < 4; ++j) hv[j] += ev * s_w1[k][ng*4 + j];
      }
      h4 o;
      #pragma unroll
      for (int j = 0; j < 4; ++j) o[j] = (_Float16)silu_f(hv[j]);
      const int nb = ng*4;
      *(h4*)&s_actA[e][((nb >> 3) ^ (e & 7))*8 + (nb & 7)] = o;
    }
    __syncthreads();

    // ---- L2 MFMA: 64n x 16e
    {
      h8 af[2];
      #pragma unroll
      for (int s = 0; s < 2; ++s)
        af[s] = *(const h8*)&Wr2T[(size_t)(wid*16 + li)*64 + s*32 + kg*8];
      f32x4 acc = (f32x4){0,0,0,0};
      #pragma unroll
      for (int s = 0; s < 2; ++s){
        const h8 bf = *(const h8*)&s_actA[li][((s*4 + kg) ^ (li & 7))*8];
        acc = __builtin_amdgcn_mfma_f32_16x16x32_f16(af[s], bf, acc, 0, 0, 0);
      }
      #pragma unroll
      for (int r = 0; r < 4; ++r){
        const int n = wid*16 + kg*4 + r;
        s_actB[li][((n >> 3) ^ (li & 7))*8 + (n & 7)] = (_Float16)silu_f(acc[r]);
      }
    }
    __syncthreads();

    // ---- L3 MFMA
    {
      h8 af[2];
      #pragma unroll
      for (int s = 0; s < 2; ++s)
        af[s] = *(const h8*)&Wr3T[(size_t)(wid*16 + li)*64 + s*32 + kg*8];
      f32x4 acc = (f32x4){0,0,0,0};
      #pragma unroll
      for (int s = 0; s < 2; ++s){
        const h8 bf = *(const h8*)&s_actB[li][((s*4 + kg) ^ (li & 7))*8];
        acc = __builtin_amdgcn_mfma_f32_16x16x32_f16(af[s], bf, acc, 0, 0, 0);
      }
      #pragma unroll
      for (int r = 0; r < 4; ++r){
        const int n = wid*16 + kg*4 + r;
        s_actA[li][((n >> 3) ^ (li & 7))*8 + (n & 7)] = (_Float16)silu_f(acc[r]);
      }
    }
    __syncthreads();

    // ---- tpw MFMA: 512c x 16e -> s_w2 = tpw*xs
    {
      h8 bf[2];
      #pragma unroll
      for (int s = 0; s < 2; ++s)
        bf[s] = *(const h8*)&s_actA[li][((s*4 + kg) ^ (li & 7))*8];
      #pragma unroll
      for (int mt = 0; mt < 8; ++mt){
        const int nbase = wid*128 + mt*16;
        h8 af[2];
        #pragma unroll
        for (int s = 0; s < 2; ++s)
          af[s] = *(const h8*)&Wr4T[(size_t)(nbase + li)*64 + s*32 + kg*8];
        f32x4 acc = (f32x4){0,0,0,0};
        #pragma unroll
        for (int s = 0; s < 2; ++s)
          acc = __builtin_amdgcn_mfma_f32_16x16x32_f16(af[s], bf[s], acc, 0, 0, 0);
        const int c0 = nbase + kg*4;
        const int u0 = c0 & 127;
        const h4 xv = *(const h4*)&s_xs[li][u0];
        h4 ov;
        #pragma unroll
        for (int r = 0; r < 4; ++r) ov[r] = (_Float16)acc[r] * xv[r];
        *(h4*)&s_w2[li][c0] = ov;
      }
    }
    __syncthreads();

    // ---- accumulate into per-node registers; thread = (2 u's, 4 sk's)
    int lo0 = s_offs[0] - pbase; lo0 = lo0 < 0 ? 0 : lo0;
    int hi0 = s_offs[1] - pbase; hi0 = hi0 > 16 ? 16 : (hi0 < 0 ? 0 : hi0);
    int lo1 = s_offs[1] - pbase; lo1 = lo1 < 0 ? 0 : lo1;
    int hi1 = s_offs[2] - pbase; hi1 = hi1 > 16 ? 16 : (hi1 < 0 ? 0 : hi1);
    int lo2 = s_offs[2] - pbase; lo2 = lo2 < 0 ? 0 : lo2;
    int hi2 = s_offs[3] - pbase; hi2 = hi2 > 16 ? 16 : (hi2 < 0 ? 0 : hi2);
    int lo3 = s_offs[3] - pbase; lo3 = lo3 < 0 ? 0 : lo3;
    int hi3 = s_offs[4] - pbase; hi3 = hi3 > 16 ? 16 : (hi3 < 0 ? 0 : hi3);

#define ACCQ0(A, LO, HI)                                             \
    for (int s = (LO); s < (HI); ++s){                               \
      const h2 w0 = *(const h2*)&s_w2[s][2*u2];                      \
      const h2 w1 = *(const h2*)&s_w2[s][128 + 2*u2];                \
      const float4 sv = *(const float4*)&s_sh[s][0];                 \
      A[0] += (float)w0[0]*sv.x; A[1] += (float)w0[1]*sv.x;          \
      A[2] += (float)w1[0]*sv.y; A[3] += (float)w1[1]*sv.y;          \
      A[4] += (float)w1[0]*sv.z; A[5] += (float)w1[1]*sv.z;          \
      A[6] += (float)w1[0]*sv.w; A[7] += (float)w1[1]*sv.w;          \
    }
#define ACCQ1(A, LO, HI)                                             \
    for (int s = (LO); s < (HI); ++s){                               \
      const h2 wv = *(const h2*)&s_w2[s][256 + 2*u2];                \
      const float4 sv = *(const float4*)&s_sh[s][4];                 \
      A[0] += (float)wv[0]*sv.x; A[1] += (float)wv[1]*sv.x;          \
      A[2] += (float)wv[0]*sv.y; A[3] += (float)wv[1]*sv.y;          \
      A[4] += (float)wv[0]*sv.z; A[5] += (float)wv[1]*sv.z;          \
      A[6] += (float)wv[0]*sv.w; A[7] += (float)wv[1]*sv.w;          \
    }
#define ACCQ2(A, LO, HI)                                             \
    for (int s = (LO); s < (HI); ++s){                               \
      const h2 wv = *(const h2*)&s_w2[s][256 + 2*u2];                \
      const h2 wx = *(const h2*)&s_w2[s][384 + 2*u2];                \
      const float4 sv = *(const float4*)&s_sh[s][8];                 \
      A[0] += (float)wv[0]*sv.x; A[1] += (float)wv[1]*sv.x;          \
      A[2] += (float)wx[0]*sv.y; A[3] += (float)wx[1]*sv.y;          \
      A[4] += (float)wx[0]*sv.z; A[5] += (float)wx[1]*sv.z;          \
      A[6] += (float)wx[0]*sv.w; A[7] += (float)wx[1]*sv.w;          \
    }
#define ACCQ3(A, LO, HI)                                             \
    for (int s = (LO); s < (HI); ++s){                               \
      const h2 wx = *(const h2*)&s_w2[s][384 + 2*u2];                \
      const float4 sv = *(const float4*)&s_sh[s][12];                \
      A[0] += (float)wx[0]*sv.x; A[1] += (float)wx[1]*sv.x;          \
      A[2] += (float)wx[0]*sv.y; A[3] += (float)wx[1]*sv.y;          \
      A[4] += (float)wx[0]*sv.z; A[5] += (float)wx[1]*sv.z;          \
      A[6] += (float)wx[0]*sv.w; A[7] += (float)wx[1]*sv.w;          \
    }

    if (q == 0){
      ACCQ0(a0, lo0, hi0) ACCQ0(a1, lo1, hi1) ACCQ0(a2, lo2, hi2) ACCQ0(a3, lo3, hi3)
    } else if (q == 1){
      ACCQ1(a0, lo0, hi0) ACCQ1(a1, lo1, hi1) ACCQ1(a2, lo2, hi2) ACCQ1(a3, lo3, hi3)
    } else if (q == 2){
      ACCQ2(a0, lo0, hi0) ACCQ2(a1, lo1, hi1) ACCQ2(a2, lo2, hi2) ACCQ2(a3, lo3, hi3)
    } else {
      ACCQ3(a0, lo0, hi0) ACCQ3(a1, lo1, hi1) ACCQ3(a2, lo2, hi2) ACCQ3(a3, lo3, hi3)
    }

    if (tid < 4){
      int lo = s_offs[tid]     - pbase; lo = lo < 0 ? 0 : lo;
      int hi = s_offs[tid + 1] - pbase; hi = hi > 16 ? 16 : (hi < 0 ? 0 : hi);
      float r = 0.f;
      for (int s = lo; s < hi; ++s) r += s_dd[s];
      s_rho[tid] += r;
    }
    __syncthreads();
  }

  // ---- epilogue: per-node rho -> emb, tinv; write msg
  if (tid < 64){
    const int ni = tid >> 4, f = tid & 15;
    const float fr  = expf(-0.28782313662425572f * (float)f);  // ln(100)/16
    const float ang = s_rho[ni] * fr;
    s_emb[ni][f]      = sinf(ang);
    s_emb[ni][f + 16] = cosf(ang);
  }
  __syncthreads();

  float db00=0.f, db01=0.f, db10=0.f, db11=0.f;
  float db20=0.f, db21=0.f, db30=0.f, db31=0.f;
  if (q == 0){
    #pragma unroll 8
    for (int j = 0; j < 32; ++j){
      const float w0 = Wsin[j*128 + 2*u2];
      const float w1 = Wsin[j*128 + 2*u2 + 1];
      const float e0 = s_emb[0][j], e1 = s_emb[1][j];
      const float e2 = s_emb[2][j], e3 = s_emb[3][j];
      db00 += e0*w0; db01 += e0*w1;
      db10 += e1*w0; db11 += e1*w1;
      db20 += e2*w0; db21 += e2*w1;
      db30 += e3*w0; db31 += e3*w1;
    }
  }
  const float t0 = 1.f/(s_rho[0]+1.f), t1 = 1.f/(s_rho[1]+1.f);
  const float t2 = 1.f/(s_rho[2]+1.f), t3 = 1.f/(s_rho[3]+1.f);

  #pragma unroll
  for (int j = 0; j < 4; ++j){
    const int sk = q*4 + j;
    const size_t base = (size_t)sk*128 + 2*u2;
    float2 v0 = { a0[j*2+0]*t0, a0[j*2+1]*t0 };
    float2 v1 = { a1[j*2+0]*t1, a1[j*2+1]*t1 };
    float2 v2 = { a2[j*2+0]*t2, a2[j*2+1]*t2 };
    float2 v3 = { a3[j*2+0]*t3, a3[j*2+1]*t3 };
    if (q == 0 && j == 0){
      v0.x += db00; v0.y += db01;
      v1.x += db10; v1.y += db11;
      v2.x += db20; v2.y += db21;
      v3.x += db30; v3.y += db31;
    }
    *(float2*)&msg[(size_t)(n0+0)*2048 + base] = v0;
    *(float2*)&msg[(size_t)(n0+1)*2048 + base] = v1;
    *(float2*)&msg[(size_t)(n0+2)*2048 + base] = v2;
    *(float2*)&msg[(size_t)(n0+3)*2048 + base] = v3;
  }
}

// ---------------------------------------------------------------- K4: final GEMM body (128x128 LDS-staged MFMA tile)
template<int L, int D>
__device__ __forceinline__ void final_body(const int bb,
                                           const float* __restrict__ msg,
                                           const float* __restrict__ attrs,
                                           const _Float16* __restrict__ WC16T,
                                           float* __restrict__ outD,
                                           _Float16* __restrict__ sA,
                                           _Float16* __restrict__ sB,      // [2][64*128]
                                           _Float16* __restrict__ sAttr){
  constexpr int OFF  = (L==0 ? 0 : L==1 ? 1 : L==2 ? 4 : 9);
  constexpr int ROWS = N_NODES * D;
  const int r0  = bb * 128;
  const int tid = threadIdx.x;

  {
    const int rl = tid >> 1, half = tid & 1;
    const int gr = r0 + rl;
    h8 vals[8];
    if (gr < ROWS){
      const int n = gr / D, k = gr - n*D;
      const float4* src = (const float4*)(msg + (size_t)n*2048 + (size_t)(OFF+k)*128 + half*64);
      #pragma unroll
      for (int j = 0; j < 8; ++j){
        const float4 v0 = src[j*2], v1 = src[j*2+1];
        h8 hv;
        hv[0]=(_Float16)v0.x; hv[1]=(_Float16)v0.y; hv[2]=(_Float16)v0.z; hv[3]=(_Float16)v0.w;
        hv[4]=(_Float16)v1.x; hv[5]=(_Float16)v1.y; hv[6]=(_Float16)v1.z; hv[7]=(_Float16)v1.w;
        vals[j] = hv;
      }
    } else {
      #pragma unroll
      for (int j = 0; j < 8; ++j) vals[j] = (h8){};
    }
    #pragma unroll
    for (int j = 0; j < 8; ++j){
      const int cu = half*8 + j;
      const int cs = (cu & 8) | ((cu & 7) ^ (rl & 7));
      *(h8*)&sA[rl*128 + cs*8] = vals[j];
    }
  }
  for (int i = tid; i < 1280; i += 256){
    const int rl = i / 10, aa = i - rl*10;
    const int gr = r0 + rl;
    sAttr[i] = (gr < ROWS) ? (_Float16)attrs[(gr / D)*10 + aa] : (_Float16)0.f;
  }
  {
    const int w = tid >> 1, part = tid & 1;
    const _Float16* src = WC16T + ((size_t)L*128 + w)*1280 + part*32;
    #pragma unroll
    for (int j = 0; j < 4; ++j){
      const h8 v = *(const h8*)(src + j*8);
      const int cc = part*4 + j;
      *(h8*)&sB[w*64 + (cc ^ (w & 7))*8] = v;
    }
  }
  __syncthreads();

  const int wid = tid >> 6, lane = tid & 63;
  const int wm = wid >> 1, wn = wid & 1;
  const int li = lane & 15, kg = lane >> 4;

  f32x4 acc[4][4];
  #pragma unroll
  for (int m = 0; m < 4; ++m)
    #pragma unroll
    for (int nn = 0; nn < 4; ++nn) acc[m][nn] = (f32x4){0,0,0,0};

  for (int step = 0; step < 20; ++step){
    _Float16* sbc = (step & 1) ? (sB + 8192) : sB;
    _Float16* sbn = (step & 1) ? sB : (sB + 8192);
    const bool more = (step + 1 < 20);
    h8 pre[4];
    if (more){
      const int a2 = (step+1) >> 1, u02 = ((step+1) & 1) << 6;
      const _Float16* src = WC16T + ((size_t)L*128 + (tid>>1))*1280 + a2*128 + u02 + (tid&1)*32;
      #pragma unroll
      for (int j = 0; j < 4; ++j) pre[j] = *(const h8*)(src + j*8);
    }

    const int a  = step >> 1;
    const int uh = (step & 1) << 3;

    h8 afr[4][2], bfr[4][2];
    #pragma unroll
    for (int m = 0; m < 4; ++m){
      const int row = wm*64 + m*16 + li;
      const _Float16 av = sAttr[row*10 + a];
      h8 avx;
      #pragma unroll
      for (int j = 0; j < 8; ++j) avx[j] = av;
      #pragma unroll
      for (int s = 0; s < 2; ++s){
        const int ca = uh + s*4 + kg;
        const int cs = (ca & 8) | ((ca & 7) ^ (row & 7));
        const h8 mA = *(const h8*)&sA[row*128 + cs*8];
        afr[m][s] = mA * avx;
      }
    }
    #pragma unroll
    for (int nn = 0; nn < 4; ++nn){
      const int w = wn*64 + nn*16 + li;
      #pragma unroll
      for (int s = 0; s < 2; ++s){
        const int cb = s*4 + kg;
        bfr[nn][s] = *(const h8*)&sbc[w*64 + ((cb ^ (w & 7)))*8];
      }
    }
    #pragma unroll
    for (int s = 0; s < 2; ++s)
      #pragma unroll
      for (int m = 0; m < 4; ++m)
        #pragma unroll
        for (int nn = 0; nn < 4; ++nn)
          acc[m][nn] = __builtin_amdgcn_mfma_f32_16x16x32_f16(afr[m][s], bfr[nn][s], acc[m][nn], 0, 0, 0);

    if (more){
      const int w = tid >> 1, part = tid & 1;
      #pragma unroll
      for (int j = 0; j < 4; ++j){
        const int cc = part*4 + j;
        *(h8*)&sbn[w*64 + (cc ^ (w & 7))*8] = pre[j];
      }
    }
    __syncthreads();
  }

  #pragma unroll
  for (int m = 0; m < 4; ++m){
    const int rbase = r0 + wm*64 + m*16 + kg*4;
    #pragma unroll
    for (int rr = 0; rr < 4; ++rr){
      const int gr = rbase + rr;
      if (gr < ROWS){
        float* op = outD + (size_t)gr*128;
        #pragma unroll
        for (int nn = 0; nn < 4; ++nn)
          op[wn*64 + nn*16 + li] = acc[m][nn][rr];
      }
    }
  }
}

// single launch for all four l's
__global__ __launch_bounds__(256) void k_final_all(const float* __restrict__ msg,
                                                   const float* __restrict__ attrs,
                                                   const _Float16* __restrict__ WC16T,
                                                   float* __restrict__ outD){
  alignas(16) __shared__ _Float16 sA[128*128];
  alignas(16) __shared__ _Float16 sB[2*64*128];
  __shared__ _Float16 sAttr[128*10];
  const int b = blockIdx.x;
  if (b < 79)       final_body<0,1>(b,       msg, attrs, WC16T, outD,            sA, sB, sAttr);
  else if (b < 314) final_body<1,3>(b - 79,  msg, attrs, WC16T, outD + 1280000,  sA, sB, sAttr);
  else if (b < 705) final_body<2,5>(b - 314, msg, attrs, WC16T, outD + 5120000,  sA, sB, sAttr);
  else              final_body<3,7>(b - 705, msg, attrs, WC16T, outD + 11520000, sA, sB, sAttr);
}

// ---------------------------------------------------------------- K5: merge dense outD_l into out[n][w][sk] full lines
__global__ __launch_bounds__(256) void k_merge(const float* __restrict__ outD,
                                               float* __restrict__ out){
  const int n0 = blockIdx.x * 4;
  const int tid = threadIdx.x;
  __shared__ float lds[4*16*132];   // [nloc][sk][w] stride 132

  {
    const float4* src = (const float4*)(outD + (size_t)n0*128);
    for (int j = tid; j < 128; j += 256){
      const int row = j >> 5, c4 = j & 31;
      *(float4*)&lds[(row*16 + 0)*132 + c4*4] = src[j];
    }
  }
  {
    const float4* src = (const float4*)(outD + 1280000 + (size_t)n0*3*128);
    for (int j = tid; j < 384; j += 256){
      const int row = j >> 5, c4 = j & 31;
      const int nloc = row/3, k = row - nloc*3;
      *(float4*)&lds[(nloc*16 + 1 + k)*132 + c4*4] = src[j];
    }
  }
  {
    const float4* src = (const float4*)(outD + 5120000 + (size_t)n0*5*128);
    for (int j = tid; j < 640; j += 256){
      const int row = j >> 5, c4 = j & 31;
      const int nloc = row/5, k = row - nloc*5;
      *(float4*)&lds[(nloc*16 + 4 + k)*132 + c4*4] = src[j];
    }
  }
  {
    const float4* src = (const float4*)(outD + 11520000 + (size_t)n0*7*128);
    for (int j = tid; j < 896; j += 256){
      const int row = j >> 5, c4 = j & 31;
      const int nloc = row/7, k = row - nloc*7;
      *(float4*)&lds[(nloc*16 + 9 + k)*132 + c4*4] = src[j];
    }
  }
  __syncthreads();

  for (int j = tid; j < 2048; j += 256){
    const int nloc = j >> 9, qv = j & 511;
    const int w = qv >> 2, s0 = (qv & 3) << 2;
    float4 v;
    v.x = lds[(nloc*16 + s0 + 0)*132 + w];
    v.y = lds[(nloc*16 + s0 + 1)*132 + w];
    v.z = lds[(nloc*16 + s0 + 2)*132 + w];
    v.w = lds[(nloc*16 + s0 + 3)*132 + w];
    *(float4*)&out[(size_t)(n0 + nloc)*2048 + qv*4] = v;
  }
}

// ----------------------------------------------------------------
extern "C" void kernel_launch(void* const* d_in, const int* in_sizes, int n_in,
                              void* d_out, int out_size, void* d_ws, size_t ws_size,
                              hipStream_t stream){
  const float* node_attrs = (const float*)d_in[0];
  const float* node_feats = (const float*)d_in[1];
  const float* edge_attrs = (const float*)d_in[2];
  const float* edge_feats = (const float*)d_in[3];
  const int*   edge_index = (const int*)d_in[4];
  const float* W_up  = (const float*)d_in[5];
  const float* Wr1   = (const float*)d_in[6];
  const float* Wr2   = (const float*)d_in[7];
  const float* Wr3   = (const float*)d_in[8];
  const float* Wr4   = (const float*)d_in[9];
  const float* Wd    = (const float*)d_in[10];
  const float* Wsin  = (const float*)d_in[11];
  const float* Wlin  = (const float*)d_in[12];
  const float* Wskip = (const float*)d_in[13];
  float* out = (float*)d_out;

  float* outD    = (float*)d_ws;                    // 20,480,000 f32
  float* msg     = outD + 20480000;                 // 20,480,000 f32
  float* x       = msg + 20480000;                  //  1,280,000 f32
  _Float16* WC16T= (_Float16*)(x + 1280000);        //    655,360 halfs
  int* cnt   = (int*)(WC16T + 655360);              //     10,000
  int* off   = cnt + 10000;                         //     10,016
  int* cur   = off + 10016;                         //     10,000
  int* elist = cur + 10000;                         //    160,000
  int* esnd  = elist + 160000;                      //    160,000
  _Float16* Wr2T = (_Float16*)(esnd + 160000);      //      4,096 halfs
  _Float16* Wr3T = Wr2T + 4096;                     //      4,096 halfs
  _Float16* Wr4T = Wr3T + 4096;                     //     32,768 halfs
  _Float16* WupT = Wr4T + 32768;                    //     16,384 halfs

  hipMemsetAsync(cnt, 0, (size_t)10000 * sizeof(int), stream);

  k_prep<<<224, 256, 0, stream>>>(Wr2, Wr3, Wr4, W_up, Wr2T, Wr3T, Wr4T, WupT);
  k_node_up<<<157, 256, 0, stream>>>(node_feats, WupT, x);
  k_wc<<<512, 256, 0, stream>>>(Wlin, Wskip, WC16T);

  k_count <<<(N_EDGES + 255)/256, 256, 0, stream>>>(edge_index, cnt);
  k_scan  <<<1, 256, 0, stream>>>(cnt, off, cur);
  k_bucket<<<(N_EDGES + 255)/256, 256, 0, stream>>>(edge_index, cur, elist, esnd);

  k_fused<<<N_NODES/4, 256, 0, stream>>>(edge_feats, edge_attrs, x,
                                         Wr1, Wd, Wr2T, Wr3T, Wr4T, Wsin,
                                         off, elist, esnd, msg);

  k_final_all<<<1252, 256, 0, stream>>>(msg, node_attrs, WC16T, outD);

  k_merge<<<2500, 256, 0, stream>>>(outD, out);
}